// Round 8
// baseline (421.786 us; speedup 1.0000x reference)
//
#include <hip/hip_runtime.h>
#include <cstdint>
#include <cstddef>

typedef unsigned short u16;
typedef __attribute__((ext_vector_type(8))) short s16x8;
typedef __attribute__((ext_vector_type(4))) float f32x4;

#define NQ   8192
#define TT   512
#define STOK 32
#define LDF  260   // Fv row stride (floats): 256 + 4 pad -> bank rotation by 4/row

__device__ __forceinline__ float b2f(u16 u) {
    return __uint_as_float(((uint32_t)u) << 16);
}
__device__ __forceinline__ u16 f2b(float f) {
    uint32_t x = __float_as_uint(f);
    uint32_t r = (x + 0x7FFFu + ((x >> 16) & 1u)) >> 16;
    return (u16)r;
}
__device__ __forceinline__ float silu_f(float x) { return x / (1.f + expf(-x)); }

__global__ __launch_bounds__(256) void const_kernel(float v, float* __restrict__ out) {
    int i = blockIdx.x * 256 + threadIdx.x;
    if (i < NQ) out[i] = v;
}

// ---------------------------------------------------------------------------
// zero CNT[512] + CNT3[3]
// ---------------------------------------------------------------------------
__global__ __launch_bounds__(256) void zero_kernel(int* __restrict__ cnt,
                                                   int* __restrict__ cnt3) {
    int i = blockIdx.x * 256 + threadIdx.x;
    if (i < 512) cnt[i] = 0;
    if (i >= 512 && i < 515) cnt3[i - 512] = 0;
}

// ---------------------------------------------------------------------------
// features (verified): FIN fp32 [NQ,160] (cols 152..159 = 0), IDX
// ---------------------------------------------------------------------------
__global__ __launch_bounds__(256) void feat32_kernel(
    const float* __restrict__ xy, const float* __restrict__ t_q,
    const int* __restrict__ c, const float* __restrict__ st,
    const float* __restrict__ B, const float* __restrict__ tw,
    const float* __restrict__ tb, const float* __restrict__ ce,
    float* __restrict__ FIN, int* __restrict__ IDX) {
    int n = blockIdx.x, t = threadIdx.x;
    float tq = t_q[n];
    int lo = 0, hi = TT;
    while (lo < hi) {
        int mid = (lo + hi) >> 1;
        if (st[mid] <= tq) lo = mid + 1; else hi = mid;
    }
    int idx = lo - 1;
    if (idx < 0) idx = 0;
    float dt = tq - st[idx];
    if (dt < 0.f) dt = 0.f;
    if (t == 0) IDX[n] = idx;
    float x = xy[2 * n], y = xy[2 * n + 1];
    size_t base = (size_t)n * 160;
    if (t < 64) { float p = x * B[t] + y * B[64 + t]; FIN[base + t] = cosf(p); }
    else if (t < 128) { int j = t - 64; float p = x * B[j] + y * B[64 + j]; FIN[base + t] = sinf(p); }
    else if (t < 144) { int j = t - 128; FIN[base + t] = dt * tw[j] + tb[j]; }
    else if (t < 152) { int j = t - 144; FIN[base + t] = ce[c[n] * 8 + j]; }
    else if (t < 160) { FIN[base + t] = 0.f; }
}

// ---------------------------------------------------------------------------
// pack_split: all chain weights -> MFMA-fragment-linear bf16 hi/lo.
// pos = ((ct*NK0 + k0)*64 + quad*16 + m16)*8 + j   (ct=col>>4, NK0=K/32)
// Layout (u16 idx): m*65536 for m=0..7 = {f1w L0, f1w L1, f2w L0, f2w L1,
// wq, aow, w1, w2}; trunk_in (K=160, NK0=5, zero-padded cols>=152) at 524288.
// ---------------------------------------------------------------------------
__global__ __launch_bounds__(256) void pack_split(
    const float* __restrict__ f1w, const float* __restrict__ f2w,
    const float* __restrict__ aiw, const float* __restrict__ aow,
    const float* __restrict__ w1, const float* __restrict__ w2,
    const float* __restrict__ tiw,
    u16* __restrict__ PH, u16* __restrict__ PL) {
    int i = blockIdx.x * 256 + threadIdx.x;
    if (i >= 565248) return;
    float v;
    size_t pos;
    if (i < 524288) {
        int m = i >> 16, j = i & 65535;
        int col = j >> 8, k = j & 255;
        const float* src;
        switch (m) {
            case 0: src = f1w; break;
            case 1: src = f1w + 65536; break;
            case 2: src = f2w; break;
            case 3: src = f2w + 65536; break;
            case 4: src = aiw; break;          // wq = rows 0..255 of attn_in_w
            case 5: src = aow; break;
            case 6: src = w1; break;
            default: src = w2; break;
        }
        v = src[j];
        int ct = col >> 4, m16 = col & 15, k0 = k >> 5, quad = (k >> 3) & 3, jj = k & 7;
        pos = (size_t)m * 65536 + (size_t)(((ct * 8 + k0) * 64 + quad * 16 + m16) * 8 + jj);
    } else {
        int j = i - 524288;                    // 0..40959
        int col = j / 160, k = j % 160;
        v = (k < 152) ? tiw[col * 152 + k] : 0.f;
        int ct = col >> 4, m16 = col & 15, k0 = k >> 5, quad = (k >> 3) & 3, jj = k & 7;
        pos = 524288 + (size_t)(((ct * 5 + k0) * 64 + quad * 16 + m16) * 8 + jj);
    }
    u16 h = f2b(v);
    PH[pos] = h;
    PL[pos] = f2b(v - b2f(h));
}

// ---------------------------------------------------------------------------
// fold token projection into K/V weights; emit bf16 [512,256] + fp32 bias[512]
// ---------------------------------------------------------------------------
__global__ __launch_bounds__(256) void combine_kv32(
    const float* __restrict__ aiw, const float* __restrict__ aib,
    const float* __restrict__ btw, const float* __restrict__ btb,
    u16* __restrict__ WKVb, float* __restrict__ bkv) {
    int kv = blockIdx.x >> 8, m = blockIdx.x & 255;
    int d = threadIdx.x;
    __shared__ float wrow[256];
    wrow[d] = aiw[(size_t)(kv + 1) * 65536 + (size_t)m * 256 + d];
    __syncthreads();
    float acc = 0.f;
#pragma unroll 8
    for (int o = 0; o < 256; o++) acc += wrow[o] * btw[(size_t)o * 256 + d];
    WKVb[(size_t)kv * 65536 + (size_t)m * 256 + d] = f2b(acc);
    float pb = wrow[d] * btb[d];
#pragma unroll
    for (int mm = 32; mm >= 1; mm >>= 1) pb += __shfl_xor(pb, mm);
    __shared__ float red[4];
    if ((d & 63) == 0) red[d >> 6] = pb;
    __syncthreads();
    if (d == 0)
        bkv[kv * 256 + m] = red[0] + red[1] + red[2] + red[3] + aib[(kv + 1) * 256 + m];
}

// ---------------------------------------------------------------------------
// M_c = tow_c^T @ bpw_c (bilinear fold); emit bf16 directly
// layout: MCATb[(cc*256 + t)*256 + k] = M_c[t,k]
// ---------------------------------------------------------------------------
__global__ __launch_bounds__(256) void mcat_kernel(const float* __restrict__ tow,
                                                   const float* __restrict__ bpw,
                                                   u16* __restrict__ MCATb) {
    const int cc = blockIdx.z;
    const int t0 = blockIdx.x * 16, k0 = blockIdx.y * 16;
    const int lt = threadIdx.x & 15, lj = threadIdx.x >> 4;
    const int ot = threadIdx.x & 15, ok = threadIdx.x >> 4;
    __shared__ float As[16][17], Bs[16][17];
    float acc = 0.f;
    for (int j0 = 0; j0 < 256; j0 += 16) {
        As[lj][lt] = tow[((size_t)cc * 256 + j0 + lj) * 256 + t0 + lt];
        Bs[lj][lt] = bpw[((size_t)cc * 256 + j0 + lj) * 256 + k0 + lt];
        __syncthreads();
#pragma unroll
        for (int jj = 0; jj < 16; jj++) acc += As[jj][ot] * Bs[jj][ok];
        __syncthreads();
    }
    MCATb[((size_t)cc * 256 + t0 + ot) * 256 + k0 + ok] = f2b(acc);
}

__global__ __launch_bounds__(256) void uvs_kernel(
    const float* __restrict__ tow, const float* __restrict__ tob,
    const float* __restrict__ bpw, const float* __restrict__ bpb,
    float* __restrict__ U, float* __restrict__ V, float* __restrict__ S) {
    const int cc = blockIdx.x, t = threadIdx.x;
    float v = 0.f, u = 0.f;
    for (int r = 0; r < 256; r++) {
        v += tow[((size_t)cc * 256 + r) * 256 + t] * bpb[cc * 256 + r];
        u += bpw[((size_t)cc * 256 + r) * 256 + t] * tob[cc * 256 + r];
    }
    V[cc * 256 + t] = v;
    U[cc * 256 + t] = u;
    float sp = tob[cc * 256 + t] * bpb[cc * 256 + t];
#pragma unroll
    for (int m = 32; m >= 1; m >>= 1) sp += __shfl_xor(sp, m);
    __shared__ float red[4];
    if ((t & 63) == 0) red[t >> 6] = sp;
    __syncthreads();
    if (t == 0) S[cc] = red[0] + red[1] + red[2] + red[3];
}

// ---------------------------------------------------------------------------
// counting-sort of queries by IDX (512 buckets) -> perm ; by comp (3) -> perm2
// ---------------------------------------------------------------------------
__global__ __launch_bounds__(256) void hist_kernel(const int* __restrict__ IDX,
                                                   const int* __restrict__ c,
                                                   int* __restrict__ cnt,
                                                   int* __restrict__ cnt3) {
    int n = blockIdx.x * 256 + threadIdx.x;
    if (n < NQ) {
        atomicAdd(&cnt[IDX[n]], 1);
        atomicAdd(&cnt3[c[n]], 1);
    }
}
// scan over IDX buckets; tail (t==0): comp bases, seldot block descriptors.
// BLK[b] = (comp<<16)|rowStart ; -1 sentinel. SEG[4] = comp segment bounds.
__global__ __launch_bounds__(512) void scan_kernel(const int* __restrict__ cnt,
                                                   int* __restrict__ base,
                                                   int* __restrict__ cur,
                                                   const int* __restrict__ cnt3,
                                                   int* __restrict__ cur3,
                                                   int* __restrict__ SEG,
                                                   int* __restrict__ BLK) {
    __shared__ int s[TT];
    int t = threadIdx.x;
    int v = cnt[t];
    s[t] = v;
    __syncthreads();
    for (int off = 1; off < TT; off <<= 1) {
        int add = (t >= off) ? s[t - off] : 0;
        __syncthreads();
        s[t] += add;
        __syncthreads();
    }
    base[t] = s[t] - v;
    cur[t] = s[t] - v;
    if (t == 0) {
        int b0 = cnt3[0], b1 = cnt3[1], b2 = cnt3[2];
        SEG[0] = 0; SEG[1] = b0; SEG[2] = b0 + b1; SEG[3] = b0 + b1 + b2;
        cur3[0] = SEG[0]; cur3[1] = SEG[1]; cur3[2] = SEG[2];
        int bidx = 0;
        for (int g = 0; g < 3; g++) {
            int cntg = cnt3[g];
            int tiles = (cntg + 63) >> 6;
            for (int tl = 0; tl < tiles; tl++)
                BLK[bidx++] = (g << 16) | (SEG[g] + tl * 64);
        }
        for (; bidx < 131; bidx++) BLK[bidx] = -1;
    }
}
__global__ __launch_bounds__(256) void scat_kernel(const int* __restrict__ IDX,
                                                   const int* __restrict__ c,
                                                   int* __restrict__ cur,
                                                   int* __restrict__ cur3,
                                                   int* __restrict__ perm,
                                                   int* __restrict__ perm2) {
    int n = blockIdx.x * 256 + threadIdx.x;
    if (n < NQ) {
        int pos = atomicAdd(&cur[IDX[n]], 1);
        perm[pos] = n;
        int pos2 = atomicAdd(&cur3[c[n]], 1);
        perm2[pos2] = n;
    }
}

// ---------------------------------------------------------------------------
// mgemm_b: MFMA bf16 GEMM (KV path). A fp32 (converted on the fly), W bf16.
// ---------------------------------------------------------------------------
template <int ST16>
__global__ __launch_bounds__(256) void mgemm_b(
    const float* __restrict__ A, const u16* __restrict__ Wb,
    const float* __restrict__ bias, void* __restrict__ Cv, int ldc) {
    __shared__ u16 As[64 * 40];
    __shared__ u16 Ws[64 * 40];
    const int t = threadIdx.x;
    const size_t rb = (size_t)blockIdx.x * 64;
    const size_t cb = (size_t)blockIdx.y * 64;
    const int wave = t >> 6, lane = t & 63;
    const int m16 = lane & 15, quad = lane >> 4;
    const int sr = t >> 2, sk = (t & 3) * 8;
    const float* Ap = A + (rb + sr) * 256 + sk;
    const u16* Wp = Wb + (cb + sr) * 256 + sk;

    f32x4 acc[4] = {};
    for (int k0 = 0; k0 < 256; k0 += 32) {
        float4 a0 = *(const float4*)(Ap + k0);
        float4 a1 = *(const float4*)(Ap + k0 + 4);
        u16 ta[8] = {f2b(a0.x), f2b(a0.y), f2b(a0.z), f2b(a0.w),
                     f2b(a1.x), f2b(a1.y), f2b(a1.z), f2b(a1.w)};
        *(uint4*)&As[sr * 40 + sk] = *(const uint4*)ta;
        *(uint4*)&Ws[sr * 40 + sk] = *(const uint4*)(Wp + k0);
        __syncthreads();
        s16x8 af = *(const s16x8*)&As[(wave * 16 + m16) * 40 + quad * 8];
#pragma unroll
        for (int ct = 0; ct < 4; ct++) {
            s16x8 bf = *(const s16x8*)&Ws[(ct * 16 + m16) * 40 + quad * 8];
            acc[ct] = __builtin_amdgcn_mfma_f32_16x16x32_bf16(af, bf, acc[ct], 0, 0, 0);
        }
        __syncthreads();
    }
#pragma unroll
    for (int ct = 0; ct < 4; ct++) {
        size_t col = cb + ct * 16 + m16;
        float bb = bias ? bias[col] : 0.f;
#pragma unroll
        for (int r = 0; r < 4; r++) {
            size_t row = rb + wave * 16 + quad * 4 + r;
            float x = acc[ct][r] + bb;
            if (ST16) {
                ((u16*)Cv)[row * (size_t)ldc + col] = f2b(x);
            } else {
                ((float*)Cv)[row * (size_t)ldc + col] = x;
            }
        }
    }
}

// ---------------------------------------------------------------------------
// seldot: component-grouped H-GEMM + fused final dot.
// One block = 64 perm2-consecutive rows (component-uniform, clamped dup rows
// at segment tails compute identical values -> benign duplicate writes).
// Computes H[row, 0..255] = C2[row] @ M_g^T in acc[16] (never stored), then
// out[n] = (sum_col F*(H+v_g) + u_g*C2 + s_g) * exp(lt)*cs_g + cb_g.
// __launch_bounds__(256,1): full VGPR headroom (acc[16]=64 VGPR), grid<=130
// blocks < 256 CUs so occupancy is irrelevant -> avoids R4-R6 spill mode.
// ---------------------------------------------------------------------------
__global__ __launch_bounds__(256, 1) void seldot_kernel(
    const float* __restrict__ C2, const float* __restrict__ F,
    const u16* __restrict__ MC, const int* __restrict__ BLK,
    const int* __restrict__ SEG, const int* __restrict__ perm2,
    const float* __restrict__ Ub, const float* __restrict__ Vb,
    const float* __restrict__ Sb, const float* __restrict__ lt,
    const float* __restrict__ cs, const float* __restrict__ cbv,
    float* __restrict__ out) {
    const int bd = BLK[blockIdx.x];
    if (bd < 0) return;
    const int g = bd >> 16, rowStart = bd & 0xFFFF;
    __shared__ u16 As[64 * 40];
    __shared__ u16 Ws[256 * 40];
    __shared__ int rowIdx[64];
    __shared__ float vS[256], uS[256];
    const int t = threadIdx.x;
    const int wave = t >> 6, lane = t & 63;
    const int m16 = lane & 15, quad = lane >> 4;
    const int sr = t >> 2, sk = (t & 3) * 8;
    if (t < 64) {
        int pos = rowStart + t;
        int segEnd = SEG[g + 1];
        if (pos >= segEnd) pos = segEnd - 1;
        rowIdx[t] = perm2[pos];
    }
    vS[t] = Vb[g * 256 + t];
    uS[t] = Ub[g * 256 + t];
    __syncthreads();

    const float* Ap = C2 + (size_t)rowIdx[sr] * 256 + sk;
    const u16* Wp = MC + (size_t)g * 65536;
    f32x4 acc[16];
#pragma unroll
    for (int i = 0; i < 16; i++) acc[i] = (f32x4){0.f, 0.f, 0.f, 0.f};

    for (int k0 = 0; k0 < 256; k0 += 32) {
        float4 a0 = *(const float4*)(Ap + k0);
        float4 a1 = *(const float4*)(Ap + k0 + 4);
        u16 ta[8] = {f2b(a0.x), f2b(a0.y), f2b(a0.z), f2b(a0.w),
                     f2b(a1.x), f2b(a1.y), f2b(a1.z), f2b(a1.w)};
        *(uint4*)&As[sr * 40 + sk] = *(const uint4*)ta;
#pragma unroll
        for (int wr = 0; wr < 4; wr++)
            *(uint4*)&Ws[(wr * 64 + sr) * 40 + sk] =
                *(const uint4*)(Wp + (size_t)(wr * 64 + sr) * 256 + k0 + sk);
        __syncthreads();
        s16x8 af = *(const s16x8*)&As[(wave * 16 + m16) * 40 + quad * 8];
#pragma unroll
        for (int ct = 0; ct < 16; ct++) {
            s16x8 bf = *(const s16x8*)&Ws[(ct * 16 + m16) * 40 + quad * 8];
            acc[ct] = __builtin_amdgcn_mfma_f32_16x16x32_bf16(af, bf, acc[ct], 0, 0, 0);
        }
        __syncthreads();
    }

    // fused dot epilogue
    float tot[4] = {0.f, 0.f, 0.f, 0.f};
#pragma unroll
    for (int ct = 0; ct < 16; ct++) {
        const int col = ct * 16 + m16;
        const float vv = vS[col], uu = uS[col];
#pragma unroll
        for (int r = 0; r < 4; r++) {
            const int row = wave * 16 + quad * 4 + r;
            const size_t nb = (size_t)rowIdx[row] * 256 + col;
            tot[r] += F[nb] * (acc[ct][r] + vv) + uu * C2[nb];
        }
    }
    const float scale = expf(lt[0]) * cs[g];
    const float sg = Sb[g], cbg = cbv[g];
#pragma unroll
    for (int r = 0; r < 4; r++) {
        float s = tot[r];
        s += __shfl_xor(s, 1);
        s += __shfl_xor(s, 2);
        s += __shfl_xor(s, 4);
        s += __shfl_xor(s, 8);
        if (m16 == 0) {
            const int n = rowIdx[wave * 16 + quad * 4 + r];
            out[n] = (s + sg) * scale + cbg;
        }
    }
}

// ---------------------------------------------------------------------------
// Fused chain machinery, v3: 1024 threads (16 waves), 32 rows, wave owns one
// 16-col tile. wload() preloads ALL B-fragments of a GEMM phase into a
// register array so the 16 weight loads issue back-to-back -> ONE latency
// exposure per phase. (Best-known config: 321.7 us. MCAT-fold-into-chain
// variants R4-R6 all hit an unfixable 64-VGPR spill signature -> reverted;
// SEL+dot now live in the standalone seldot_kernel instead.)
// MFMA order is numerics-defining: split x3 (ah*bh + al*bh + ah*bl).
// ---------------------------------------------------------------------------
template <int NK0>
struct WF { s16x8 h[NK0], l[NK0]; };

template <int NK0>
__device__ __forceinline__ void wload(const u16* __restrict__ PH,
                                      const u16* __restrict__ PL, size_t mb,
                                      int wave, int lane, WF<NK0>& w) {
#pragma unroll
    for (int k0 = 0; k0 < NK0; k0++) {
        const size_t wo = mb + ((size_t)(wave * NK0 + k0) * 64 + lane) * 8;
        w.h[k0] = *(const s16x8*)&PH[wo];
        w.l[k0] = *(const s16x8*)&PL[wo];
    }
}

template <int NK0>
__device__ __forceinline__ void cgemm_c(const WF<NK0>& w,
                                        const u16* Ch, const u16* Cl,
                                        int lane, f32x4 (&acc)[2]) {
    acc[0] = (f32x4){0.f, 0.f, 0.f, 0.f};
    acc[1] = (f32x4){0.f, 0.f, 0.f, 0.f};
#pragma unroll
    for (int k0 = 0; k0 < NK0; k0++) {
        s16x8 a0h = *(const s16x8*)&Ch[(k0 * 64 + lane) * 8];
        s16x8 a0l = *(const s16x8*)&Cl[(k0 * 64 + lane) * 8];
        s16x8 a1h = *(const s16x8*)&Ch[((8 + k0) * 64 + lane) * 8];
        s16x8 a1l = *(const s16x8*)&Cl[((8 + k0) * 64 + lane) * 8];
        acc[0] = __builtin_amdgcn_mfma_f32_16x16x32_bf16(a0h, w.h[k0], acc[0], 0, 0, 0);
        acc[0] = __builtin_amdgcn_mfma_f32_16x16x32_bf16(a0l, w.h[k0], acc[0], 0, 0, 0);
        acc[0] = __builtin_amdgcn_mfma_f32_16x16x32_bf16(a0h, w.l[k0], acc[0], 0, 0, 0);
        acc[1] = __builtin_amdgcn_mfma_f32_16x16x32_bf16(a1h, w.h[k0], acc[1], 0, 0, 0);
        acc[1] = __builtin_amdgcn_mfma_f32_16x16x32_bf16(a1l, w.h[k0], acc[1], 0, 0, 0);
        acc[1] = __builtin_amdgcn_mfma_f32_16x16x32_bf16(a1h, w.l[k0], acc[1], 0, 0, 0);
    }
}

// LN over Fv -> packed split Ch/Cl. Phase A: 32 threads/row compute stats.
// Phase B (transposed): each thread normalizes one 8-col chunk, writes uint4.
__device__ __forceinline__ void ln_split(const float* __restrict__ Fv,
                                         u16* __restrict__ Ch, u16* __restrict__ Cl,
                                         const float* __restrict__ g,
                                         const float* __restrict__ b,
                                         float* __restrict__ mean_s,
                                         float* __restrict__ rstd_s, int t) {
    {
        const int row = t >> 5, q = t & 31;
        const float* fr = Fv + row * LDF;
        float4 v0 = *(const float4*)&fr[q * 4];
        float4 v1 = *(const float4*)&fr[q * 4 + 128];
        float s1 = v0.x + v0.y + v0.z + v0.w + v1.x + v1.y + v1.z + v1.w;
        float s2 = v0.x * v0.x + v0.y * v0.y + v0.z * v0.z + v0.w * v0.w +
                   v1.x * v1.x + v1.y * v1.y + v1.z * v1.z + v1.w * v1.w;
#pragma unroll
        for (int m = 16; m >= 1; m >>= 1) {
            s1 += __shfl_xor(s1, m);
            s2 += __shfl_xor(s2, m);
        }
        if (q == 0) {
            float mean = s1 * (1.f / 256.f);
            mean_s[row] = mean;
            rstd_s[row] = rsqrtf(s2 * (1.f / 256.f) - mean * mean + 1e-5f);
        }
    }
    __syncthreads();
    {
        const int rw = t & 31, qc = t >> 5;
        const float* fr = Fv + rw * LDF + qc * 8;
        float4 v0 = *(const float4*)fr;
        float4 v1 = *(const float4*)(fr + 4);
        const float mean = mean_s[rw], rstd = rstd_s[rw];
        float4 g0 = *(const float4*)&g[qc * 8], g1 = *(const float4*)&g[qc * 8 + 4];
        float4 b0 = *(const float4*)&b[qc * 8], b1 = *(const float4*)&b[qc * 8 + 4];
        float va[8] = {v0.x, v0.y, v0.z, v0.w, v1.x, v1.y, v1.z, v1.w};
        float ga[8] = {g0.x, g0.y, g0.z, g0.w, g1.x, g1.y, g1.z, g1.w};
        float ba[8] = {b0.x, b0.y, b0.z, b0.w, b1.x, b1.y, b1.z, b1.w};
        u16 hv[8], lv[8];
#pragma unroll
        for (int j = 0; j < 8; j++) {
            float x = (va[j] - mean) * rstd * ga[j] + ba[j];
            hv[j] = f2b(x);
            lv[j] = f2b(x - b2f(hv[j]));
        }
        const int c = qc * 8;
        const int off = (((rw >> 4) * 8 + (c >> 5)) * 64 +
                         (((c >> 3) & 3) * 16 + (rw & 15))) * 8;
        *(uint4*)&Ch[off] = *(const uint4*)hv;
        *(uint4*)&Cl[off] = *(const uint4*)lv;
    }
}

// ---------------------------------------------------------------------------
// chain1: trunk_in -> [LN,fc1,fc2] x2 -> (F to global) -> LN -> q-proj
// ---------------------------------------------------------------------------
__global__ __launch_bounds__(1024) void chain1_kernel(
    const float* __restrict__ FIN, const u16* __restrict__ PH,
    const u16* __restrict__ PL, const float* __restrict__ tib,
    const float* __restrict__ lng, const float* __restrict__ lnb,
    const float* __restrict__ f1b, const float* __restrict__ f2bv,
    const float* __restrict__ bng, const float* __restrict__ bnb,
    const float* __restrict__ aib,
    float* __restrict__ Qb, float* __restrict__ Fg) {
    __shared__ u16 Ch[8192], Cl[8192];
    __shared__ float Fv[32 * LDF];
    __shared__ float mean_s[32], rstd_s[32];
    const int t = threadIdx.x;
    const int wave = t >> 6, lane = t & 63;
    const int m16 = lane & 15, quad = lane >> 4;
    const size_t rb = (size_t)blockIdx.x * 32;
    const int col = wave * 16 + m16;
    f32x4 acc[2];

    // phase 0: FIN [32,160] -> split packed
    {
        const int row = t >> 5, q = t & 31;
        if (q < 20) {
            const float* p = FIN + (rb + row) * 160 + q * 8;
            float4 v0 = *(const float4*)p, v1 = *(const float4*)(p + 4);
            float va[8] = {v0.x, v0.y, v0.z, v0.w, v1.x, v1.y, v1.z, v1.w};
            u16 hv[8], lv[8];
#pragma unroll
            for (int j = 0; j < 8; j++) { hv[j] = f2b(va[j]); lv[j] = f2b(va[j] - b2f(hv[j])); }
            const int c = q * 8;
            const int off = (((row >> 4) * 8 + (c >> 5)) * 64 +
                             (((c >> 3) & 3) * 16 + (row & 15))) * 8;
            *(uint4*)&Ch[off] = *(const uint4*)hv;
            *(uint4*)&Cl[off] = *(const uint4*)lv;
        }
    }

    // trunk_in (K=160): silu -> Fv
    {
        WF<5> w;
        wload<5>(PH, PL, 524288, wave, lane, w);
        __syncthreads();
        cgemm_c<5>(w, Ch, Cl, lane, acc);
    }
    {
        const float bb = tib[col];
#pragma unroll
        for (int rt = 0; rt < 2; rt++)
#pragma unroll
            for (int r = 0; r < 4; r++)
                Fv[(rt * 16 + quad * 4 + r) * LDF + col] = silu_f(acc[rt][r] + bb);
    }
    __syncthreads();

    // two residual blocks
#pragma unroll
    for (int L = 0; L < 2; L++) {
        ln_split(Fv, Ch, Cl, lng + L * 256, lnb + L * 256, mean_s, rstd_s, t);
        {
            WF<8> w;
            wload<8>(PH, PL, (size_t)L * 65536, wave, lane, w);  // fc1
            __syncthreads();
            cgemm_c<8>(w, Ch, Cl, lane, acc);
        }
        __syncthreads();
        {
            const float bb = f1b[L * 256 + col];
            const int k0c = col >> 5, qc4 = (col >> 3) & 3, jc = col & 7;
#pragma unroll
            for (int rt = 0; rt < 2; rt++)
#pragma unroll
                for (int r = 0; r < 4; r++) {
                    const int row = rt * 16 + quad * 4 + r;
                    float x = silu_f(acc[rt][r] + bb);
                    const int off = ((rt * 8 + k0c) * 64 + (qc4 * 16 + (row & 15))) * 8 + jc;
                    u16 h = f2b(x);
                    Ch[off] = h;
                    Cl[off] = f2b(x - b2f(h));
                }
        }
        {
            WF<8> w;
            wload<8>(PH, PL, 131072 + (size_t)L * 65536, wave, lane, w);  // fc2
            __syncthreads();
            cgemm_c<8>(w, Ch, Cl, lane, acc);
        }
        {
            const float bb = f2bv[L * 256 + col];
#pragma unroll
            for (int rt = 0; rt < 2; rt++)
#pragma unroll
                for (int r = 0; r < 4; r++) {
                    const int row = rt * 16 + quad * 4 + r;
                    Fv[row * LDF + col] += acc[rt][r] + bb;
                }
        }
        __syncthreads();
    }

    // F -> global ; LN(bn) -> packed C
    {
        const int row = t >> 5, q = t & 31;
        const float* fr = Fv + row * LDF + q * 8;
        float4 v0 = *(const float4*)fr, v1 = *(const float4*)(fr + 4);
        float* dst = Fg + (rb + row) * 256 + q * 8;
        *(float4*)dst = v0;
        *(float4*)(dst + 4) = v1;
    }
    ln_split(Fv, Ch, Cl, bng, bnb, mean_s, rstd_s, t);

    // q projection -> Qb global
    {
        WF<8> w;
        wload<8>(PH, PL, 262144, wave, lane, w);
        __syncthreads();
        cgemm_c<8>(w, Ch, Cl, lane, acc);
    }
    {
        const float bb = aib[col];
#pragma unroll
        for (int rt = 0; rt < 2; rt++)
#pragma unroll
            for (int r = 0; r < 4; r++) {
                const int row = rt * 16 + quad * 4 + r;
                Qb[(rb + row) * 256 + col] = acc[rt][r] + bb;
            }
    }
}

// ---------------------------------------------------------------------------
// chain2: attn_out -> LN -> bc1(silu) -> bc2(+res) -> C2 global
// ---------------------------------------------------------------------------
__global__ __launch_bounds__(1024) void chain2_kernel(
    const float* __restrict__ CTX, const u16* __restrict__ PH,
    const u16* __restrict__ PL, const float* __restrict__ aob,
    const float* __restrict__ clg, const float* __restrict__ clb,
    const float* __restrict__ b1, const float* __restrict__ b2v,
    float* __restrict__ C2g) {
    __shared__ u16 Ch[8192], Cl[8192];
    __shared__ float Fv[32 * LDF];
    __shared__ float mean_s[32], rstd_s[32];
    const int t = threadIdx.x;
    const int wave = t >> 6, lane = t & 63;
    const int m16 = lane & 15, quad = lane >> 4;
    const size_t rb = (size_t)blockIdx.x * 32;
    const int col = wave * 16 + m16;
    f32x4 acc[2];

    // phase 0: CTX -> split packed
    {
        const int row = t >> 5, q = t & 31;
        const float* p = CTX + (rb + row) * 256 + q * 8;
        float4 v0 = *(const float4*)p, v1 = *(const float4*)(p + 4);
        float va[8] = {v0.x, v0.y, v0.z, v0.w, v1.x, v1.y, v1.z, v1.w};
        u16 hv[8], lv[8];
#pragma unroll
        for (int j = 0; j < 8; j++) { hv[j] = f2b(va[j]); lv[j] = f2b(va[j] - b2f(hv[j])); }
        const int c = q * 8;
        const int off = (((row >> 4) * 8 + (c >> 5)) * 64 +
                         (((c >> 3) & 3) * 16 + (row & 15))) * 8;
        *(uint4*)&Ch[off] = *(const uint4*)hv;
        *(uint4*)&Cl[off] = *(const uint4*)lv;
    }

    // attn_out -> Fv
    {
        WF<8> w;
        wload<8>(PH, PL, 327680, wave, lane, w);
        __syncthreads();
        cgemm_c<8>(w, Ch, Cl, lane, acc);
    }
    {
        const float bb = aob[col];
#pragma unroll
        for (int rt = 0; rt < 2; rt++)
#pragma unroll
            for (int r = 0; r < 4; r++)
                Fv[(rt * 16 + quad * 4 + r) * LDF + col] = acc[rt][r] + bb;
    }
    __syncthreads();

    ln_split(Fv, Ch, Cl, clg, clb, mean_s, rstd_s, t);
    {
        WF<8> w;
        wload<8>(PH, PL, 393216, wave, lane, w);  // bc1
        __syncthreads();
        cgemm_c<8>(w, Ch, Cl, lane, acc);
    }
    __syncthreads();
    {
        const float bb = b1[col];
        const int k0c = col >> 5, qc4 = (col >> 3) & 3, jc = col & 7;
#pragma unroll
        for (int rt = 0; rt < 2; rt++)
#pragma unroll
            for (int r = 0; r < 4; r++) {
                const int row = rt * 16 + quad * 4 + r;
                float x = silu_f(acc[rt][r] + bb);
                const int off = ((rt * 8 + k0c) * 64 + (qc4 * 16 + (row & 15))) * 8 + jc;
                u16 h = f2b(x);
                Ch[off] = h;
                Cl[off] = f2b(x - b2f(h));
            }
    }
    {
        WF<8> w;
        wload<8>(PH, PL, 458752, wave, lane, w);  // bc2
        __syncthreads();
        cgemm_c<8>(w, Ch, Cl, lane, acc);
    }
    {
        const float bb = b2v[col];
#pragma unroll
        for (int rt = 0; rt < 2; rt++)
#pragma unroll
            for (int r = 0; r < 4; r++) {
                const int row = rt * 16 + quad * 4 + r;
                C2g[(rb + row) * 256 + col] = acc[rt][r] + bb + Fv[row * LDF + col];
            }
    }
}

// ---------------------------------------------------------------------------
// attn4: one block per query (perm-ordered). KV interleaved [16384,512] bf16.
// In-place Qb -> CTX.
// ---------------------------------------------------------------------------
__global__ __launch_bounds__(256) void attn4_kernel(
    float* __restrict__ QC, const u16* __restrict__ KV,
    const int* __restrict__ idx, const int* __restrict__ perm) {
    __shared__ u16 vsh[STOK * 264];
    __shared__ float qsh[256], attw[4][STOK];
    const int n = perm[blockIdx.x];
    const int t = threadIdx.x;
    qsh[t] = QC[(size_t)n * 256 + t];
    int ii = idx[n];
    ii = ii < 0 ? 0 : (ii > TT - 1 ? TT - 1 : ii);
    const u16* kvb = KV + (size_t)ii * STOK * 512;
#pragma unroll
    for (int i = t; i < 1024; i += 256) {
        int s = i >> 5, dq = (i & 31) * 8;
        *(uint4*)&vsh[s * 264 + dq] = *(const uint4*)&kvb[(size_t)s * 512 + 256 + dq];
    }
    __syncthreads();
    if (t < 128) {
        int h = t >> 5, s = t & 31;
        const u16* kp = kvb + (size_t)s * 512 + h * 64;
        uint4 kv[8];
#pragma unroll
        for (int dq = 0; dq < 8; dq++) kv[dq] = *(const uint4*)(kp + dq * 8);
        float p0 = 0.f, p1 = 0.f;
#pragma unroll
        for (int dq = 0; dq < 8; dq++) {
            const u16* ks = (const u16*)&kv[dq];
            float a0 = 0.f;
#pragma unroll
            for (int j = 0; j < 8; j++) a0 += qsh[h * 64 + dq * 8 + j] * b2f(ks[j]);
            if (dq & 1) p1 += a0; else p0 += a0;
        }
        float sc = (p0 + p1) * 0.125f;
        float mx = sc;
#pragma unroll
        for (int m = 16; m >= 1; m >>= 1) mx = fmaxf(mx, __shfl_xor(mx, m));
        float e = expf(sc - mx);
        float sum = e;
#pragma unroll
        for (int m = 16; m >= 1; m >>= 1) sum += __shfl_xor(sum, m);
        attw[h][s] = e / sum;
    }
    __syncthreads();
    {
        int h = t >> 6;
        float a = 0.f;
#pragma unroll 8
        for (int s = 0; s < STOK; s++) a += attw[h][s] * b2f(vsh[s * 264 + t]);
        QC[(size_t)n * 256 + t] = a;
    }
}

// ---------------------------------------------------------------------------
extern "C" void kernel_launch(void* const* d_in, const int* in_sizes, int n_in,
                              void* d_out, int out_size, void* d_ws, size_t ws_size,
                              hipStream_t stream) {
    float* out = (float*)d_out;
    const dim3 blk(256);

    static const int EXPECT[38] = {
        16384, 8192, 8192, 4194304, 512, 128, 16, 16, 24,
        38912, 256, 512, 512, 131072, 512, 131072, 512,
        65536, 256, 256, 256, 196608, 768, 65536, 256,
        256, 256, 65536, 256, 65536, 256, 196608, 768,
        196608, 768, 1, 3, 3};
    if (n_in != 38) { const_kernel<<<NQ / 256, blk, 0, stream>>>(99.0e6f, out); return; }
    for (int i = 0; i < 38; i++)
        if (in_sizes[i] != EXPECT[i]) {
            const_kernel<<<NQ / 256, blk, 0, stream>>>((100.0f + i) * 1.0e6f, out);
            return;
        }

    const float* xy  = (const float*)d_in[0];
    const float* tq  = (const float*)d_in[1];
    const int*   c   = (const int*)d_in[2];
    const float* hs  = (const float*)d_in[3];
    const float* st  = (const float*)d_in[4];
    const float* Bm  = (const float*)d_in[5];
    const float* tw  = (const float*)d_in[6];
    const float* tbv = (const float*)d_in[7];
    const float* ce  = (const float*)d_in[8];
    const float* tiw = (const float*)d_in[9];
    const float* tib = (const float*)d_in[10];
    const float* lng = (const float*)d_in[11];
    const float* lnb = (const float*)d_in[12];
    const float* f1w = (const float*)d_in[13];
    const float* f1b = (const float*)d_in[14];
    const float* f2w = (const float*)d_in[15];
    const float* f2b_ = (const float*)d_in[16];
    const float* btw = (const float*)d_in[17];
    const float* btb = (const float*)d_in[18];
    const float* bng = (const float*)d_in[19];
    const float* bnb = (const float*)d_in[20];
    const float* aiw = (const float*)d_in[21];
    const float* aib = (const float*)d_in[22];
    const float* aow = (const float*)d_in[23];
    const float* aob = (const float*)d_in[24];
    const float* clg = (const float*)d_in[25];
    const float* clb = (const float*)d_in[26];
    const float* w1  = (const float*)d_in[27];
    const float* b1  = (const float*)d_in[28];
    const float* w2  = (const float*)d_in[29];
    const float* b2  = (const float*)d_in[30];
    const float* tow = (const float*)d_in[31];
    const float* tob = (const float*)d_in[32];
    const float* bpw = (const float*)d_in[33];
    const float* bpb = (const float*)d_in[34];
    const float* lt  = (const float*)d_in[35];
    const float* cs  = (const float*)d_in[36];
    const float* cbv = (const float*)d_in[37];

    char* ws = (char*)d_ws;
    const size_t MB = 1 << 20;
    if (ws_size < 44 * MB) {
        const_kernel<<<NQ / 256, blk, 0, stream>>>(8.0e6f, out);
        return;
    }

    // KV interleaved [16384,512] bf16 = 16 MB at [0,16). Slots 8 MB each.
    u16*   KV   = (u16*)(ws + 0 * MB);
    char*  S_A  = ws + 16 * MB;   // FIN
    char*  S_B  = ws + 24 * MB;   // F (trunk state, written once by chain1)
    char*  S_C  = ws + 32 * MB;   // Qb -> CTX (attn in-place) -> C2 (in-place)
    char*  misc = ws + 40 * MB;
    float* FIN  = (float*)S_A;
    float* F    = (float*)S_B;
    float* Qb   = (float*)S_C;
    float* C2   = (float*)S_C;
    int*   IDX  = (int*)(misc + 0);                   // 32KB
    float* bkv  = (float*)(misc + 32 * 1024);         // 4KB
    float* Ubuf = (float*)(misc + 36 * 1024);
    float* Vbuf = (float*)(misc + 40 * 1024);
    float* Sbuf = (float*)(misc + 44 * 1024);
    int*   CNT  = (int*)(misc + 48 * 1024);
    int*   BASE = (int*)(misc + 52 * 1024);
    int*   CUR  = (int*)(misc + 56 * 1024);
    int*   PERM = (int*)(misc + 60 * 1024);           // 32KB -> 92K
    u16*   WKVb = (u16*)(misc + 92 * 1024);           // [512,256] 256KB -> 348K
    u16*   MCATb= (u16*)(misc + 348 * 1024);          // [768,256] 384KB -> 732K
    u16*   PH   = (u16*)(misc + 732 * 1024);          // packed hi 1104KB -> 1836K
    u16*   PL   = (u16*)(misc + 1836 * 1024);         // packed lo 1104KB -> 2940K
    int*   PERM2= (int*)(misc + 2940 * 1024);         // 32KB -> 2972K
    int*   CNT3 = (int*)(misc + 2972 * 1024);         // 3 ints
    int*   CUR3 = (int*)(misc + 2972 * 1024 + 16);    // 3 ints
    int*   SEG  = (int*)(misc + 2972 * 1024 + 32);    // 4 ints
    int*   BLK  = (int*)(misc + 2972 * 1024 + 64);    // 131 ints

    const dim3 gKV(TT * STOK / 64, 8);   // M=16384, N=512

    // ---- prep (input-only) ----
    zero_kernel<<<3, blk, 0, stream>>>(CNT, CNT3);
    pack_split<<<2208, blk, 0, stream>>>(f1w, f2w, aiw, aow, w1, w2, tiw, PH, PL);
    combine_kv32<<<512, blk, 0, stream>>>(aiw, aib, btw, btb, WKVb, bkv);
    mcat_kernel<<<dim3(16, 16, 3), blk, 0, stream>>>(tow, bpw, MCATb);
    uvs_kernel<<<3, blk, 0, stream>>>(tow, tob, bpw, bpb, Ubuf, Vbuf, Sbuf);
    feat32_kernel<<<NQ, blk, 0, stream>>>(xy, tq, c, st, Bm, tw, tbv, ce, FIN, IDX);

    // ---- sort queries by time index (perm) and component (perm2 + BLK) ----
    hist_kernel<<<NQ / 256, blk, 0, stream>>>(IDX, c, CNT, CNT3);
    scan_kernel<<<1, dim3(512), 0, stream>>>(CNT, BASE, CUR, CNT3, CUR3, SEG, BLK);
    scat_kernel<<<NQ / 256, blk, 0, stream>>>(IDX, c, CUR, CUR3, PERM, PERM2);

    // ---- K/V (single merged GEMM, bf16 interleaved output) ----
    mgemm_b<1><<<gKV, blk, 0, stream>>>(hs, WKVb, bkv, KV, 512);

    // ---- fused trunk chain: 6 GEMMs in one dispatch, 16 waves/block ----
    chain1_kernel<<<NQ / 32, dim3(1024), 0, stream>>>(FIN, PH, PL, tib, lng, lnb,
                                                      f1b, f2b_, bng, bnb, aib, Qb, F);
    // ---- attention ----
    attn4_kernel<<<NQ, blk, 0, stream>>>(Qb, KV, IDX, PERM);
    // ---- fused post chain ----
    chain2_kernel<<<NQ / 32, dim3(1024), 0, stream>>>(Qb, PH, PL, aob, clg, clb,
                                                      b1, b2, C2);
    // ---- component-grouped SEL GEMM + fused final dot -> out ----
    seldot_kernel<<<131, blk, 0, stream>>>(C2, F, MCATb, BLK, SEG, PERM2,
                                           Ubuf, Vbuf, Sbuf, lt, cs, cbv, out);
}

// Round 9
// 325.015 us; speedup vs baseline: 1.2977x; 1.2977x over previous
//
#include <hip/hip_runtime.h>
#include <cstdint>
#include <cstddef>

typedef unsigned short u16;
typedef __attribute__((ext_vector_type(8))) short s16x8;
typedef __attribute__((ext_vector_type(4))) float f32x4;

#define NQ   8192
#define TT   512
#define STOK 32
#define LDF  260   // Fv row stride (floats): 256 + 4 pad -> bank rotation by 4/row

__device__ __forceinline__ float b2f(u16 u) {
    return __uint_as_float(((uint32_t)u) << 16);
}
__device__ __forceinline__ u16 f2b(float f) {
    uint32_t x = __float_as_uint(f);
    uint32_t r = (x + 0x7FFFu + ((x >> 16) & 1u)) >> 16;
    return (u16)r;
}
__device__ __forceinline__ float silu_f(float x) { return x / (1.f + expf(-x)); }

__global__ __launch_bounds__(256) void const_kernel(float v, float* __restrict__ out) {
    int i = blockIdx.x * 256 + threadIdx.x;
    if (i < NQ) out[i] = v;
}

// ---------------------------------------------------------------------------
// zero CNT[512] + CNT3[3]
// ---------------------------------------------------------------------------
__global__ __launch_bounds__(256) void zero_kernel(int* __restrict__ cnt,
                                                   int* __restrict__ cnt3) {
    int i = blockIdx.x * 256 + threadIdx.x;
    if (i < 512) cnt[i] = 0;
    if (i >= 512 && i < 515) cnt3[i - 512] = 0;
}

// ---------------------------------------------------------------------------
// features (verified): FIN fp32 [NQ,160] (cols 152..159 = 0), IDX
// ---------------------------------------------------------------------------
__global__ __launch_bounds__(256) void feat32_kernel(
    const float* __restrict__ xy, const float* __restrict__ t_q,
    const int* __restrict__ c, const float* __restrict__ st,
    const float* __restrict__ B, const float* __restrict__ tw,
    const float* __restrict__ tb, const float* __restrict__ ce,
    float* __restrict__ FIN, int* __restrict__ IDX) {
    int n = blockIdx.x, t = threadIdx.x;
    float tq = t_q[n];
    int lo = 0, hi = TT;
    while (lo < hi) {
        int mid = (lo + hi) >> 1;
        if (st[mid] <= tq) lo = mid + 1; else hi = mid;
    }
    int idx = lo - 1;
    if (idx < 0) idx = 0;
    float dt = tq - st[idx];
    if (dt < 0.f) dt = 0.f;
    if (t == 0) IDX[n] = idx;
    float x = xy[2 * n], y = xy[2 * n + 1];
    size_t base = (size_t)n * 160;
    if (t < 64) { float p = x * B[t] + y * B[64 + t]; FIN[base + t] = cosf(p); }
    else if (t < 128) { int j = t - 64; float p = x * B[j] + y * B[64 + j]; FIN[base + t] = sinf(p); }
    else if (t < 144) { int j = t - 128; FIN[base + t] = dt * tw[j] + tb[j]; }
    else if (t < 152) { int j = t - 144; FIN[base + t] = ce[c[n] * 8 + j]; }
    else if (t < 160) { FIN[base + t] = 0.f; }
}

// ---------------------------------------------------------------------------
// pack_split: all chain weights -> MFMA-fragment-linear bf16 hi/lo.
// pos = ((ct*NK0 + k0)*64 + quad*16 + m16)*8 + j   (ct=col>>4, NK0=K/32)
// Layout (u16 idx): m*65536 for m=0..7 = {f1w L0, f1w L1, f2w L0, f2w L1,
// wq, aow, w1, w2}; trunk_in (K=160, NK0=5, zero-padded cols>=152) at 524288.
// ---------------------------------------------------------------------------
__global__ __launch_bounds__(256) void pack_split(
    const float* __restrict__ f1w, const float* __restrict__ f2w,
    const float* __restrict__ aiw, const float* __restrict__ aow,
    const float* __restrict__ w1, const float* __restrict__ w2,
    const float* __restrict__ tiw,
    u16* __restrict__ PH, u16* __restrict__ PL) {
    int i = blockIdx.x * 256 + threadIdx.x;
    if (i >= 565248) return;
    float v;
    size_t pos;
    if (i < 524288) {
        int m = i >> 16, j = i & 65535;
        int col = j >> 8, k = j & 255;
        const float* src;
        switch (m) {
            case 0: src = f1w; break;
            case 1: src = f1w + 65536; break;
            case 2: src = f2w; break;
            case 3: src = f2w + 65536; break;
            case 4: src = aiw; break;          // wq = rows 0..255 of attn_in_w
            case 5: src = aow; break;
            case 6: src = w1; break;
            default: src = w2; break;
        }
        v = src[j];
        int ct = col >> 4, m16 = col & 15, k0 = k >> 5, quad = (k >> 3) & 3, jj = k & 7;
        pos = (size_t)m * 65536 + (size_t)(((ct * 8 + k0) * 64 + quad * 16 + m16) * 8 + jj);
    } else {
        int j = i - 524288;                    // 0..40959
        int col = j / 160, k = j % 160;
        v = (k < 152) ? tiw[col * 152 + k] : 0.f;
        int ct = col >> 4, m16 = col & 15, k0 = k >> 5, quad = (k >> 3) & 3, jj = k & 7;
        pos = 524288 + (size_t)(((ct * 5 + k0) * 64 + quad * 16 + m16) * 8 + jj);
    }
    u16 h = f2b(v);
    PH[pos] = h;
    PL[pos] = f2b(v - b2f(h));
}

// ---------------------------------------------------------------------------
// fold token projection into K/V weights; emit bf16 [512,256] + fp32 bias[512]
// ---------------------------------------------------------------------------
__global__ __launch_bounds__(256) void combine_kv32(
    const float* __restrict__ aiw, const float* __restrict__ aib,
    const float* __restrict__ btw, const float* __restrict__ btb,
    u16* __restrict__ WKVb, float* __restrict__ bkv) {
    int kv = blockIdx.x >> 8, m = blockIdx.x & 255;
    int d = threadIdx.x;
    __shared__ float wrow[256];
    wrow[d] = aiw[(size_t)(kv + 1) * 65536 + (size_t)m * 256 + d];
    __syncthreads();
    float acc = 0.f;
#pragma unroll 8
    for (int o = 0; o < 256; o++) acc += wrow[o] * btw[(size_t)o * 256 + d];
    WKVb[(size_t)kv * 65536 + (size_t)m * 256 + d] = f2b(acc);
    float pb = wrow[d] * btb[d];
#pragma unroll
    for (int mm = 32; mm >= 1; mm >>= 1) pb += __shfl_xor(pb, mm);
    __shared__ float red[4];
    if ((d & 63) == 0) red[d >> 6] = pb;
    __syncthreads();
    if (d == 0)
        bkv[kv * 256 + m] = red[0] + red[1] + red[2] + red[3] + aib[(kv + 1) * 256 + m];
}

// ---------------------------------------------------------------------------
// M_c = tow_c^T @ bpw_c (bilinear fold); emit bf16 directly
// layout: MCATb[(cc*256 + t)*256 + k] = M_c[t,k]
// ---------------------------------------------------------------------------
__global__ __launch_bounds__(256) void mcat_kernel(const float* __restrict__ tow,
                                                   const float* __restrict__ bpw,
                                                   u16* __restrict__ MCATb) {
    const int cc = blockIdx.z;
    const int t0 = blockIdx.x * 16, k0 = blockIdx.y * 16;
    const int lt = threadIdx.x & 15, lj = threadIdx.x >> 4;
    const int ot = threadIdx.x & 15, ok = threadIdx.x >> 4;
    __shared__ float As[16][17], Bs[16][17];
    float acc = 0.f;
    for (int j0 = 0; j0 < 256; j0 += 16) {
        As[lj][lt] = tow[((size_t)cc * 256 + j0 + lj) * 256 + t0 + lt];
        Bs[lj][lt] = bpw[((size_t)cc * 256 + j0 + lj) * 256 + k0 + lt];
        __syncthreads();
#pragma unroll
        for (int jj = 0; jj < 16; jj++) acc += As[jj][ot] * Bs[jj][ok];
        __syncthreads();
    }
    MCATb[((size_t)cc * 256 + t0 + ot) * 256 + k0 + ok] = f2b(acc);
}

__global__ __launch_bounds__(256) void uvs_kernel(
    const float* __restrict__ tow, const float* __restrict__ tob,
    const float* __restrict__ bpw, const float* __restrict__ bpb,
    float* __restrict__ U, float* __restrict__ V, float* __restrict__ S) {
    const int cc = blockIdx.x, t = threadIdx.x;
    float v = 0.f, u = 0.f;
    for (int r = 0; r < 256; r++) {
        v += tow[((size_t)cc * 256 + r) * 256 + t] * bpb[cc * 256 + r];
        u += bpw[((size_t)cc * 256 + r) * 256 + t] * tob[cc * 256 + r];
    }
    V[cc * 256 + t] = v;
    U[cc * 256 + t] = u;
    float sp = tob[cc * 256 + t] * bpb[cc * 256 + t];
#pragma unroll
    for (int m = 32; m >= 1; m >>= 1) sp += __shfl_xor(sp, m);
    __shared__ float red[4];
    if ((t & 63) == 0) red[t >> 6] = sp;
    __syncthreads();
    if (t == 0) S[cc] = red[0] + red[1] + red[2] + red[3];
}

// ---------------------------------------------------------------------------
// counting-sort of queries by IDX (512 buckets) -> perm ; by comp (3) -> perm2
// 3-bucket atomics are WAVE-AGGREGATED (__ballot + leader atomicAdd): the
// naive per-thread atomicAdd on 3 addresses serialized ~2700-deep and cost
// 55 us/dispatch in R8 (Guideline 12).
// ---------------------------------------------------------------------------
__global__ __launch_bounds__(256) void hist_kernel(const int* __restrict__ IDX,
                                                   const int* __restrict__ c,
                                                   int* __restrict__ cnt,
                                                   int* __restrict__ cnt3) {
    int n = blockIdx.x * 256 + threadIdx.x;
    int lane = threadIdx.x & 63;
    atomicAdd(&cnt[IDX[n]], 1);          // 512 buckets: contention fine
    int cc = c[n];
#pragma unroll
    for (int g = 0; g < 3; g++) {
        unsigned long long m = __ballot(cc == g);
        if (cc == g) {
            int leader = __ffsll((long long)m) - 1;
            if (lane == leader) atomicAdd(&cnt3[g], __popcll(m));
        }
    }
}
// scan over IDX buckets; tail (t==0): comp bases, seldot block descriptors.
// BLK[b] = (comp<<16)|rowStart ; -1 sentinel. SEG[4] = comp segment bounds.
__global__ __launch_bounds__(512) void scan_kernel(const int* __restrict__ cnt,
                                                   int* __restrict__ base,
                                                   int* __restrict__ cur,
                                                   const int* __restrict__ cnt3,
                                                   int* __restrict__ cur3,
                                                   int* __restrict__ SEG,
                                                   int* __restrict__ BLK) {
    __shared__ int s[TT];
    int t = threadIdx.x;
    int v = cnt[t];
    s[t] = v;
    __syncthreads();
    for (int off = 1; off < TT; off <<= 1) {
        int add = (t >= off) ? s[t - off] : 0;
        __syncthreads();
        s[t] += add;
        __syncthreads();
    }
    base[t] = s[t] - v;
    cur[t] = s[t] - v;
    if (t == 0) {
        int b0 = cnt3[0], b1 = cnt3[1], b2 = cnt3[2];
        SEG[0] = 0; SEG[1] = b0; SEG[2] = b0 + b1; SEG[3] = b0 + b1 + b2;
        cur3[0] = SEG[0]; cur3[1] = SEG[1]; cur3[2] = SEG[2];
        int bidx = 0;
        for (int g = 0; g < 3; g++) {
            int cntg = cnt3[g];
            int tiles = (cntg + 63) >> 6;
            for (int tl = 0; tl < tiles; tl++)
                BLK[bidx++] = (g << 16) | (SEG[g] + tl * 64);
        }
        for (; bidx < 131; bidx++) BLK[bidx] = -1;
    }
}
__global__ __launch_bounds__(256) void scat_kernel(const int* __restrict__ IDX,
                                                   const int* __restrict__ c,
                                                   int* __restrict__ cur,
                                                   int* __restrict__ cur3,
                                                   int* __restrict__ perm,
                                                   int* __restrict__ perm2) {
    int n = blockIdx.x * 256 + threadIdx.x;
    int lane = threadIdx.x & 63;
    unsigned long long below = (lane == 63) ? ~0ull >> 1
                                            : (1ull << lane) - 1ull;
    int pos = atomicAdd(&cur[IDX[n]], 1);
    perm[pos] = n;
    int cc = c[n];
#pragma unroll
    for (int g = 0; g < 3; g++) {
        unsigned long long m = __ballot(cc == g);
        if (cc == g) {
            int leader = __ffsll((long long)m) - 1;
            int pre = __popcll(m & below);
            int base2 = 0;
            if (lane == leader) base2 = atomicAdd(&cur3[g], __popcll(m));
            base2 = __shfl(base2, leader);
            perm2[base2 + pre] = n;
        }
    }
}

// ---------------------------------------------------------------------------
// mgemm_b: MFMA bf16 GEMM (KV path). A fp32 (converted on the fly), W bf16.
// ---------------------------------------------------------------------------
template <int ST16>
__global__ __launch_bounds__(256) void mgemm_b(
    const float* __restrict__ A, const u16* __restrict__ Wb,
    const float* __restrict__ bias, void* __restrict__ Cv, int ldc) {
    __shared__ u16 As[64 * 40];
    __shared__ u16 Ws[64 * 40];
    const int t = threadIdx.x;
    const size_t rb = (size_t)blockIdx.x * 64;
    const size_t cb = (size_t)blockIdx.y * 64;
    const int wave = t >> 6, lane = t & 63;
    const int m16 = lane & 15, quad = lane >> 4;
    const int sr = t >> 2, sk = (t & 3) * 8;
    const float* Ap = A + (rb + sr) * 256 + sk;
    const u16* Wp = Wb + (cb + sr) * 256 + sk;

    f32x4 acc[4] = {};
    for (int k0 = 0; k0 < 256; k0 += 32) {
        float4 a0 = *(const float4*)(Ap + k0);
        float4 a1 = *(const float4*)(Ap + k0 + 4);
        u16 ta[8] = {f2b(a0.x), f2b(a0.y), f2b(a0.z), f2b(a0.w),
                     f2b(a1.x), f2b(a1.y), f2b(a1.z), f2b(a1.w)};
        *(uint4*)&As[sr * 40 + sk] = *(const uint4*)ta;
        *(uint4*)&Ws[sr * 40 + sk] = *(const uint4*)(Wp + k0);
        __syncthreads();
        s16x8 af = *(const s16x8*)&As[(wave * 16 + m16) * 40 + quad * 8];
#pragma unroll
        for (int ct = 0; ct < 4; ct++) {
            s16x8 bf = *(const s16x8*)&Ws[(ct * 16 + m16) * 40 + quad * 8];
            acc[ct] = __builtin_amdgcn_mfma_f32_16x16x32_bf16(af, bf, acc[ct], 0, 0, 0);
        }
        __syncthreads();
    }
#pragma unroll
    for (int ct = 0; ct < 4; ct++) {
        size_t col = cb + ct * 16 + m16;
        float bb = bias ? bias[col] : 0.f;
#pragma unroll
        for (int r = 0; r < 4; r++) {
            size_t row = rb + wave * 16 + quad * 4 + r;
            float x = acc[ct][r] + bb;
            if (ST16) {
                ((u16*)Cv)[row * (size_t)ldc + col] = f2b(x);
            } else {
                ((float*)Cv)[row * (size_t)ldc + col] = x;
            }
        }
    }
}

// ---------------------------------------------------------------------------
// seldot: component-grouped H-GEMM + fused final dot.
// One block = 64 perm2-consecutive rows (component-uniform, clamped dup rows
// at segment tails compute identical values -> benign duplicate writes).
// Computes H[row, 0..255] = C2[row] @ M_g^T in acc[16] (never stored), then
// out[n] = (sum_col F*(H+v_g) + u_g*C2 + s_g) * exp(lt)*cs_g + cb_g.
// __launch_bounds__(256,1): full VGPR headroom (acc[16]=64 VGPR), grid<=131
// blocks < 256 CUs so occupancy is irrelevant -> avoids R4-R6 spill mode.
// ---------------------------------------------------------------------------
__global__ __launch_bounds__(256, 1) void seldot_kernel(
    const float* __restrict__ C2, const float* __restrict__ F,
    const u16* __restrict__ MC, const int* __restrict__ BLK,
    const int* __restrict__ SEG, const int* __restrict__ perm2,
    const float* __restrict__ Ub, const float* __restrict__ Vb,
    const float* __restrict__ Sb, const float* __restrict__ lt,
    const float* __restrict__ cs, const float* __restrict__ cbv,
    float* __restrict__ out) {
    const int bd = BLK[blockIdx.x];
    if (bd < 0) return;
    const int g = bd >> 16, rowStart = bd & 0xFFFF;
    __shared__ u16 As[64 * 40];
    __shared__ u16 Ws[256 * 40];
    __shared__ int rowIdx[64];
    __shared__ float vS[256], uS[256];
    const int t = threadIdx.x;
    const int wave = t >> 6, lane = t & 63;
    const int m16 = lane & 15, quad = lane >> 4;
    const int sr = t >> 2, sk = (t & 3) * 8;
    if (t < 64) {
        int pos = rowStart + t;
        int segEnd = SEG[g + 1];
        if (pos >= segEnd) pos = segEnd - 1;
        rowIdx[t] = perm2[pos];
    }
    vS[t] = Vb[g * 256 + t];
    uS[t] = Ub[g * 256 + t];
    __syncthreads();

    const float* Ap = C2 + (size_t)rowIdx[sr] * 256 + sk;
    const u16* Wp = MC + (size_t)g * 65536;
    f32x4 acc[16];
#pragma unroll
    for (int i = 0; i < 16; i++) acc[i] = (f32x4){0.f, 0.f, 0.f, 0.f};

    for (int k0 = 0; k0 < 256; k0 += 32) {
        float4 a0 = *(const float4*)(Ap + k0);
        float4 a1 = *(const float4*)(Ap + k0 + 4);
        u16 ta[8] = {f2b(a0.x), f2b(a0.y), f2b(a0.z), f2b(a0.w),
                     f2b(a1.x), f2b(a1.y), f2b(a1.z), f2b(a1.w)};
        *(uint4*)&As[sr * 40 + sk] = *(const uint4*)ta;
#pragma unroll
        for (int wr = 0; wr < 4; wr++)
            *(uint4*)&Ws[(wr * 64 + sr) * 40 + sk] =
                *(const uint4*)(Wp + (size_t)(wr * 64 + sr) * 256 + k0 + sk);
        __syncthreads();
        s16x8 af = *(const s16x8*)&As[(wave * 16 + m16) * 40 + quad * 8];
#pragma unroll
        for (int ct = 0; ct < 16; ct++) {
            s16x8 bf = *(const s16x8*)&Ws[(ct * 16 + m16) * 40 + quad * 8];
            acc[ct] = __builtin_amdgcn_mfma_f32_16x16x32_bf16(af, bf, acc[ct], 0, 0, 0);
        }
        __syncthreads();
    }

    // fused dot epilogue
    float tot[4] = {0.f, 0.f, 0.f, 0.f};
#pragma unroll
    for (int ct = 0; ct < 16; ct++) {
        const int col = ct * 16 + m16;
        const float vv = vS[col], uu = uS[col];
#pragma unroll
        for (int r = 0; r < 4; r++) {
            const int row = wave * 16 + quad * 4 + r;
            const size_t nb = (size_t)rowIdx[row] * 256 + col;
            tot[r] += F[nb] * (acc[ct][r] + vv) + uu * C2[nb];
        }
    }
    const float scale = expf(lt[0]) * cs[g];
    const float sg = Sb[g], cbg = cbv[g];
#pragma unroll
    for (int r = 0; r < 4; r++) {
        float s = tot[r];
        s += __shfl_xor(s, 1);
        s += __shfl_xor(s, 2);
        s += __shfl_xor(s, 4);
        s += __shfl_xor(s, 8);
        if (m16 == 0) {
            const int n = rowIdx[wave * 16 + quad * 4 + r];
            out[n] = (s + sg) * scale + cbg;
        }
    }
}

// ---------------------------------------------------------------------------
// Fused chain machinery, v3: 1024 threads (16 waves), 32 rows, wave owns one
// 16-col tile. wload() preloads ALL B-fragments of a GEMM phase into a
// register array so the 16 weight loads issue back-to-back -> ONE latency
// exposure per phase. (Best-known chains: 321.7 us baseline. MCAT-fold-into-
// chain variants R4-R6 all hit an unfixable 64-VGPR spill signature; SEL+dot
// live in the standalone seldot_kernel instead.)
// MFMA order is numerics-defining: split x3 (ah*bh + al*bh + ah*bl).
// ---------------------------------------------------------------------------
template <int NK0>
struct WF { s16x8 h[NK0], l[NK0]; };

template <int NK0>
__device__ __forceinline__ void wload(const u16* __restrict__ PH,
                                      const u16* __restrict__ PL, size_t mb,
                                      int wave, int lane, WF<NK0>& w) {
#pragma unroll
    for (int k0 = 0; k0 < NK0; k0++) {
        const size_t wo = mb + ((size_t)(wave * NK0 + k0) * 64 + lane) * 8;
        w.h[k0] = *(const s16x8*)&PH[wo];
        w.l[k0] = *(const s16x8*)&PL[wo];
    }
}

template <int NK0>
__device__ __forceinline__ void cgemm_c(const WF<NK0>& w,
                                        const u16* Ch, const u16* Cl,
                                        int lane, f32x4 (&acc)[2]) {
    acc[0] = (f32x4){0.f, 0.f, 0.f, 0.f};
    acc[1] = (f32x4){0.f, 0.f, 0.f, 0.f};
#pragma unroll
    for (int k0 = 0; k0 < NK0; k0++) {
        s16x8 a0h = *(const s16x8*)&Ch[(k0 * 64 + lane) * 8];
        s16x8 a0l = *(const s16x8*)&Cl[(k0 * 64 + lane) * 8];
        s16x8 a1h = *(const s16x8*)&Ch[((8 + k0) * 64 + lane) * 8];
        s16x8 a1l = *(const s16x8*)&Cl[((8 + k0) * 64 + lane) * 8];
        acc[0] = __builtin_amdgcn_mfma_f32_16x16x32_bf16(a0h, w.h[k0], acc[0], 0, 0, 0);
        acc[0] = __builtin_amdgcn_mfma_f32_16x16x32_bf16(a0l, w.h[k0], acc[0], 0, 0, 0);
        acc[0] = __builtin_amdgcn_mfma_f32_16x16x32_bf16(a0h, w.l[k0], acc[0], 0, 0, 0);
        acc[1] = __builtin_amdgcn_mfma_f32_16x16x32_bf16(a1h, w.h[k0], acc[1], 0, 0, 0);
        acc[1] = __builtin_amdgcn_mfma_f32_16x16x32_bf16(a1l, w.h[k0], acc[1], 0, 0, 0);
        acc[1] = __builtin_amdgcn_mfma_f32_16x16x32_bf16(a1h, w.l[k0], acc[1], 0, 0, 0);
    }
}

// LN over Fv -> packed split Ch/Cl. Phase A: 32 threads/row compute stats.
// Phase B (transposed): each thread normalizes one 8-col chunk, writes uint4.
__device__ __forceinline__ void ln_split(const float* __restrict__ Fv,
                                         u16* __restrict__ Ch, u16* __restrict__ Cl,
                                         const float* __restrict__ g,
                                         const float* __restrict__ b,
                                         float* __restrict__ mean_s,
                                         float* __restrict__ rstd_s, int t) {
    {
        const int row = t >> 5, q = t & 31;
        const float* fr = Fv + row * LDF;
        float4 v0 = *(const float4*)&fr[q * 4];
        float4 v1 = *(const float4*)&fr[q * 4 + 128];
        float s1 = v0.x + v0.y + v0.z + v0.w + v1.x + v1.y + v1.z + v1.w;
        float s2 = v0.x * v0.x + v0.y * v0.y + v0.z * v0.z + v0.w * v0.w +
                   v1.x * v1.x + v1.y * v1.y + v1.z * v1.z + v1.w * v1.w;
#pragma unroll
        for (int m = 16; m >= 1; m >>= 1) {
            s1 += __shfl_xor(s1, m);
            s2 += __shfl_xor(s2, m);
        }
        if (q == 0) {
            float mean = s1 * (1.f / 256.f);
            mean_s[row] = mean;
            rstd_s[row] = rsqrtf(s2 * (1.f / 256.f) - mean * mean + 1e-5f);
        }
    }
    __syncthreads();
    {
        const int rw = t & 31, qc = t >> 5;
        const float* fr = Fv + rw * LDF + qc * 8;
        float4 v0 = *(const float4*)fr;
        float4 v1 = *(const float4*)(fr + 4);
        const float mean = mean_s[rw], rstd = rstd_s[rw];
        float4 g0 = *(const float4*)&g[qc * 8], g1 = *(const float4*)&g[qc * 8 + 4];
        float4 b0 = *(const float4*)&b[qc * 8], b1 = *(const float4*)&b[qc * 8 + 4];
        float va[8] = {v0.x, v0.y, v0.z, v0.w, v1.x, v1.y, v1.z, v1.w};
        float ga[8] = {g0.x, g0.y, g0.z, g0.w, g1.x, g1.y, g1.z, g1.w};
        float ba[8] = {b0.x, b0.y, b0.z, b0.w, b1.x, b1.y, b1.z, b1.w};
        u16 hv[8], lv[8];
#pragma unroll
        for (int j = 0; j < 8; j++) {
            float x = (va[j] - mean) * rstd * ga[j] + ba[j];
            hv[j] = f2b(x);
            lv[j] = f2b(x - b2f(hv[j]));
        }
        const int c = qc * 8;
        const int off = (((rw >> 4) * 8 + (c >> 5)) * 64 +
                         (((c >> 3) & 3) * 16 + (rw & 15))) * 8;
        *(uint4*)&Ch[off] = *(const uint4*)hv;
        *(uint4*)&Cl[off] = *(const uint4*)lv;
    }
}

// ---------------------------------------------------------------------------
// chain1: trunk_in -> [LN,fc1,fc2] x2 -> (F to global) -> LN -> q-proj
// ---------------------------------------------------------------------------
__global__ __launch_bounds__(1024) void chain1_kernel(
    const float* __restrict__ FIN, const u16* __restrict__ PH,
    const u16* __restrict__ PL, const float* __restrict__ tib,
    const float* __restrict__ lng, const float* __restrict__ lnb,
    const float* __restrict__ f1b, const float* __restrict__ f2bv,
    const float* __restrict__ bng, const float* __restrict__ bnb,
    const float* __restrict__ aib,
    float* __restrict__ Qb, float* __restrict__ Fg) {
    __shared__ u16 Ch[8192], Cl[8192];
    __shared__ float Fv[32 * LDF];
    __shared__ float mean_s[32], rstd_s[32];
    const int t = threadIdx.x;
    const int wave = t >> 6, lane = t & 63;
    const int m16 = lane & 15, quad = lane >> 4;
    const size_t rb = (size_t)blockIdx.x * 32;
    const int col = wave * 16 + m16;
    f32x4 acc[2];

    // phase 0: FIN [32,160] -> split packed
    {
        const int row = t >> 5, q = t & 31;
        if (q < 20) {
            const float* p = FIN + (rb + row) * 160 + q * 8;
            float4 v0 = *(const float4*)p, v1 = *(const float4*)(p + 4);
            float va[8] = {v0.x, v0.y, v0.z, v0.w, v1.x, v1.y, v1.z, v1.w};
            u16 hv[8], lv[8];
#pragma unroll
            for (int j = 0; j < 8; j++) { hv[j] = f2b(va[j]); lv[j] = f2b(va[j] - b2f(hv[j])); }
            const int c = q * 8;
            const int off = (((row >> 4) * 8 + (c >> 5)) * 64 +
                             (((c >> 3) & 3) * 16 + (row & 15))) * 8;
            *(uint4*)&Ch[off] = *(const uint4*)hv;
            *(uint4*)&Cl[off] = *(const uint4*)lv;
        }
    }

    // trunk_in (K=160): silu -> Fv
    {
        WF<5> w;
        wload<5>(PH, PL, 524288, wave, lane, w);
        __syncthreads();
        cgemm_c<5>(w, Ch, Cl, lane, acc);
    }
    {
        const float bb = tib[col];
#pragma unroll
        for (int rt = 0; rt < 2; rt++)
#pragma unroll
            for (int r = 0; r < 4; r++)
                Fv[(rt * 16 + quad * 4 + r) * LDF + col] = silu_f(acc[rt][r] + bb);
    }
    __syncthreads();

    // two residual blocks
#pragma unroll
    for (int L = 0; L < 2; L++) {
        ln_split(Fv, Ch, Cl, lng + L * 256, lnb + L * 256, mean_s, rstd_s, t);
        {
            WF<8> w;
            wload<8>(PH, PL, (size_t)L * 65536, wave, lane, w);  // fc1
            __syncthreads();
            cgemm_c<8>(w, Ch, Cl, lane, acc);
        }
        __syncthreads();
        {
            const float bb = f1b[L * 256 + col];
            const int k0c = col >> 5, qc4 = (col >> 3) & 3, jc = col & 7;
#pragma unroll
            for (int rt = 0; rt < 2; rt++)
#pragma unroll
                for (int r = 0; r < 4; r++) {
                    const int row = rt * 16 + quad * 4 + r;
                    float x = silu_f(acc[rt][r] + bb);
                    const int off = ((rt * 8 + k0c) * 64 + (qc4 * 16 + (row & 15))) * 8 + jc;
                    u16 h = f2b(x);
                    Ch[off] = h;
                    Cl[off] = f2b(x - b2f(h));
                }
        }
        {
            WF<8> w;
            wload<8>(PH, PL, 131072 + (size_t)L * 65536, wave, lane, w);  // fc2
            __syncthreads();
            cgemm_c<8>(w, Ch, Cl, lane, acc);
        }
        {
            const float bb = f2bv[L * 256 + col];
#pragma unroll
            for (int rt = 0; rt < 2; rt++)
#pragma unroll
                for (int r = 0; r < 4; r++) {
                    const int row = rt * 16 + quad * 4 + r;
                    Fv[row * LDF + col] += acc[rt][r] + bb;
                }
        }
        __syncthreads();
    }

    // F -> global ; LN(bn) -> packed C
    {
        const int row = t >> 5, q = t & 31;
        const float* fr = Fv + row * LDF + q * 8;
        float4 v0 = *(const float4*)fr, v1 = *(const float4*)(fr + 4);
        float* dst = Fg + (rb + row) * 256 + q * 8;
        *(float4*)dst = v0;
        *(float4*)(dst + 4) = v1;
    }
    ln_split(Fv, Ch, Cl, bng, bnb, mean_s, rstd_s, t);

    // q projection -> Qb global
    {
        WF<8> w;
        wload<8>(PH, PL, 262144, wave, lane, w);
        __syncthreads();
        cgemm_c<8>(w, Ch, Cl, lane, acc);
    }
    {
        const float bb = aib[col];
#pragma unroll
        for (int rt = 0; rt < 2; rt++)
#pragma unroll
            for (int r = 0; r < 4; r++) {
                const int row = rt * 16 + quad * 4 + r;
                Qb[(rb + row) * 256 + col] = acc[rt][r] + bb;
            }
    }
}

// ---------------------------------------------------------------------------
// chain2: attn_out -> LN -> bc1(silu) -> bc2(+res) -> C2 global
// ---------------------------------------------------------------------------
__global__ __launch_bounds__(1024) void chain2_kernel(
    const float* __restrict__ CTX, const u16* __restrict__ PH,
    const u16* __restrict__ PL, const float* __restrict__ aob,
    const float* __restrict__ clg, const float* __restrict__ clb,
    const float* __restrict__ b1, const float* __restrict__ b2v,
    float* __restrict__ C2g) {
    __shared__ u16 Ch[8192], Cl[8192];
    __shared__ float Fv[32 * LDF];
    __shared__ float mean_s[32], rstd_s[32];
    const int t = threadIdx.x;
    const int wave = t >> 6, lane = t & 63;
    const int m16 = lane & 15, quad = lane >> 4;
    const size_t rb = (size_t)blockIdx.x * 32;
    const int col = wave * 16 + m16;
    f32x4 acc[2];

    // phase 0: CTX -> split packed
    {
        const int row = t >> 5, q = t & 31;
        const float* p = CTX + (rb + row) * 256 + q * 8;
        float4 v0 = *(const float4*)p, v1 = *(const float4*)(p + 4);
        float va[8] = {v0.x, v0.y, v0.z, v0.w, v1.x, v1.y, v1.z, v1.w};
        u16 hv[8], lv[8];
#pragma unroll
        for (int j = 0; j < 8; j++) { hv[j] = f2b(va[j]); lv[j] = f2b(va[j] - b2f(hv[j])); }
        const int c = q * 8;
        const int off = (((row >> 4) * 8 + (c >> 5)) * 64 +
                         (((c >> 3) & 3) * 16 + (row & 15))) * 8;
        *(uint4*)&Ch[off] = *(const uint4*)hv;
        *(uint4*)&Cl[off] = *(const uint4*)lv;
    }

    // attn_out -> Fv
    {
        WF<8> w;
        wload<8>(PH, PL, 327680, wave, lane, w);
        __syncthreads();
        cgemm_c<8>(w, Ch, Cl, lane, acc);
    }
    {
        const float bb = aob[col];
#pragma unroll
        for (int rt = 0; rt < 2; rt++)
#pragma unroll
            for (int r = 0; r < 4; r++)
                Fv[(rt * 16 + quad * 4 + r) * LDF + col] = acc[rt][r] + bb;
    }
    __syncthreads();

    ln_split(Fv, Ch, Cl, clg, clb, mean_s, rstd_s, t);
    {
        WF<8> w;
        wload<8>(PH, PL, 393216, wave, lane, w);  // bc1
        __syncthreads();
        cgemm_c<8>(w, Ch, Cl, lane, acc);
    }
    __syncthreads();
    {
        const float bb = b1[col];
        const int k0c = col >> 5, qc4 = (col >> 3) & 3, jc = col & 7;
#pragma unroll
        for (int rt = 0; rt < 2; rt++)
#pragma unroll
            for (int r = 0; r < 4; r++) {
                const int row = rt * 16 + quad * 4 + r;
                float x = silu_f(acc[rt][r] + bb);
                const int off = ((rt * 8 + k0c) * 64 + (qc4 * 16 + (row & 15))) * 8 + jc;
                u16 h = f2b(x);
                Ch[off] = h;
                Cl[off] = f2b(x - b2f(h));
            }
    }
    {
        WF<8> w;
        wload<8>(PH, PL, 458752, wave, lane, w);  // bc2
        __syncthreads();
        cgemm_c<8>(w, Ch, Cl, lane, acc);
    }
    {
        const float bb = b2v[col];
#pragma unroll
        for (int rt = 0; rt < 2; rt++)
#pragma unroll
            for (int r = 0; r < 4; r++) {
                const int row = rt * 16 + quad * 4 + r;
                C2g[(rb + row) * 256 + col] = acc[rt][r] + bb + Fv[row * LDF + col];
            }
    }
}

// ---------------------------------------------------------------------------
// attn4: one block per query (perm-ordered). KV interleaved [16384,512] bf16.
// In-place Qb -> CTX.
// ---------------------------------------------------------------------------
__global__ __launch_bounds__(256) void attn4_kernel(
    float* __restrict__ QC, const u16* __restrict__ KV,
    const int* __restrict__ idx, const int* __restrict__ perm) {
    __shared__ u16 vsh[STOK * 264];
    __shared__ float qsh[256], attw[4][STOK];
    const int n = perm[blockIdx.x];
    const int t = threadIdx.x;
    qsh[t] = QC[(size_t)n * 256 + t];
    int ii = idx[n];
    ii = ii < 0 ? 0 : (ii > TT - 1 ? TT - 1 : ii);
    const u16* kvb = KV + (size_t)ii * STOK * 512;
#pragma unroll
    for (int i = t; i < 1024; i += 256) {
        int s = i >> 5, dq = (i & 31) * 8;
        *(uint4*)&vsh[s * 264 + dq] = *(const uint4*)&kvb[(size_t)s * 512 + 256 + dq];
    }
    __syncthreads();
    if (t < 128) {
        int h = t >> 5, s = t & 31;
        const u16* kp = kvb + (size_t)s * 512 + h * 64;
        uint4 kv[8];
#pragma unroll
        for (int dq = 0; dq < 8; dq++) kv[dq] = *(const uint4*)(kp + dq * 8);
        float p0 = 0.f, p1 = 0.f;
#pragma unroll
        for (int dq = 0; dq < 8; dq++) {
            const u16* ks = (const u16*)&kv[dq];
            float a0 = 0.f;
#pragma unroll
            for (int j = 0; j < 8; j++) a0 += qsh[h * 64 + dq * 8 + j] * b2f(ks[j]);
            if (dq & 1) p1 += a0; else p0 += a0;
        }
        float sc = (p0 + p1) * 0.125f;
        float mx = sc;
#pragma unroll
        for (int m = 16; m >= 1; m >>= 1) mx = fmaxf(mx, __shfl_xor(mx, m));
        float e = expf(sc - mx);
        float sum = e;
#pragma unroll
        for (int m = 16; m >= 1; m >>= 1) sum += __shfl_xor(sum, m);
        attw[h][s] = e / sum;
    }
    __syncthreads();
    {
        int h = t >> 6;
        float a = 0.f;
#pragma unroll 8
        for (int s = 0; s < STOK; s++) a += attw[h][s] * b2f(vsh[s * 264 + t]);
        QC[(size_t)n * 256 + t] = a;
    }
}

// ---------------------------------------------------------------------------
extern "C" void kernel_launch(void* const* d_in, const int* in_sizes, int n_in,
                              void* d_out, int out_size, void* d_ws, size_t ws_size,
                              hipStream_t stream) {
    float* out = (float*)d_out;
    const dim3 blk(256);

    static const int EXPECT[38] = {
        16384, 8192, 8192, 4194304, 512, 128, 16, 16, 24,
        38912, 256, 512, 512, 131072, 512, 131072, 512,
        65536, 256, 256, 256, 196608, 768, 65536, 256,
        256, 256, 65536, 256, 65536, 256, 196608, 768,
        196608, 768, 1, 3, 3};
    if (n_in != 38) { const_kernel<<<NQ / 256, blk, 0, stream>>>(99.0e6f, out); return; }
    for (int i = 0; i < 38; i++)
        if (in_sizes[i] != EXPECT[i]) {
            const_kernel<<<NQ / 256, blk, 0, stream>>>((100.0f + i) * 1.0e6f, out);
            return;
        }

    const float* xy  = (const float*)d_in[0];
    const float* tq  = (const float*)d_in[1];
    const int*   c   = (const int*)d_in[2];
    const float* hs  = (const float*)d_in[3];
    const float* st  = (const float*)d_in[4];
    const float* Bm  = (const float*)d_in[5];
    const float* tw  = (const float*)d_in[6];
    const float* tbv = (const float*)d_in[7];
    const float* ce  = (const float*)d_in[8];
    const float* tiw = (const float*)d_in[9];
    const float* tib = (const float*)d_in[10];
    const float* lng = (const float*)d_in[11];
    const float* lnb = (const float*)d_in[12];
    const float* f1w = (const float*)d_in[13];
    const float* f1b = (const float*)d_in[14];
    const float* f2w = (const float*)d_in[15];
    const float* f2b_ = (const float*)d_in[16];
    const float* btw = (const float*)d_in[17];
    const float* btb = (const float*)d_in[18];
    const float* bng = (const float*)d_in[19];
    const float* bnb = (const float*)d_in[20];
    const float* aiw = (const float*)d_in[21];
    const float* aib = (const float*)d_in[22];
    const float* aow = (const float*)d_in[23];
    const float* aob = (const float*)d_in[24];
    const float* clg = (const float*)d_in[25];
    const float* clb = (const float*)d_in[26];
    const float* w1  = (const float*)d_in[27];
    const float* b1  = (const float*)d_in[28];
    const float* w2  = (const float*)d_in[29];
    const float* b2  = (const float*)d_in[30];
    const float* tow = (const float*)d_in[31];
    const float* tob = (const float*)d_in[32];
    const float* bpw = (const float*)d_in[33];
    const float* bpb = (const float*)d_in[34];
    const float* lt  = (const float*)d_in[35];
    const float* cs  = (const float*)d_in[36];
    const float* cbv = (const float*)d_in[37];

    char* ws = (char*)d_ws;
    const size_t MB = 1 << 20;
    if (ws_size < 44 * MB) {
        const_kernel<<<NQ / 256, blk, 0, stream>>>(8.0e6f, out);
        return;
    }

    // KV interleaved [16384,512] bf16 = 16 MB at [0,16). Slots 8 MB each.
    u16*   KV   = (u16*)(ws + 0 * MB);
    char*  S_A  = ws + 16 * MB;   // FIN
    char*  S_B  = ws + 24 * MB;   // F (trunk state, written once by chain1)
    char*  S_C  = ws + 32 * MB;   // Qb -> CTX (attn in-place) -> C2 (in-place)
    char*  misc = ws + 40 * MB;
    float* FIN  = (float*)S_A;
    float* F    = (float*)S_B;
    float* Qb   = (float*)S_C;
    float* C2   = (float*)S_C;
    int*   IDX  = (int*)(misc + 0);                   // 32KB
    float* bkv  = (float*)(misc + 32 * 1024);         // 4KB
    float* Ubuf = (float*)(misc + 36 * 1024);
    float* Vbuf = (float*)(misc + 40 * 1024);
    float* Sbuf = (float*)(misc + 44 * 1024);
    int*   CNT  = (int*)(misc + 48 * 1024);
    int*   BASE = (int*)(misc + 52 * 1024);
    int*   CUR  = (int*)(misc + 56 * 1024);
    int*   PERM = (int*)(misc + 60 * 1024);           // 32KB -> 92K
    u16*   WKVb = (u16*)(misc + 92 * 1024);           // [512,256] 256KB -> 348K
    u16*   MCATb= (u16*)(misc + 348 * 1024);          // [768,256] 384KB -> 732K
    u16*   PH   = (u16*)(misc + 732 * 1024);          // packed hi 1104KB -> 1836K
    u16*   PL   = (u16*)(misc + 1836 * 1024);         // packed lo 1104KB -> 2940K
    int*   PERM2= (int*)(misc + 2940 * 1024);         // 32KB -> 2972K
    int*   CNT3 = (int*)(misc + 2972 * 1024);         // 3 ints
    int*   CUR3 = (int*)(misc + 2972 * 1024 + 16);    // 3 ints
    int*   SEG  = (int*)(misc + 2972 * 1024 + 32);    // 4 ints
    int*   BLK  = (int*)(misc + 2972 * 1024 + 64);    // 131 ints

    const dim3 gKV(TT * STOK / 64, 8);   // M=16384, N=512

    // ---- prep (input-only) ----
    zero_kernel<<<3, blk, 0, stream>>>(CNT, CNT3);
    pack_split<<<2208, blk, 0, stream>>>(f1w, f2w, aiw, aow, w1, w2, tiw, PH, PL);
    combine_kv32<<<512, blk, 0, stream>>>(aiw, aib, btw, btb, WKVb, bkv);
    mcat_kernel<<<dim3(16, 16, 3), blk, 0, stream>>>(tow, bpw, MCATb);
    uvs_kernel<<<3, blk, 0, stream>>>(tow, tob, bpw, bpb, Ubuf, Vbuf, Sbuf);
    feat32_kernel<<<NQ, blk, 0, stream>>>(xy, tq, c, st, Bm, tw, tbv, ce, FIN, IDX);

    // ---- sort queries by time index (perm) and component (perm2 + BLK) ----
    hist_kernel<<<NQ / 256, blk, 0, stream>>>(IDX, c, CNT, CNT3);
    scan_kernel<<<1, dim3(512), 0, stream>>>(CNT, BASE, CUR, CNT3, CUR3, SEG, BLK);
    scat_kernel<<<NQ / 256, blk, 0, stream>>>(IDX, c, CUR, CUR3, PERM, PERM2);

    // ---- K/V (single merged GEMM, bf16 interleaved output) ----
    mgemm_b<1><<<gKV, blk, 0, stream>>>(hs, WKVb, bkv, KV, 512);

    // ---- fused trunk chain: 6 GEMMs in one dispatch, 16 waves/block ----
    chain1_kernel<<<NQ / 32, dim3(1024), 0, stream>>>(FIN, PH, PL, tib, lng, lnb,
                                                      f1b, f2b_, bng, bnb, aib, Qb, F);
    // ---- attention ----
    attn4_kernel<<<NQ, blk, 0, stream>>>(Qb, KV, IDX, PERM);
    // ---- fused post chain ----
    chain2_kernel<<<NQ / 32, dim3(1024), 0, stream>>>(Qb, PH, PL, aob, clg, clb,
                                                      b1, b2, C2);
    // ---- component-grouped SEL GEMM + fused final dot -> out ----
    seldot_kernel<<<131, blk, 0, stream>>>(C2, F, MCATb, BLK, SEG, PERM2,
                                           Ubuf, Vbuf, Sbuf, lt, cs, cbv, out);
}

// Round 11
// 322.091 us; speedup vs baseline: 1.3095x; 1.0091x over previous
//
#include <hip/hip_runtime.h>
#include <cstdint>
#include <cstddef>

typedef unsigned short u16;
typedef __attribute__((ext_vector_type(8))) short s16x8;
typedef __attribute__((ext_vector_type(4))) float f32x4;

#define NQ   8192
#define TT   512
#define STOK 32
#define LDF  260   // Fv row stride (floats): 256 + 4 pad -> bank rotation by 4/row

__device__ __forceinline__ float b2f(u16 u) {
    return __uint_as_float(((uint32_t)u) << 16);
}
__device__ __forceinline__ u16 f2b(float f) {
    uint32_t x = __float_as_uint(f);
    uint32_t r = (x + 0x7FFFu + ((x >> 16) & 1u)) >> 16;
    return (u16)r;
}
__device__ __forceinline__ float silu_f(float x) { return x / (1.f + expf(-x)); }

__global__ __launch_bounds__(256) void const_kernel(float v, float* __restrict__ out) {
    int i = blockIdx.x * 256 + threadIdx.x;
    if (i < NQ) out[i] = v;
}

// ---------------------------------------------------------------------------
// zero CNT[512]
// ---------------------------------------------------------------------------
__global__ __launch_bounds__(256) void zero_kernel(int* __restrict__ cnt) {
    int i = blockIdx.x * 256 + threadIdx.x;
    if (i < 512) cnt[i] = 0;
}

// ---------------------------------------------------------------------------
// features (verified): FIN fp32 [NQ,160] (cols 152..159 = 0), IDX
// ---------------------------------------------------------------------------
__global__ __launch_bounds__(256) void feat32_kernel(
    const float* __restrict__ xy, const float* __restrict__ t_q,
    const int* __restrict__ c, const float* __restrict__ st,
    const float* __restrict__ B, const float* __restrict__ tw,
    const float* __restrict__ tb, const float* __restrict__ ce,
    float* __restrict__ FIN, int* __restrict__ IDX) {
    int n = blockIdx.x, t = threadIdx.x;
    float tq = t_q[n];
    int lo = 0, hi = TT;
    while (lo < hi) {
        int mid = (lo + hi) >> 1;
        if (st[mid] <= tq) lo = mid + 1; else hi = mid;
    }
    int idx = lo - 1;
    if (idx < 0) idx = 0;
    float dt = tq - st[idx];
    if (dt < 0.f) dt = 0.f;
    if (t == 0) IDX[n] = idx;
    float x = xy[2 * n], y = xy[2 * n + 1];
    size_t base = (size_t)n * 160;
    if (t < 64) { float p = x * B[t] + y * B[64 + t]; FIN[base + t] = cosf(p); }
    else if (t < 128) { int j = t - 64; float p = x * B[j] + y * B[64 + j]; FIN[base + t] = sinf(p); }
    else if (t < 144) { int j = t - 128; FIN[base + t] = dt * tw[j] + tb[j]; }
    else if (t < 152) { int j = t - 144; FIN[base + t] = ce[c[n] * 8 + j]; }
    else if (t < 160) { FIN[base + t] = 0.f; }
}

// ---------------------------------------------------------------------------
// pack_split: all chain weights -> MFMA-fragment-linear bf16 hi/lo.
// pos = ((ct*NK0 + k0)*64 + quad*16 + m16)*8 + j   (ct=col>>4, NK0=K/32)
// Layout (u16 idx): m*65536 for m=0..7 = {f1w L0, f1w L1, f2w L0, f2w L1,
// wq, aow, w1, w2}; trunk_in (K=160, NK0=5, zero-padded cols>=152) at 524288.
// ---------------------------------------------------------------------------
__global__ __launch_bounds__(256) void pack_split(
    const float* __restrict__ f1w, const float* __restrict__ f2w,
    const float* __restrict__ aiw, const float* __restrict__ aow,
    const float* __restrict__ w1, const float* __restrict__ w2,
    const float* __restrict__ tiw,
    u16* __restrict__ PH, u16* __restrict__ PL) {
    int i = blockIdx.x * 256 + threadIdx.x;
    if (i >= 565248) return;
    float v;
    size_t pos;
    if (i < 524288) {
        int m = i >> 16, j = i & 65535;
        int col = j >> 8, k = j & 255;
        const float* src;
        switch (m) {
            case 0: src = f1w; break;
            case 1: src = f1w + 65536; break;
            case 2: src = f2w; break;
            case 3: src = f2w + 65536; break;
            case 4: src = aiw; break;          // wq = rows 0..255 of attn_in_w
            case 5: src = aow; break;
            case 6: src = w1; break;
            default: src = w2; break;
        }
        v = src[j];
        int ct = col >> 4, m16 = col & 15, k0 = k >> 5, quad = (k >> 3) & 3, jj = k & 7;
        pos = (size_t)m * 65536 + (size_t)(((ct * 8 + k0) * 64 + quad * 16 + m16) * 8 + jj);
    } else {
        int j = i - 524288;                    // 0..40959
        int col = j / 160, k = j % 160;
        v = (k < 152) ? tiw[col * 152 + k] : 0.f;
        int ct = col >> 4, m16 = col & 15, k0 = k >> 5, quad = (k >> 3) & 3, jj = k & 7;
        pos = 524288 + (size_t)(((ct * 5 + k0) * 64 + quad * 16 + m16) * 8 + jj);
    }
    u16 h = f2b(v);
    PH[pos] = h;
    PL[pos] = f2b(v - b2f(h));
}

// ---------------------------------------------------------------------------
// fold token projection into K/V weights; emit bf16 [512,256] + fp32 bias[512]
// ---------------------------------------------------------------------------
__global__ __launch_bounds__(256) void combine_kv32(
    const float* __restrict__ aiw, const float* __restrict__ aib,
    const float* __restrict__ btw, const float* __restrict__ btb,
    u16* __restrict__ WKVb, float* __restrict__ bkv) {
    int kv = blockIdx.x >> 8, m = blockIdx.x & 255;
    int d = threadIdx.x;
    __shared__ float wrow[256];
    wrow[d] = aiw[(size_t)(kv + 1) * 65536 + (size_t)m * 256 + d];
    __syncthreads();
    float acc = 0.f;
#pragma unroll 8
    for (int o = 0; o < 256; o++) acc += wrow[o] * btw[(size_t)o * 256 + d];
    WKVb[(size_t)kv * 65536 + (size_t)m * 256 + d] = f2b(acc);
    float pb = wrow[d] * btb[d];
#pragma unroll
    for (int mm = 32; mm >= 1; mm >>= 1) pb += __shfl_xor(pb, mm);
    __shared__ float red[4];
    if ((d & 63) == 0) red[d >> 6] = pb;
    __syncthreads();
    if (d == 0)
        bkv[kv * 256 + m] = red[0] + red[1] + red[2] + red[3] + aib[(kv + 1) * 256 + m];
}

// ---------------------------------------------------------------------------
// M_c = tow_c^T @ bpw_c (bilinear fold); emit bf16 directly
// ---------------------------------------------------------------------------
__global__ __launch_bounds__(256) void mcat_kernel(const float* __restrict__ tow,
                                                   const float* __restrict__ bpw,
                                                   u16* __restrict__ MCATb) {
    const int cc = blockIdx.z;
    const int t0 = blockIdx.x * 16, k0 = blockIdx.y * 16;
    const int lt = threadIdx.x & 15, lj = threadIdx.x >> 4;
    const int ot = threadIdx.x & 15, ok = threadIdx.x >> 4;
    __shared__ float As[16][17], Bs[16][17];
    float acc = 0.f;
    for (int j0 = 0; j0 < 256; j0 += 16) {
        As[lj][lt] = tow[((size_t)cc * 256 + j0 + lj) * 256 + t0 + lt];
        Bs[lj][lt] = bpw[((size_t)cc * 256 + j0 + lj) * 256 + k0 + lt];
        __syncthreads();
#pragma unroll
        for (int jj = 0; jj < 16; jj++) acc += As[jj][ot] * Bs[jj][ok];
        __syncthreads();
    }
    MCATb[((size_t)cc * 256 + t0 + ot) * 256 + k0 + ok] = f2b(acc);
}

__global__ __launch_bounds__(256) void uvs_kernel(
    const float* __restrict__ tow, const float* __restrict__ tob,
    const float* __restrict__ bpw, const float* __restrict__ bpb,
    float* __restrict__ U, float* __restrict__ V, float* __restrict__ S) {
    const int cc = blockIdx.x, t = threadIdx.x;
    float v = 0.f, u = 0.f;
    for (int r = 0; r < 256; r++) {
        v += tow[((size_t)cc * 256 + r) * 256 + t] * bpb[cc * 256 + r];
        u += bpw[((size_t)cc * 256 + r) * 256 + t] * tob[cc * 256 + r];
    }
    V[cc * 256 + t] = v;
    U[cc * 256 + t] = u;
    float sp = tob[cc * 256 + t] * bpb[cc * 256 + t];
#pragma unroll
    for (int m = 32; m >= 1; m >>= 1) sp += __shfl_xor(sp, m);
    __shared__ float red[4];
    if ((t & 63) == 0) red[t >> 6] = sp;
    __syncthreads();
    if (t == 0) S[cc] = red[0] + red[1] + red[2] + red[3];
}

// ---------------------------------------------------------------------------
// counting-sort of queries by IDX (512 buckets) -> perm
// ---------------------------------------------------------------------------
__global__ __launch_bounds__(256) void hist_kernel(const int* __restrict__ IDX,
                                                   int* __restrict__ cnt) {
    int n = blockIdx.x * 256 + threadIdx.x;
    if (n < NQ) atomicAdd(&cnt[IDX[n]], 1);
}
__global__ __launch_bounds__(512) void scan_kernel(const int* __restrict__ cnt,
                                                   int* __restrict__ base,
                                                   int* __restrict__ cur) {
    __shared__ int s[TT];
    int t = threadIdx.x;
    int v = cnt[t];
    s[t] = v;
    __syncthreads();
    for (int off = 1; off < TT; off <<= 1) {
        int add = (t >= off) ? s[t - off] : 0;
        __syncthreads();
        s[t] += add;
        __syncthreads();
    }
    base[t] = s[t] - v;
    cur[t] = s[t] - v;
}
__global__ __launch_bounds__(256) void scat_kernel(const int* __restrict__ IDX,
                                                   int* __restrict__ cur,
                                                   int* __restrict__ perm) {
    int n = blockIdx.x * 256 + threadIdx.x;
    if (n < NQ) {
        int pos = atomicAdd(&cur[IDX[n]], 1);
        perm[pos] = n;
    }
}

// ---------------------------------------------------------------------------
// mgemm_b: MFMA bf16 GEMM, A fp32 (converted on the fly), W pre-converted
// bf16. K=256, output stride ldc. ST16: store bf16. SEL: component select.
// ---------------------------------------------------------------------------
template <int ST16, int SEL>
__global__ __launch_bounds__(256) void mgemm_b(
    const float* __restrict__ A, const u16* __restrict__ Wb,
    const float* __restrict__ bias, const int* __restrict__ csel,
    void* __restrict__ Cv, int ldc) {
    __shared__ u16 As[64 * 40];
    __shared__ u16 Ws[64 * 40];
    const int t = threadIdx.x;
    const size_t rb = (size_t)blockIdx.x * 64;
    const size_t cb = (size_t)blockIdx.y * 64;
    const int wave = t >> 6, lane = t & 63;
    const int m16 = lane & 15, quad = lane >> 4;
    const int sr = t >> 2, sk = (t & 3) * 8;
    const float* Ap = A + (rb + sr) * 256 + sk;
    const u16* Wp = Wb + (cb + sr) * 256 + sk;

    f32x4 acc[4] = {};
    for (int k0 = 0; k0 < 256; k0 += 32) {
        float4 a0 = *(const float4*)(Ap + k0);
        float4 a1 = *(const float4*)(Ap + k0 + 4);
        u16 ta[8] = {f2b(a0.x), f2b(a0.y), f2b(a0.z), f2b(a0.w),
                     f2b(a1.x), f2b(a1.y), f2b(a1.z), f2b(a1.w)};
        *(uint4*)&As[sr * 40 + sk] = *(const uint4*)ta;
        *(uint4*)&Ws[sr * 40 + sk] = *(const uint4*)(Wp + k0);
        __syncthreads();
        s16x8 af = *(const s16x8*)&As[(wave * 16 + m16) * 40 + quad * 8];
#pragma unroll
        for (int ct = 0; ct < 4; ct++) {
            s16x8 bf = *(const s16x8*)&Ws[(ct * 16 + m16) * 40 + quad * 8];
            acc[ct] = __builtin_amdgcn_mfma_f32_16x16x32_bf16(af, bf, acc[ct], 0, 0, 0);
        }
        __syncthreads();
    }
#pragma unroll
    for (int ct = 0; ct < 4; ct++) {
        size_t col = cb + ct * 16 + m16;
        float bb = bias ? bias[col] : 0.f;
#pragma unroll
        for (int r = 0; r < 4; r++) {
            size_t row = rb + wave * 16 + quad * 4 + r;
            float x = acc[ct][r] + bb;
            if (SEL) {
                int comp = (int)(col >> 8);
                if (csel[row] == comp)
                    ((float*)Cv)[row * 256 + (col & 255)] = x;
            } else if (ST16) {
                ((u16*)Cv)[row * (size_t)ldc + col] = f2b(x);
            } else {
                ((float*)Cv)[row * (size_t)ldc + col] = x;
            }
        }
    }
}

// ---------------------------------------------------------------------------
// Fused chain machinery, v3: 1024 threads (16 waves), 32 rows, wave owns one
// 16-col tile. wload() preloads ALL B-fragments of a GEMM phase into a
// register array so the 16 weight loads issue back-to-back -> ONE latency
// exposure per phase. (Best-known config: 321.7 us. MCAT-fold variants R4-R6
// hit an unfixable 64-VGPR spill signature; 16-row/2-blocks-per-CU variant
// R10 failed correctness with an unidentified defect -> both reverted.)
// MFMA order is numerics-defining: split x3 (ah*bh + al*bh + ah*bl).
// ---------------------------------------------------------------------------
template <int NK0>
struct WF { s16x8 h[NK0], l[NK0]; };

template <int NK0>
__device__ __forceinline__ void wload(const u16* __restrict__ PH,
                                      const u16* __restrict__ PL, size_t mb,
                                      int wave, int lane, WF<NK0>& w) {
#pragma unroll
    for (int k0 = 0; k0 < NK0; k0++) {
        const size_t wo = mb + ((size_t)(wave * NK0 + k0) * 64 + lane) * 8;
        w.h[k0] = *(const s16x8*)&PH[wo];
        w.l[k0] = *(const s16x8*)&PL[wo];
    }
}

template <int NK0>
__device__ __forceinline__ void cgemm_c(const WF<NK0>& w,
                                        const u16* Ch, const u16* Cl,
                                        int lane, f32x4 (&acc)[2]) {
    acc[0] = (f32x4){0.f, 0.f, 0.f, 0.f};
    acc[1] = (f32x4){0.f, 0.f, 0.f, 0.f};
#pragma unroll
    for (int k0 = 0; k0 < NK0; k0++) {
        s16x8 a0h = *(const s16x8*)&Ch[(k0 * 64 + lane) * 8];
        s16x8 a0l = *(const s16x8*)&Cl[(k0 * 64 + lane) * 8];
        s16x8 a1h = *(const s16x8*)&Ch[((8 + k0) * 64 + lane) * 8];
        s16x8 a1l = *(const s16x8*)&Cl[((8 + k0) * 64 + lane) * 8];
        acc[0] = __builtin_amdgcn_mfma_f32_16x16x32_bf16(a0h, w.h[k0], acc[0], 0, 0, 0);
        acc[0] = __builtin_amdgcn_mfma_f32_16x16x32_bf16(a0l, w.h[k0], acc[0], 0, 0, 0);
        acc[0] = __builtin_amdgcn_mfma_f32_16x16x32_bf16(a0h, w.l[k0], acc[0], 0, 0, 0);
        acc[1] = __builtin_amdgcn_mfma_f32_16x16x32_bf16(a1h, w.h[k0], acc[1], 0, 0, 0);
        acc[1] = __builtin_amdgcn_mfma_f32_16x16x32_bf16(a1l, w.h[k0], acc[1], 0, 0, 0);
        acc[1] = __builtin_amdgcn_mfma_f32_16x16x32_bf16(a1h, w.l[k0], acc[1], 0, 0, 0);
    }
}

// LN over Fv -> packed split Ch/Cl. Phase A: 32 threads/row compute stats.
// Phase B (transposed): each thread normalizes one 8-col chunk, writes uint4.
__device__ __forceinline__ void ln_split(const float* __restrict__ Fv,
                                         u16* __restrict__ Ch, u16* __restrict__ Cl,
                                         const float* __restrict__ g,
                                         const float* __restrict__ b,
                                         float* __restrict__ mean_s,
                                         float* __restrict__ rstd_s, int t) {
    {
        const int row = t >> 5, q = t & 31;
        const float* fr = Fv + row * LDF;
        float4 v0 = *(const float4*)&fr[q * 4];
        float4 v1 = *(const float4*)&fr[q * 4 + 128];
        float s1 = v0.x + v0.y + v0.z + v0.w + v1.x + v1.y + v1.z + v1.w;
        float s2 = v0.x * v0.x + v0.y * v0.y + v0.z * v0.z + v0.w * v0.w +
                   v1.x * v1.x + v1.y * v1.y + v1.z * v1.z + v1.w * v1.w;
#pragma unroll
        for (int m = 16; m >= 1; m >>= 1) {
            s1 += __shfl_xor(s1, m);
            s2 += __shfl_xor(s2, m);
        }
        if (q == 0) {
            float mean = s1 * (1.f / 256.f);
            mean_s[row] = mean;
            rstd_s[row] = rsqrtf(s2 * (1.f / 256.f) - mean * mean + 1e-5f);
        }
    }
    __syncthreads();
    {
        const int rw = t & 31, qc = t >> 5;
        const float* fr = Fv + rw * LDF + qc * 8;
        float4 v0 = *(const float4*)fr;
        float4 v1 = *(const float4*)(fr + 4);
        const float mean = mean_s[rw], rstd = rstd_s[rw];
        float4 g0 = *(const float4*)&g[qc * 8], g1 = *(const float4*)&g[qc * 8 + 4];
        float4 b0 = *(const float4*)&b[qc * 8], b1 = *(const float4*)&b[qc * 8 + 4];
        float va[8] = {v0.x, v0.y, v0.z, v0.w, v1.x, v1.y, v1.z, v1.w};
        float ga[8] = {g0.x, g0.y, g0.z, g0.w, g1.x, g1.y, g1.z, g1.w};
        float ba[8] = {b0.x, b0.y, b0.z, b0.w, b1.x, b1.y, b1.z, b1.w};
        u16 hv[8], lv[8];
#pragma unroll
        for (int j = 0; j < 8; j++) {
            float x = (va[j] - mean) * rstd * ga[j] + ba[j];
            hv[j] = f2b(x);
            lv[j] = f2b(x - b2f(hv[j]));
        }
        const int c = qc * 8;
        const int off = (((rw >> 4) * 8 + (c >> 5)) * 64 +
                         (((c >> 3) & 3) * 16 + (rw & 15))) * 8;
        *(uint4*)&Ch[off] = *(const uint4*)hv;
        *(uint4*)&Cl[off] = *(const uint4*)lv;
    }
}

// ---------------------------------------------------------------------------
// chain1: trunk_in -> [LN,fc1,fc2] x2 -> (F to global) -> LN -> q-proj
// ---------------------------------------------------------------------------
__global__ __launch_bounds__(1024) void chain1_kernel(
    const float* __restrict__ FIN, const u16* __restrict__ PH,
    const u16* __restrict__ PL, const float* __restrict__ tib,
    const float* __restrict__ lng, const float* __restrict__ lnb,
    const float* __restrict__ f1b, const float* __restrict__ f2bv,
    const float* __restrict__ bng, const float* __restrict__ bnb,
    const float* __restrict__ aib,
    float* __restrict__ Qb, float* __restrict__ Fg) {
    __shared__ u16 Ch[8192], Cl[8192];
    __shared__ float Fv[32 * LDF];
    __shared__ float mean_s[32], rstd_s[32];
    const int t = threadIdx.x;
    const int wave = t >> 6, lane = t & 63;
    const int m16 = lane & 15, quad = lane >> 4;
    const size_t rb = (size_t)blockIdx.x * 32;
    const int col = wave * 16 + m16;
    f32x4 acc[2];

    // phase 0: FIN [32,160] -> split packed
    {
        const int row = t >> 5, q = t & 31;
        if (q < 20) {
            const float* p = FIN + (rb + row) * 160 + q * 8;
            float4 v0 = *(const float4*)p, v1 = *(const float4*)(p + 4);
            float va[8] = {v0.x, v0.y, v0.z, v0.w, v1.x, v1.y, v1.z, v1.w};
            u16 hv[8], lv[8];
#pragma unroll
            for (int j = 0; j < 8; j++) { hv[j] = f2b(va[j]); lv[j] = f2b(va[j] - b2f(hv[j])); }
            const int c = q * 8;
            const int off = (((row >> 4) * 8 + (c >> 5)) * 64 +
                             (((c >> 3) & 3) * 16 + (row & 15))) * 8;
            *(uint4*)&Ch[off] = *(const uint4*)hv;
            *(uint4*)&Cl[off] = *(const uint4*)lv;
        }
    }

    // trunk_in (K=160): silu -> Fv
    {
        WF<5> w;
        wload<5>(PH, PL, 524288, wave, lane, w);
        __syncthreads();
        cgemm_c<5>(w, Ch, Cl, lane, acc);
    }
    {
        const float bb = tib[col];
#pragma unroll
        for (int rt = 0; rt < 2; rt++)
#pragma unroll
            for (int r = 0; r < 4; r++)
                Fv[(rt * 16 + quad * 4 + r) * LDF + col] = silu_f(acc[rt][r] + bb);
    }
    __syncthreads();

    // two residual blocks
#pragma unroll
    for (int L = 0; L < 2; L++) {
        ln_split(Fv, Ch, Cl, lng + L * 256, lnb + L * 256, mean_s, rstd_s, t);
        {
            WF<8> w;
            wload<8>(PH, PL, (size_t)L * 65536, wave, lane, w);  // fc1
            __syncthreads();
            cgemm_c<8>(w, Ch, Cl, lane, acc);
        }
        __syncthreads();
        {
            const float bb = f1b[L * 256 + col];
            const int k0c = col >> 5, qc4 = (col >> 3) & 3, jc = col & 7;
#pragma unroll
            for (int rt = 0; rt < 2; rt++)
#pragma unroll
                for (int r = 0; r < 4; r++) {
                    const int row = rt * 16 + quad * 4 + r;
                    float x = silu_f(acc[rt][r] + bb);
                    const int off = ((rt * 8 + k0c) * 64 + (qc4 * 16 + (row & 15))) * 8 + jc;
                    u16 h = f2b(x);
                    Ch[off] = h;
                    Cl[off] = f2b(x - b2f(h));
                }
        }
        {
            WF<8> w;
            wload<8>(PH, PL, 131072 + (size_t)L * 65536, wave, lane, w);  // fc2
            __syncthreads();
            cgemm_c<8>(w, Ch, Cl, lane, acc);
        }
        {
            const float bb = f2bv[L * 256 + col];
#pragma unroll
            for (int rt = 0; rt < 2; rt++)
#pragma unroll
                for (int r = 0; r < 4; r++) {
                    const int row = rt * 16 + quad * 4 + r;
                    Fv[row * LDF + col] += acc[rt][r] + bb;
                }
        }
        __syncthreads();
    }

    // F -> global ; LN(bn) -> packed C
    {
        const int row = t >> 5, q = t & 31;
        const float* fr = Fv + row * LDF + q * 8;
        float4 v0 = *(const float4*)fr, v1 = *(const float4*)(fr + 4);
        float* dst = Fg + (rb + row) * 256 + q * 8;
        *(float4*)dst = v0;
        *(float4*)(dst + 4) = v1;
    }
    ln_split(Fv, Ch, Cl, bng, bnb, mean_s, rstd_s, t);

    // q projection -> Qb global
    {
        WF<8> w;
        wload<8>(PH, PL, 262144, wave, lane, w);
        __syncthreads();
        cgemm_c<8>(w, Ch, Cl, lane, acc);
    }
    {
        const float bb = aib[col];
#pragma unroll
        for (int rt = 0; rt < 2; rt++)
#pragma unroll
            for (int r = 0; r < 4; r++) {
                const int row = rt * 16 + quad * 4 + r;
                Qb[(rb + row) * 256 + col] = acc[rt][r] + bb;
            }
    }
}

// ---------------------------------------------------------------------------
// chain2: attn_out -> LN -> bc1(silu) -> bc2(+res) -> C2 global
// ---------------------------------------------------------------------------
__global__ __launch_bounds__(1024) void chain2_kernel(
    const float* __restrict__ CTX, const u16* __restrict__ PH,
    const u16* __restrict__ PL, const float* __restrict__ aob,
    const float* __restrict__ clg, const float* __restrict__ clb,
    const float* __restrict__ b1, const float* __restrict__ b2v,
    float* __restrict__ C2g) {
    __shared__ u16 Ch[8192], Cl[8192];
    __shared__ float Fv[32 * LDF];
    __shared__ float mean_s[32], rstd_s[32];
    const int t = threadIdx.x;
    const int wave = t >> 6, lane = t & 63;
    const int m16 = lane & 15, quad = lane >> 4;
    const size_t rb = (size_t)blockIdx.x * 32;
    const int col = wave * 16 + m16;
    f32x4 acc[2];

    // phase 0: CTX -> split packed
    {
        const int row = t >> 5, q = t & 31;
        const float* p = CTX + (rb + row) * 256 + q * 8;
        float4 v0 = *(const float4*)p, v1 = *(const float4*)(p + 4);
        float va[8] = {v0.x, v0.y, v0.z, v0.w, v1.x, v1.y, v1.z, v1.w};
        u16 hv[8], lv[8];
#pragma unroll
        for (int j = 0; j < 8; j++) { hv[j] = f2b(va[j]); lv[j] = f2b(va[j] - b2f(hv[j])); }
        const int c = q * 8;
        const int off = (((row >> 4) * 8 + (c >> 5)) * 64 +
                         (((c >> 3) & 3) * 16 + (row & 15))) * 8;
        *(uint4*)&Ch[off] = *(const uint4*)hv;
        *(uint4*)&Cl[off] = *(const uint4*)lv;
    }

    // attn_out -> Fv
    {
        WF<8> w;
        wload<8>(PH, PL, 327680, wave, lane, w);
        __syncthreads();
        cgemm_c<8>(w, Ch, Cl, lane, acc);
    }
    {
        const float bb = aob[col];
#pragma unroll
        for (int rt = 0; rt < 2; rt++)
#pragma unroll
            for (int r = 0; r < 4; r++)
                Fv[(rt * 16 + quad * 4 + r) * LDF + col] = acc[rt][r] + bb;
    }
    __syncthreads();

    ln_split(Fv, Ch, Cl, clg, clb, mean_s, rstd_s, t);
    {
        WF<8> w;
        wload<8>(PH, PL, 393216, wave, lane, w);  // bc1
        __syncthreads();
        cgemm_c<8>(w, Ch, Cl, lane, acc);
    }
    __syncthreads();
    {
        const float bb = b1[col];
        const int k0c = col >> 5, qc4 = (col >> 3) & 3, jc = col & 7;
#pragma unroll
        for (int rt = 0; rt < 2; rt++)
#pragma unroll
            for (int r = 0; r < 4; r++) {
                const int row = rt * 16 + quad * 4 + r;
                float x = silu_f(acc[rt][r] + bb);
                const int off = ((rt * 8 + k0c) * 64 + (qc4 * 16 + (row & 15))) * 8 + jc;
                u16 h = f2b(x);
                Ch[off] = h;
                Cl[off] = f2b(x - b2f(h));
            }
    }
    {
        WF<8> w;
        wload<8>(PH, PL, 458752, wave, lane, w);  // bc2
        __syncthreads();
        cgemm_c<8>(w, Ch, Cl, lane, acc);
    }
    {
        const float bb = b2v[col];
#pragma unroll
        for (int rt = 0; rt < 2; rt++)
#pragma unroll
            for (int r = 0; r < 4; r++) {
                const int row = rt * 16 + quad * 4 + r;
                C2g[(rb + row) * 256 + col] = acc[rt][r] + bb + Fv[row * LDF + col];
            }
    }
}

// ---------------------------------------------------------------------------
// attn4: one block per query (perm-ordered). KV interleaved [16384,512] bf16.
// In-place Qb -> CTX.
// ---------------------------------------------------------------------------
__global__ __launch_bounds__(256) void attn4_kernel(
    float* __restrict__ QC, const u16* __restrict__ KV,
    const int* __restrict__ idx, const int* __restrict__ perm) {
    __shared__ u16 vsh[STOK * 264];
    __shared__ float qsh[256], attw[4][STOK];
    const int n = perm[blockIdx.x];
    const int t = threadIdx.x;
    qsh[t] = QC[(size_t)n * 256 + t];
    int ii = idx[n];
    ii = ii < 0 ? 0 : (ii > TT - 1 ? TT - 1 : ii);
    const u16* kvb = KV + (size_t)ii * STOK * 512;
#pragma unroll
    for (int i = t; i < 1024; i += 256) {
        int s = i >> 5, dq = (i & 31) * 8;
        *(uint4*)&vsh[s * 264 + dq] = *(const uint4*)&kvb[(size_t)s * 512 + 256 + dq];
    }
    __syncthreads();
    if (t < 128) {
        int h = t >> 5, s = t & 31;
        const u16* kp = kvb + (size_t)s * 512 + h * 64;
        uint4 kv[8];
#pragma unroll
        for (int dq = 0; dq < 8; dq++) kv[dq] = *(const uint4*)(kp + dq * 8);
        float p0 = 0.f, p1 = 0.f;
#pragma unroll
        for (int dq = 0; dq < 8; dq++) {
            const u16* ks = (const u16*)&kv[dq];
            float a0 = 0.f;
#pragma unroll
            for (int j = 0; j < 8; j++) a0 += qsh[h * 64 + dq * 8 + j] * b2f(ks[j]);
            if (dq & 1) p1 += a0; else p0 += a0;
        }
        float sc = (p0 + p1) * 0.125f;
        float mx = sc;
#pragma unroll
        for (int m = 16; m >= 1; m >>= 1) mx = fmaxf(mx, __shfl_xor(mx, m));
        float e = expf(sc - mx);
        float sum = e;
#pragma unroll
        for (int m = 16; m >= 1; m >>= 1) sum += __shfl_xor(sum, m);
        attw[h][s] = e / sum;
    }
    __syncthreads();
    {
        int h = t >> 6;
        float a = 0.f;
#pragma unroll 8
        for (int s = 0; s < STOK; s++) a += attw[h][s] * b2f(vsh[s * 264 + t]);
        QC[(size_t)n * 256 + t] = a;
    }
}

// ---------------------------------------------------------------------------
// final dot: out[n] = (F·H + F·v_cc + u_cc·C2 + s_cc) * exp(lt)*cs + cb
// ---------------------------------------------------------------------------
__global__ __launch_bounds__(256) void dot_kernel(
    const float* __restrict__ F, const float* __restrict__ H,
    const float* __restrict__ C2, const int* __restrict__ c,
    const float* __restrict__ U, const float* __restrict__ V,
    const float* __restrict__ S, const float* __restrict__ lt,
    const float* __restrict__ cs, const float* __restrict__ cbv,
    float* __restrict__ out) {
    const int n = blockIdx.x * 4 + (threadIdx.x >> 6);
    const int lane = threadIdx.x & 63;
    const int cc = c[n];
    float4 f4 = *(const float4*)&F[(size_t)n * 256 + lane * 4];
    float4 h4 = *(const float4*)&H[(size_t)n * 256 + lane * 4];
    float4 g4 = *(const float4*)&C2[(size_t)n * 256 + lane * 4];
    float4 v4 = *(const float4*)&V[cc * 256 + lane * 4];
    float4 u4 = *(const float4*)&U[cc * 256 + lane * 4];
    float a = f4.x * (h4.x + v4.x) + f4.y * (h4.y + v4.y) +
              f4.z * (h4.z + v4.z) + f4.w * (h4.w + v4.w) +
              u4.x * g4.x + u4.y * g4.y + u4.z * g4.z + u4.w * g4.w;
#pragma unroll
    for (int m = 32; m >= 1; m >>= 1) a += __shfl_xor(a, m);
    if (lane == 0)
        out[n] = (a + S[cc]) * expf(lt[0]) * cs[cc] + cbv[cc];
}

// ---------------------------------------------------------------------------
extern "C" void kernel_launch(void* const* d_in, const int* in_sizes, int n_in,
                              void* d_out, int out_size, void* d_ws, size_t ws_size,
                              hipStream_t stream) {
    float* out = (float*)d_out;
    const dim3 blk(256);

    static const int EXPECT[38] = {
        16384, 8192, 8192, 4194304, 512, 128, 16, 16, 24,
        38912, 256, 512, 512, 131072, 512, 131072, 512,
        65536, 256, 256, 256, 196608, 768, 65536, 256,
        256, 256, 65536, 256, 65536, 256, 196608, 768,
        196608, 768, 1, 3, 3};
    if (n_in != 38) { const_kernel<<<NQ / 256, blk, 0, stream>>>(99.0e6f, out); return; }
    for (int i = 0; i < 38; i++)
        if (in_sizes[i] != EXPECT[i]) {
            const_kernel<<<NQ / 256, blk, 0, stream>>>((100.0f + i) * 1.0e6f, out);
            return;
        }

    const float* xy  = (const float*)d_in[0];
    const float* tq  = (const float*)d_in[1];
    const int*   c   = (const int*)d_in[2];
    const float* hs  = (const float*)d_in[3];
    const float* st  = (const float*)d_in[4];
    const float* Bm  = (const float*)d_in[5];
    const float* tw  = (const float*)d_in[6];
    const float* tbv = (const float*)d_in[7];
    const float* ce  = (const float*)d_in[8];
    const float* tiw = (const float*)d_in[9];
    const float* tib = (const float*)d_in[10];
    const float* lng = (const float*)d_in[11];
    const float* lnb = (const float*)d_in[12];
    const float* f1w = (const float*)d_in[13];
    const float* f1b = (const float*)d_in[14];
    const float* f2w = (const float*)d_in[15];
    const float* f2b_ = (const float*)d_in[16];
    const float* btw = (const float*)d_in[17];
    const float* btb = (const float*)d_in[18];
    const float* bng = (const float*)d_in[19];
    const float* bnb = (const float*)d_in[20];
    const float* aiw = (const float*)d_in[21];
    const float* aib = (const float*)d_in[22];
    const float* aow = (const float*)d_in[23];
    const float* aob = (const float*)d_in[24];
    const float* clg = (const float*)d_in[25];
    const float* clb = (const float*)d_in[26];
    const float* w1  = (const float*)d_in[27];
    const float* b1  = (const float*)d_in[28];
    const float* w2  = (const float*)d_in[29];
    const float* b2  = (const float*)d_in[30];
    const float* tow = (const float*)d_in[31];
    const float* tob = (const float*)d_in[32];
    const float* bpw = (const float*)d_in[33];
    const float* bpb = (const float*)d_in[34];
    const float* lt  = (const float*)d_in[35];
    const float* cs  = (const float*)d_in[36];
    const float* cbv = (const float*)d_in[37];

    char* ws = (char*)d_ws;
    const size_t MB = 1 << 20;
    if (ws_size < 44 * MB) {
        const_kernel<<<NQ / 256, blk, 0, stream>>>(8.0e6f, out);
        return;
    }

    // KV interleaved [16384,512] bf16 = 16 MB at [0,16). Slots 8 MB each.
    u16*   KV   = (u16*)(ws + 0 * MB);
    char*  S_A  = ws + 16 * MB;   // FIN -> H (SEL output)
    char*  S_B  = ws + 24 * MB;   // F (trunk state, written once by chain1)
    char*  S_C  = ws + 32 * MB;   // Qb -> CTX (attn in-place) -> C2 (in-place)
    char*  misc = ws + 40 * MB;
    float* FIN  = (float*)S_A;
    float* H    = (float*)S_A;
    float* F    = (float*)S_B;
    float* Qb   = (float*)S_C;
    float* C2   = (float*)S_C;
    int*   IDX  = (int*)(misc + 0);                   // 32KB
    float* bkv  = (float*)(misc + 32 * 1024);         // 4KB
    float* Ubuf = (float*)(misc + 36 * 1024);
    float* Vbuf = (float*)(misc + 40 * 1024);
    float* Sbuf = (float*)(misc + 44 * 1024);
    int*   CNT  = (int*)(misc + 48 * 1024);
    int*   BASE = (int*)(misc + 52 * 1024);
    int*   CUR  = (int*)(misc + 56 * 1024);
    int*   PERM = (int*)(misc + 60 * 1024);           // 32KB -> 92K
    u16*   WKVb = (u16*)(misc + 92 * 1024);           // [512,256] 256KB -> 348K
    u16*   MCATb= (u16*)(misc + 348 * 1024);          // [768,256] 384KB -> 732K
    u16*   PH   = (u16*)(misc + 732 * 1024);          // packed hi 1104KB -> 1836K
    u16*   PL   = (u16*)(misc + 1836 * 1024);         // packed lo 1104KB -> 2940K

    const dim3 gKV(TT * STOK / 64, 8);   // M=16384, N=512
    const dim3 gSEL(NQ / 64, 12);

    // ---- prep (input-only) ----
    zero_kernel<<<2, blk, 0, stream>>>(CNT);
    pack_split<<<2208, blk, 0, stream>>>(f1w, f2w, aiw, aow, w1, w2, tiw, PH, PL);
    combine_kv32<<<512, blk, 0, stream>>>(aiw, aib, btw, btb, WKVb, bkv);
    mcat_kernel<<<dim3(16, 16, 3), blk, 0, stream>>>(tow, bpw, MCATb);
    uvs_kernel<<<3, blk, 0, stream>>>(tow, tob, bpw, bpb, Ubuf, Vbuf, Sbuf);
    feat32_kernel<<<NQ, blk, 0, stream>>>(xy, tq, c, st, Bm, tw, tbv, ce, FIN, IDX);

    // ---- sort queries by time index ----
    hist_kernel<<<NQ / 256, blk, 0, stream>>>(IDX, CNT);
    scan_kernel<<<1, dim3(512), 0, stream>>>(CNT, BASE, CUR);
    scat_kernel<<<NQ / 256, blk, 0, stream>>>(IDX, CUR, PERM);

    // ---- K/V (single merged GEMM, bf16 interleaved output) ----
    mgemm_b<1, 0><<<gKV, blk, 0, stream>>>(hs, WKVb, bkv, nullptr, KV, 512);

    // ---- fused trunk chain: 6 GEMMs in one dispatch, 16 waves/block ----
    chain1_kernel<<<NQ / 32, dim3(1024), 0, stream>>>(FIN, PH, PL, tib, lng, lnb,
                                                      f1b, f2b_, bng, bnb, aib, Qb, F);
    // ---- attention ----
    attn4_kernel<<<NQ, blk, 0, stream>>>(Qb, KV, IDX, PERM);
    // ---- fused post chain ----
    chain2_kernel<<<NQ / 32, dim3(1024), 0, stream>>>(Qb, PH, PL, aob, clg, clb,
                                                      b1, b2, C2);
    // ---- H[n] = M_{c[n]} @ C2[n] (SEL) ----
    mgemm_b<0, 1><<<gSEL, blk, 0, stream>>>(C2, MCATb, nullptr, c, H, 256);
    // ---- final dot ----
    dot_kernel<<<NQ / 4, blk, 0, stream>>>(F, H, C2, c, Ubuf, Vbuf, Sbuf, lt, cs, cbv, out);
}

// Round 12
// 286.154 us; speedup vs baseline: 1.4740x; 1.1256x over previous
//
#include <hip/hip_runtime.h>
#include <cstdint>
#include <cstddef>

typedef unsigned short u16;
typedef __attribute__((ext_vector_type(8))) short s16x8;
typedef __attribute__((ext_vector_type(4))) float f32x4;

#define NQ   8192
#define TT   512
#define STOK 32
#define LDF  260   // Fv row stride (floats): 256 + 4 pad -> bank rotation by 4/row

// prep_all block ranges
#define PB_PACK 2208
#define PB_COMB (PB_PACK + 512)    // 2720
#define PB_MCAT (PB_COMB + 768)    // 3488
#define PB_UVS  (PB_MCAT + 24)     // 3512
#define PB_TOT  (PB_UVS + NQ)      // 11704

__device__ __forceinline__ float b2f(u16 u) {
    return __uint_as_float(((uint32_t)u) << 16);
}
__device__ __forceinline__ u16 f2b(float f) {
    uint32_t x = __float_as_uint(f);
    uint32_t r = (x + 0x7FFFu + ((x >> 16) & 1u)) >> 16;
    return (u16)r;
}
__device__ __forceinline__ float silu_f(float x) { return x / (1.f + expf(-x)); }

__global__ __launch_bounds__(256) void const_kernel(float v, float* __restrict__ out) {
    int i = blockIdx.x * 256 + threadIdx.x;
    if (i < NQ) out[i] = v;
}

// ---------------------------------------------------------------------------
// zero CNT[512] + U[768] + V[768] (uvs now accumulates via atomicAdd)
// ---------------------------------------------------------------------------
__global__ __launch_bounds__(256) void zero_kernel(int* __restrict__ cnt,
                                                   float* __restrict__ U,
                                                   float* __restrict__ V) {
    int i = blockIdx.x * 256 + threadIdx.x;
    if (i < 512) cnt[i] = 0;
    else if (i < 1280) U[i - 512] = 0.f;
    else if (i < 2048) V[i - 1280] = 0.f;
}

// ---------------------------------------------------------------------------
// prep_all: merged input-only prep (R11 had these as 5 serialized dispatches;
// uvs ran 3 blocks on 256 CUs = serial latency). Block-uniform branch per
// range; uvs parallelized 8x with fp32 atomicAdd into pre-zeroed U/V.
//   [0,2208)        pack_split
//   [2208,2720)     combine_kv32
//   [2720,3488)     mcat
//   [3488,3512)     uvs (3 comps x 8 row-chunks)
//   [3512,11704)    feat32
// ---------------------------------------------------------------------------
__global__ __launch_bounds__(256) void prep_all(
    const float* __restrict__ f1w, const float* __restrict__ f2w,
    const float* __restrict__ aiw, const float* __restrict__ aow,
    const float* __restrict__ w1, const float* __restrict__ w2,
    const float* __restrict__ tiw,
    u16* __restrict__ PH, u16* __restrict__ PL,
    const float* __restrict__ aib, const float* __restrict__ btw,
    const float* __restrict__ btb, u16* __restrict__ WKVb,
    float* __restrict__ bkv,
    const float* __restrict__ tow, const float* __restrict__ bpw,
    u16* __restrict__ MCATb,
    const float* __restrict__ tob, const float* __restrict__ bpb,
    float* __restrict__ U, float* __restrict__ V, float* __restrict__ S,
    const float* __restrict__ xy, const float* __restrict__ t_q,
    const int* __restrict__ c, const float* __restrict__ st,
    const float* __restrict__ B, const float* __restrict__ tw,
    const float* __restrict__ tb, const float* __restrict__ ce,
    float* __restrict__ FIN, int* __restrict__ IDX) {
    __shared__ float As2[16][17], Bs2[16][17];
    __shared__ float wrow[256];
    __shared__ float red[4];
    const int b = blockIdx.x;
    const int t = threadIdx.x;

    if (b < PB_PACK) {
        // ---- pack_split: chain weights -> MFMA-fragment-linear bf16 hi/lo
        int i = b * 256 + t;
        if (i >= 565248) return;
        float v;
        size_t pos;
        if (i < 524288) {
            int m = i >> 16, j = i & 65535;
            int col = j >> 8, k = j & 255;
            const float* src;
            switch (m) {
                case 0: src = f1w; break;
                case 1: src = f1w + 65536; break;
                case 2: src = f2w; break;
                case 3: src = f2w + 65536; break;
                case 4: src = aiw; break;      // wq = rows 0..255 of attn_in_w
                case 5: src = aow; break;
                case 6: src = w1; break;
                default: src = w2; break;
            }
            v = src[j];
            int ct = col >> 4, m16 = col & 15, k0 = k >> 5, quad = (k >> 3) & 3, jj = k & 7;
            pos = (size_t)m * 65536 + (size_t)(((ct * 8 + k0) * 64 + quad * 16 + m16) * 8 + jj);
        } else {
            int j = i - 524288;                // 0..40959
            int col = j / 160, k = j % 160;
            v = (k < 152) ? tiw[col * 152 + k] : 0.f;
            int ct = col >> 4, m16 = col & 15, k0 = k >> 5, quad = (k >> 3) & 3, jj = k & 7;
            pos = 524288 + (size_t)(((ct * 5 + k0) * 64 + quad * 16 + m16) * 8 + jj);
        }
        u16 h = f2b(v);
        PH[pos] = h;
        PL[pos] = f2b(v - b2f(h));
    } else if (b < PB_COMB) {
        // ---- combine_kv32: fold token projection into K/V weights
        int bb = b - PB_PACK;
        int kv = bb >> 8, m = bb & 255;
        int d = t;
        wrow[d] = aiw[(size_t)(kv + 1) * 65536 + (size_t)m * 256 + d];
        __syncthreads();
        float acc = 0.f;
#pragma unroll 8
        for (int o = 0; o < 256; o++) acc += wrow[o] * btw[(size_t)o * 256 + d];
        WKVb[(size_t)kv * 65536 + (size_t)m * 256 + d] = f2b(acc);
        float pb = wrow[d] * btb[d];
#pragma unroll
        for (int mm = 32; mm >= 1; mm >>= 1) pb += __shfl_xor(pb, mm);
        if ((d & 63) == 0) red[d >> 6] = pb;
        __syncthreads();
        if (d == 0)
            bkv[kv * 256 + m] = red[0] + red[1] + red[2] + red[3] + aib[(kv + 1) * 256 + m];
    } else if (b < PB_MCAT) {
        // ---- mcat: M_c = tow_c^T @ bpw_c, bf16 out
        int m = b - PB_COMB;
        const int cc = m >> 8;
        const int rem = m & 255;
        const int t0 = (rem >> 4) * 16, k0 = (rem & 15) * 16;
        const int lt = t & 15, lj = t >> 4;
        const int ot = t & 15, ok = t >> 4;
        float acc = 0.f;
        for (int j0 = 0; j0 < 256; j0 += 16) {
            As2[lj][lt] = tow[((size_t)cc * 256 + j0 + lj) * 256 + t0 + lt];
            Bs2[lj][lt] = bpw[((size_t)cc * 256 + j0 + lj) * 256 + k0 + lt];
            __syncthreads();
#pragma unroll
            for (int jj = 0; jj < 16; jj++) acc += As2[jj][ot] * Bs2[jj][ok];
            __syncthreads();
        }
        MCATb[((size_t)cc * 256 + t0 + ot) * 256 + k0 + ok] = f2b(acc);
    } else if (b < PB_UVS) {
        // ---- uvs (8x parallel per comp, atomicAdd into zeroed U/V)
        int m = b - PB_MCAT;
        const int cc = m / 8, j = m % 8;
        float v = 0.f, u = 0.f;
        for (int r = j * 32; r < j * 32 + 32; r++) {
            v += tow[((size_t)cc * 256 + r) * 256 + t] * bpb[cc * 256 + r];
            u += bpw[((size_t)cc * 256 + r) * 256 + t] * tob[cc * 256 + r];
        }
        atomicAdd(&V[cc * 256 + t], v);
        atomicAdd(&U[cc * 256 + t], u);
        if (j == 0) {
            float sp = tob[cc * 256 + t] * bpb[cc * 256 + t];
#pragma unroll
            for (int mm = 32; mm >= 1; mm >>= 1) sp += __shfl_xor(sp, mm);
            if ((t & 63) == 0) red[t >> 6] = sp;
            __syncthreads();
            if (t == 0) S[cc] = red[0] + red[1] + red[2] + red[3];
        }
    } else {
        // ---- feat32: FIN fp32 [NQ,160] (cols 152..159 = 0), IDX
        int n = b - PB_UVS;
        float tq = t_q[n];
        int lo = 0, hi = TT;
        while (lo < hi) {
            int mid = (lo + hi) >> 1;
            if (st[mid] <= tq) lo = mid + 1; else hi = mid;
        }
        int idx = lo - 1;
        if (idx < 0) idx = 0;
        float dt = tq - st[idx];
        if (dt < 0.f) dt = 0.f;
        if (t == 0) IDX[n] = idx;
        float x = xy[2 * n], y = xy[2 * n + 1];
        size_t base = (size_t)n * 160;
        if (t < 64) { float p = x * B[t] + y * B[64 + t]; FIN[base + t] = cosf(p); }
        else if (t < 128) { int j = t - 64; float p = x * B[j] + y * B[64 + j]; FIN[base + t] = sinf(p); }
        else if (t < 144) { int j = t - 128; FIN[base + t] = dt * tw[j] + tb[j]; }
        else if (t < 152) { int j = t - 144; FIN[base + t] = ce[c[n] * 8 + j]; }
        else if (t < 160) { FIN[base + t] = 0.f; }
    }
}

// ---------------------------------------------------------------------------
// counting-sort of queries by IDX (512 buckets) -> perm
// ---------------------------------------------------------------------------
__global__ __launch_bounds__(256) void hist_kernel(const int* __restrict__ IDX,
                                                   int* __restrict__ cnt) {
    int n = blockIdx.x * 256 + threadIdx.x;
    if (n < NQ) atomicAdd(&cnt[IDX[n]], 1);
}
__global__ __launch_bounds__(512) void scan_kernel(const int* __restrict__ cnt,
                                                   int* __restrict__ base,
                                                   int* __restrict__ cur) {
    __shared__ int s[TT];
    int t = threadIdx.x;
    int v = cnt[t];
    s[t] = v;
    __syncthreads();
    for (int off = 1; off < TT; off <<= 1) {
        int add = (t >= off) ? s[t - off] : 0;
        __syncthreads();
        s[t] += add;
        __syncthreads();
    }
    base[t] = s[t] - v;
    cur[t] = s[t] - v;
}
__global__ __launch_bounds__(256) void scat_kernel(const int* __restrict__ IDX,
                                                   int* __restrict__ cur,
                                                   int* __restrict__ perm) {
    int n = blockIdx.x * 256 + threadIdx.x;
    if (n < NQ) {
        int pos = atomicAdd(&cur[IDX[n]], 1);
        perm[pos] = n;
    }
}

// ---------------------------------------------------------------------------
// mgemm_b: MFMA bf16 GEMM, A fp32 (converted on the fly), W pre-converted
// bf16. K=256, output stride ldc. ST16: store bf16. SEL: component select.
// ---------------------------------------------------------------------------
template <int ST16, int SEL>
__global__ __launch_bounds__(256) void mgemm_b(
    const float* __restrict__ A, const u16* __restrict__ Wb,
    const float* __restrict__ bias, const int* __restrict__ csel,
    void* __restrict__ Cv, int ldc) {
    __shared__ u16 As[64 * 40];
    __shared__ u16 Ws[64 * 40];
    const int t = threadIdx.x;
    const size_t rb = (size_t)blockIdx.x * 64;
    const size_t cb = (size_t)blockIdx.y * 64;
    const int wave = t >> 6, lane = t & 63;
    const int m16 = lane & 15, quad = lane >> 4;
    const int sr = t >> 2, sk = (t & 3) * 8;
    const float* Ap = A + (rb + sr) * 256 + sk;
    const u16* Wp = Wb + (cb + sr) * 256 + sk;

    f32x4 acc[4] = {};
    for (int k0 = 0; k0 < 256; k0 += 32) {
        float4 a0 = *(const float4*)(Ap + k0);
        float4 a1 = *(const float4*)(Ap + k0 + 4);
        u16 ta[8] = {f2b(a0.x), f2b(a0.y), f2b(a0.z), f2b(a0.w),
                     f2b(a1.x), f2b(a1.y), f2b(a1.z), f2b(a1.w)};
        *(uint4*)&As[sr * 40 + sk] = *(const uint4*)ta;
        *(uint4*)&Ws[sr * 40 + sk] = *(const uint4*)(Wp + k0);
        __syncthreads();
        s16x8 af = *(const s16x8*)&As[(wave * 16 + m16) * 40 + quad * 8];
#pragma unroll
        for (int ct = 0; ct < 4; ct++) {
            s16x8 bf = *(const s16x8*)&Ws[(ct * 16 + m16) * 40 + quad * 8];
            acc[ct] = __builtin_amdgcn_mfma_f32_16x16x32_bf16(af, bf, acc[ct], 0, 0, 0);
        }
        __syncthreads();
    }
#pragma unroll
    for (int ct = 0; ct < 4; ct++) {
        size_t col = cb + ct * 16 + m16;
        float bb = bias ? bias[col] : 0.f;
#pragma unroll
        for (int r = 0; r < 4; r++) {
            size_t row = rb + wave * 16 + quad * 4 + r;
            float x = acc[ct][r] + bb;
            if (SEL) {
                int comp = (int)(col >> 8);
                if (csel[row] == comp)
                    ((float*)Cv)[row * 256 + (col & 255)] = x;
            } else if (ST16) {
                ((u16*)Cv)[row * (size_t)ldc + col] = f2b(x);
            } else {
                ((float*)Cv)[row * (size_t)ldc + col] = x;
            }
        }
    }
}

// ---------------------------------------------------------------------------
// Fused chain machinery, v3: 1024 threads (16 waves), 32 rows, wave owns one
// 16-col tile. wload() preloads ALL B-fragments of a GEMM phase into a
// register array so the 16 weight loads issue back-to-back -> ONE latency
// exposure per phase. (Best-known config: 321.7-322.1 us. MCAT-fold R4-R6:
// spill signature; 16-row 2-blocks/CU R10: correctness failure -> reverted.)
// MFMA order is numerics-defining: split x3 (ah*bh + al*bh + ah*bl).
// ---------------------------------------------------------------------------
template <int NK0>
struct WF { s16x8 h[NK0], l[NK0]; };

template <int NK0>
__device__ __forceinline__ void wload(const u16* __restrict__ PH,
                                      const u16* __restrict__ PL, size_t mb,
                                      int wave, int lane, WF<NK0>& w) {
#pragma unroll
    for (int k0 = 0; k0 < NK0; k0++) {
        const size_t wo = mb + ((size_t)(wave * NK0 + k0) * 64 + lane) * 8;
        w.h[k0] = *(const s16x8*)&PH[wo];
        w.l[k0] = *(const s16x8*)&PL[wo];
    }
}

template <int NK0>
__device__ __forceinline__ void cgemm_c(const WF<NK0>& w,
                                        const u16* Ch, const u16* Cl,
                                        int lane, f32x4 (&acc)[2]) {
    acc[0] = (f32x4){0.f, 0.f, 0.f, 0.f};
    acc[1] = (f32x4){0.f, 0.f, 0.f, 0.f};
#pragma unroll
    for (int k0 = 0; k0 < NK0; k0++) {
        s16x8 a0h = *(const s16x8*)&Ch[(k0 * 64 + lane) * 8];
        s16x8 a0l = *(const s16x8*)&Cl[(k0 * 64 + lane) * 8];
        s16x8 a1h = *(const s16x8*)&Ch[((8 + k0) * 64 + lane) * 8];
        s16x8 a1l = *(const s16x8*)&Cl[((8 + k0) * 64 + lane) * 8];
        acc[0] = __builtin_amdgcn_mfma_f32_16x16x32_bf16(a0h, w.h[k0], acc[0], 0, 0, 0);
        acc[0] = __builtin_amdgcn_mfma_f32_16x16x32_bf16(a0l, w.h[k0], acc[0], 0, 0, 0);
        acc[0] = __builtin_amdgcn_mfma_f32_16x16x32_bf16(a0h, w.l[k0], acc[0], 0, 0, 0);
        acc[1] = __builtin_amdgcn_mfma_f32_16x16x32_bf16(a1h, w.h[k0], acc[1], 0, 0, 0);
        acc[1] = __builtin_amdgcn_mfma_f32_16x16x32_bf16(a1l, w.h[k0], acc[1], 0, 0, 0);
        acc[1] = __builtin_amdgcn_mfma_f32_16x16x32_bf16(a1h, w.l[k0], acc[1], 0, 0, 0);
    }
}

// LN over Fv -> packed split Ch/Cl. Phase A: 32 threads/row compute stats.
// Phase B (transposed): each thread normalizes one 8-col chunk, writes uint4.
__device__ __forceinline__ void ln_split(const float* __restrict__ Fv,
                                         u16* __restrict__ Ch, u16* __restrict__ Cl,
                                         const float* __restrict__ g,
                                         const float* __restrict__ b,
                                         float* __restrict__ mean_s,
                                         float* __restrict__ rstd_s, int t) {
    {
        const int row = t >> 5, q = t & 31;
        const float* fr = Fv + row * LDF;
        float4 v0 = *(const float4*)&fr[q * 4];
        float4 v1 = *(const float4*)&fr[q * 4 + 128];
        float s1 = v0.x + v0.y + v0.z + v0.w + v1.x + v1.y + v1.z + v1.w;
        float s2 = v0.x * v0.x + v0.y * v0.y + v0.z * v0.z + v0.w * v0.w +
                   v1.x * v1.x + v1.y * v1.y + v1.z * v1.z + v1.w * v1.w;
#pragma unroll
        for (int m = 16; m >= 1; m >>= 1) {
            s1 += __shfl_xor(s1, m);
            s2 += __shfl_xor(s2, m);
        }
        if (q == 0) {
            float mean = s1 * (1.f / 256.f);
            mean_s[row] = mean;
            rstd_s[row] = rsqrtf(s2 * (1.f / 256.f) - mean * mean + 1e-5f);
        }
    }
    __syncthreads();
    {
        const int rw = t & 31, qc = t >> 5;
        const float* fr = Fv + rw * LDF + qc * 8;
        float4 v0 = *(const float4*)fr;
        float4 v1 = *(const float4*)(fr + 4);
        const float mean = mean_s[rw], rstd = rstd_s[rw];
        float4 g0 = *(const float4*)&g[qc * 8], g1 = *(const float4*)&g[qc * 8 + 4];
        float4 b0 = *(const float4*)&b[qc * 8], b1 = *(const float4*)&b[qc * 8 + 4];
        float va[8] = {v0.x, v0.y, v0.z, v0.w, v1.x, v1.y, v1.z, v1.w};
        float ga[8] = {g0.x, g0.y, g0.z, g0.w, g1.x, g1.y, g1.z, g1.w};
        float ba[8] = {b0.x, b0.y, b0.z, b0.w, b1.x, b1.y, b1.z, b1.w};
        u16 hv[8], lv[8];
#pragma unroll
        for (int j = 0; j < 8; j++) {
            float x = (va[j] - mean) * rstd * ga[j] + ba[j];
            hv[j] = f2b(x);
            lv[j] = f2b(x - b2f(hv[j]));
        }
        const int c = qc * 8;
        const int off = (((rw >> 4) * 8 + (c >> 5)) * 64 +
                         (((c >> 3) & 3) * 16 + (rw & 15))) * 8;
        *(uint4*)&Ch[off] = *(const uint4*)hv;
        *(uint4*)&Cl[off] = *(const uint4*)lv;
    }
}

// ---------------------------------------------------------------------------
// chain1: trunk_in -> [LN,fc1,fc2] x2 -> (F to global) -> LN -> q-proj
// ---------------------------------------------------------------------------
__global__ __launch_bounds__(1024) void chain1_kernel(
    const float* __restrict__ FIN, const u16* __restrict__ PH,
    const u16* __restrict__ PL, const float* __restrict__ tib,
    const float* __restrict__ lng, const float* __restrict__ lnb,
    const float* __restrict__ f1b, const float* __restrict__ f2bv,
    const float* __restrict__ bng, const float* __restrict__ bnb,
    const float* __restrict__ aib,
    float* __restrict__ Qb, float* __restrict__ Fg) {
    __shared__ u16 Ch[8192], Cl[8192];
    __shared__ float Fv[32 * LDF];
    __shared__ float mean_s[32], rstd_s[32];
    const int t = threadIdx.x;
    const int wave = t >> 6, lane = t & 63;
    const int m16 = lane & 15, quad = lane >> 4;
    const size_t rb = (size_t)blockIdx.x * 32;
    const int col = wave * 16 + m16;
    f32x4 acc[2];

    // phase 0: FIN [32,160] -> split packed
    {
        const int row = t >> 5, q = t & 31;
        if (q < 20) {
            const float* p = FIN + (rb + row) * 160 + q * 8;
            float4 v0 = *(const float4*)p, v1 = *(const float4*)(p + 4);
            float va[8] = {v0.x, v0.y, v0.z, v0.w, v1.x, v1.y, v1.z, v1.w};
            u16 hv[8], lv[8];
#pragma unroll
            for (int j = 0; j < 8; j++) { hv[j] = f2b(va[j]); lv[j] = f2b(va[j] - b2f(hv[j])); }
            const int c = q * 8;
            const int off = (((row >> 4) * 8 + (c >> 5)) * 64 +
                             (((c >> 3) & 3) * 16 + (row & 15))) * 8;
            *(uint4*)&Ch[off] = *(const uint4*)hv;
            *(uint4*)&Cl[off] = *(const uint4*)lv;
        }
    }

    // trunk_in (K=160): silu -> Fv
    {
        WF<5> w;
        wload<5>(PH, PL, 524288, wave, lane, w);
        __syncthreads();
        cgemm_c<5>(w, Ch, Cl, lane, acc);
    }
    {
        const float bb = tib[col];
#pragma unroll
        for (int rt = 0; rt < 2; rt++)
#pragma unroll
            for (int r = 0; r < 4; r++)
                Fv[(rt * 16 + quad * 4 + r) * LDF + col] = silu_f(acc[rt][r] + bb);
    }
    __syncthreads();

    // two residual blocks
#pragma unroll
    for (int L = 0; L < 2; L++) {
        ln_split(Fv, Ch, Cl, lng + L * 256, lnb + L * 256, mean_s, rstd_s, t);
        {
            WF<8> w;
            wload<8>(PH, PL, (size_t)L * 65536, wave, lane, w);  // fc1
            __syncthreads();
            cgemm_c<8>(w, Ch, Cl, lane, acc);
        }
        __syncthreads();
        {
            const float bb = f1b[L * 256 + col];
            const int k0c = col >> 5, qc4 = (col >> 3) & 3, jc = col & 7;
#pragma unroll
            for (int rt = 0; rt < 2; rt++)
#pragma unroll
                for (int r = 0; r < 4; r++) {
                    const int row = rt * 16 + quad * 4 + r;
                    float x = silu_f(acc[rt][r] + bb);
                    const int off = ((rt * 8 + k0c) * 64 + (qc4 * 16 + (row & 15))) * 8 + jc;
                    u16 h = f2b(x);
                    Ch[off] = h;
                    Cl[off] = f2b(x - b2f(h));
                }
        }
        {
            WF<8> w;
            wload<8>(PH, PL, 131072 + (size_t)L * 65536, wave, lane, w);  // fc2
            __syncthreads();
            cgemm_c<8>(w, Ch, Cl, lane, acc);
        }
        {
            const float bb = f2bv[L * 256 + col];
#pragma unroll
            for (int rt = 0; rt < 2; rt++)
#pragma unroll
                for (int r = 0; r < 4; r++) {
                    const int row = rt * 16 + quad * 4 + r;
                    Fv[row * LDF + col] += acc[rt][r] + bb;
                }
        }
        __syncthreads();
    }

    // F -> global ; LN(bn) -> packed C
    {
        const int row = t >> 5, q = t & 31;
        const float* fr = Fv + row * LDF + q * 8;
        float4 v0 = *(const float4*)fr, v1 = *(const float4*)(fr + 4);
        float* dst = Fg + (rb + row) * 256 + q * 8;
        *(float4*)dst = v0;
        *(float4*)(dst + 4) = v1;
    }
    ln_split(Fv, Ch, Cl, bng, bnb, mean_s, rstd_s, t);

    // q projection -> Qb global
    {
        WF<8> w;
        wload<8>(PH, PL, 262144, wave, lane, w);
        __syncthreads();
        cgemm_c<8>(w, Ch, Cl, lane, acc);
    }
    {
        const float bb = aib[col];
#pragma unroll
        for (int rt = 0; rt < 2; rt++)
#pragma unroll
            for (int r = 0; r < 4; r++) {
                const int row = rt * 16 + quad * 4 + r;
                Qb[(rb + row) * 256 + col] = acc[rt][r] + bb;
            }
    }
}

// ---------------------------------------------------------------------------
// chain2: attn_out -> LN -> bc1(silu) -> bc2(+res) -> C2 global
// ---------------------------------------------------------------------------
__global__ __launch_bounds__(1024) void chain2_kernel(
    const float* __restrict__ CTX, const u16* __restrict__ PH,
    const u16* __restrict__ PL, const float* __restrict__ aob,
    const float* __restrict__ clg, const float* __restrict__ clb,
    const float* __restrict__ b1, const float* __restrict__ b2v,
    float* __restrict__ C2g) {
    __shared__ u16 Ch[8192], Cl[8192];
    __shared__ float Fv[32 * LDF];
    __shared__ float mean_s[32], rstd_s[32];
    const int t = threadIdx.x;
    const int wave = t >> 6, lane = t & 63;
    const int m16 = lane & 15, quad = lane >> 4;
    const size_t rb = (size_t)blockIdx.x * 32;
    const int col = wave * 16 + m16;
    f32x4 acc[2];

    // phase 0: CTX -> split packed
    {
        const int row = t >> 5, q = t & 31;
        const float* p = CTX + (rb + row) * 256 + q * 8;
        float4 v0 = *(const float4*)p, v1 = *(const float4*)(p + 4);
        float va[8] = {v0.x, v0.y, v0.z, v0.w, v1.x, v1.y, v1.z, v1.w};
        u16 hv[8], lv[8];
#pragma unroll
        for (int j = 0; j < 8; j++) { hv[j] = f2b(va[j]); lv[j] = f2b(va[j] - b2f(hv[j])); }
        const int c = q * 8;
        const int off = (((row >> 4) * 8 + (c >> 5)) * 64 +
                         (((c >> 3) & 3) * 16 + (row & 15))) * 8;
        *(uint4*)&Ch[off] = *(const uint4*)hv;
        *(uint4*)&Cl[off] = *(const uint4*)lv;
    }

    // attn_out -> Fv
    {
        WF<8> w;
        wload<8>(PH, PL, 327680, wave, lane, w);
        __syncthreads();
        cgemm_c<8>(w, Ch, Cl, lane, acc);
    }
    {
        const float bb = aob[col];
#pragma unroll
        for (int rt = 0; rt < 2; rt++)
#pragma unroll
            for (int r = 0; r < 4; r++)
                Fv[(rt * 16 + quad * 4 + r) * LDF + col] = acc[rt][r] + bb;
    }
    __syncthreads();

    ln_split(Fv, Ch, Cl, clg, clb, mean_s, rstd_s, t);
    {
        WF<8> w;
        wload<8>(PH, PL, 393216, wave, lane, w);  // bc1
        __syncthreads();
        cgemm_c<8>(w, Ch, Cl, lane, acc);
    }
    __syncthreads();
    {
        const float bb = b1[col];
        const int k0c = col >> 5, qc4 = (col >> 3) & 3, jc = col & 7;
#pragma unroll
        for (int rt = 0; rt < 2; rt++)
#pragma unroll
            for (int r = 0; r < 4; r++) {
                const int row = rt * 16 + quad * 4 + r;
                float x = silu_f(acc[rt][r] + bb);
                const int off = ((rt * 8 + k0c) * 64 + (qc4 * 16 + (row & 15))) * 8 + jc;
                u16 h = f2b(x);
                Ch[off] = h;
                Cl[off] = f2b(x - b2f(h));
            }
    }
    {
        WF<8> w;
        wload<8>(PH, PL, 458752, wave, lane, w);  // bc2
        __syncthreads();
        cgemm_c<8>(w, Ch, Cl, lane, acc);
    }
    {
        const float bb = b2v[col];
#pragma unroll
        for (int rt = 0; rt < 2; rt++)
#pragma unroll
            for (int r = 0; r < 4; r++) {
                const int row = rt * 16 + quad * 4 + r;
                C2g[(rb + row) * 256 + col] = acc[rt][r] + bb + Fv[row * LDF + col];
            }
    }
}

// ---------------------------------------------------------------------------
// attn4: one block per query (perm-ordered). KV interleaved [16384,512] bf16.
// In-place Qb -> CTX.
// ---------------------------------------------------------------------------
__global__ __launch_bounds__(256) void attn4_kernel(
    float* __restrict__ QC, const u16* __restrict__ KV,
    const int* __restrict__ idx, const int* __restrict__ perm) {
    __shared__ u16 vsh[STOK * 264];
    __shared__ float qsh[256], attw[4][STOK];
    const int n = perm[blockIdx.x];
    const int t = threadIdx.x;
    qsh[t] = QC[(size_t)n * 256 + t];
    int ii = idx[n];
    ii = ii < 0 ? 0 : (ii > TT - 1 ? TT - 1 : ii);
    const u16* kvb = KV + (size_t)ii * STOK * 512;
#pragma unroll
    for (int i = t; i < 1024; i += 256) {
        int s = i >> 5, dq = (i & 31) * 8;
        *(uint4*)&vsh[s * 264 + dq] = *(const uint4*)&kvb[(size_t)s * 512 + 256 + dq];
    }
    __syncthreads();
    if (t < 128) {
        int h = t >> 5, s = t & 31;
        const u16* kp = kvb + (size_t)s * 512 + h * 64;
        uint4 kv[8];
#pragma unroll
        for (int dq = 0; dq < 8; dq++) kv[dq] = *(const uint4*)(kp + dq * 8);
        float p0 = 0.f, p1 = 0.f;
#pragma unroll
        for (int dq = 0; dq < 8; dq++) {
            const u16* ks = (const u16*)&kv[dq];
            float a0 = 0.f;
#pragma unroll
            for (int j = 0; j < 8; j++) a0 += qsh[h * 64 + dq * 8 + j] * b2f(ks[j]);
            if (dq & 1) p1 += a0; else p0 += a0;
        }
        float sc = (p0 + p1) * 0.125f;
        float mx = sc;
#pragma unroll
        for (int m = 16; m >= 1; m >>= 1) mx = fmaxf(mx, __shfl_xor(mx, m));
        float e = expf(sc - mx);
        float sum = e;
#pragma unroll
        for (int m = 16; m >= 1; m >>= 1) sum += __shfl_xor(sum, m);
        attw[h][s] = e / sum;
    }
    __syncthreads();
    {
        int h = t >> 6;
        float a = 0.f;
#pragma unroll 8
        for (int s = 0; s < STOK; s++) a += attw[h][s] * b2f(vsh[s * 264 + t]);
        QC[(size_t)n * 256 + t] = a;
    }
}

// ---------------------------------------------------------------------------
// final dot: out[n] = (F·H + F·v_cc + u_cc·C2 + s_cc) * exp(lt)*cs + cb
// ---------------------------------------------------------------------------
__global__ __launch_bounds__(256) void dot_kernel(
    const float* __restrict__ F, const float* __restrict__ H,
    const float* __restrict__ C2, const int* __restrict__ c,
    const float* __restrict__ U, const float* __restrict__ V,
    const float* __restrict__ S, const float* __restrict__ lt,
    const float* __restrict__ cs, const float* __restrict__ cbv,
    float* __restrict__ out) {
    const int n = blockIdx.x * 4 + (threadIdx.x >> 6);
    const int lane = threadIdx.x & 63;
    const int cc = c[n];
    float4 f4 = *(const float4*)&F[(size_t)n * 256 + lane * 4];
    float4 h4 = *(const float4*)&H[(size_t)n * 256 + lane * 4];
    float4 g4 = *(const float4*)&C2[(size_t)n * 256 + lane * 4];
    float4 v4 = *(const float4*)&V[cc * 256 + lane * 4];
    float4 u4 = *(const float4*)&U[cc * 256 + lane * 4];
    float a = f4.x * (h4.x + v4.x) + f4.y * (h4.y + v4.y) +
              f4.z * (h4.z + v4.z) + f4.w * (h4.w + v4.w) +
              u4.x * g4.x + u4.y * g4.y + u4.z * g4.z + u4.w * g4.w;
#pragma unroll
    for (int m = 32; m >= 1; m >>= 1) a += __shfl_xor(a, m);
    if (lane == 0)
        out[n] = (a + S[cc]) * expf(lt[0]) * cs[cc] + cbv[cc];
}

// ---------------------------------------------------------------------------
extern "C" void kernel_launch(void* const* d_in, const int* in_sizes, int n_in,
                              void* d_out, int out_size, void* d_ws, size_t ws_size,
                              hipStream_t stream) {
    float* out = (float*)d_out;
    const dim3 blk(256);

    static const int EXPECT[38] = {
        16384, 8192, 8192, 4194304, 512, 128, 16, 16, 24,
        38912, 256, 512, 512, 131072, 512, 131072, 512,
        65536, 256, 256, 256, 196608, 768, 65536, 256,
        256, 256, 65536, 256, 65536, 256, 196608, 768,
        196608, 768, 1, 3, 3};
    if (n_in != 38) { const_kernel<<<NQ / 256, blk, 0, stream>>>(99.0e6f, out); return; }
    for (int i = 0; i < 38; i++)
        if (in_sizes[i] != EXPECT[i]) {
            const_kernel<<<NQ / 256, blk, 0, stream>>>((100.0f + i) * 1.0e6f, out);
            return;
        }

    const float* xy  = (const float*)d_in[0];
    const float* tq  = (const float*)d_in[1];
    const int*   c   = (const int*)d_in[2];
    const float* hs  = (const float*)d_in[3];
    const float* st  = (const float*)d_in[4];
    const float* Bm  = (const float*)d_in[5];
    const float* tw  = (const float*)d_in[6];
    const float* tbv = (const float*)d_in[7];
    const float* ce  = (const float*)d_in[8];
    const float* tiw = (const float*)d_in[9];
    const float* tib = (const float*)d_in[10];
    const float* lng = (const float*)d_in[11];
    const float* lnb = (const float*)d_in[12];
    const float* f1w = (const float*)d_in[13];
    const float* f1b = (const float*)d_in[14];
    const float* f2w = (const float*)d_in[15];
    const float* f2b_ = (const float*)d_in[16];
    const float* btw = (const float*)d_in[17];
    const float* btb = (const float*)d_in[18];
    const float* bng = (const float*)d_in[19];
    const float* bnb = (const float*)d_in[20];
    const float* aiw = (const float*)d_in[21];
    const float* aib = (const float*)d_in[22];
    const float* aow = (const float*)d_in[23];
    const float* aob = (const float*)d_in[24];
    const float* clg = (const float*)d_in[25];
    const float* clb = (const float*)d_in[26];
    const float* w1  = (const float*)d_in[27];
    const float* b1  = (const float*)d_in[28];
    const float* w2  = (const float*)d_in[29];
    const float* b2  = (const float*)d_in[30];
    const float* tow = (const float*)d_in[31];
    const float* tob = (const float*)d_in[32];
    const float* bpw = (const float*)d_in[33];
    const float* bpb = (const float*)d_in[34];
    const float* lt  = (const float*)d_in[35];
    const float* cs  = (const float*)d_in[36];
    const float* cbv = (const float*)d_in[37];

    char* ws = (char*)d_ws;
    const size_t MB = 1 << 20;
    if (ws_size < 44 * MB) {
        const_kernel<<<NQ / 256, blk, 0, stream>>>(8.0e6f, out);
        return;
    }

    // KV interleaved [16384,512] bf16 = 16 MB at [0,16). Slots 8 MB each.
    u16*   KV   = (u16*)(ws + 0 * MB);
    char*  S_A  = ws + 16 * MB;   // FIN -> H (SEL output)
    char*  S_B  = ws + 24 * MB;   // F (trunk state, written once by chain1)
    char*  S_C  = ws + 32 * MB;   // Qb -> CTX (attn in-place) -> C2 (in-place)
    char*  misc = ws + 40 * MB;
    float* FIN  = (float*)S_A;
    float* H    = (float*)S_A;
    float* F    = (float*)S_B;
    float* Qb   = (float*)S_C;
    float* C2   = (float*)S_C;
    int*   IDX  = (int*)(misc + 0);                   // 32KB
    float* bkv  = (float*)(misc + 32 * 1024);         // 4KB
    float* Ubuf = (float*)(misc + 36 * 1024);
    float* Vbuf = (float*)(misc + 40 * 1024);
    float* Sbuf = (float*)(misc + 44 * 1024);
    int*   CNT  = (int*)(misc + 48 * 1024);
    int*   BASE = (int*)(misc + 52 * 1024);
    int*   CUR  = (int*)(misc + 56 * 1024);
    int*   PERM = (int*)(misc + 60 * 1024);           // 32KB -> 92K
    u16*   WKVb = (u16*)(misc + 92 * 1024);           // [512,256] 256KB -> 348K
    u16*   MCATb= (u16*)(misc + 348 * 1024);          // [768,256] 384KB -> 732K
    u16*   PH   = (u16*)(misc + 732 * 1024);          // packed hi 1104KB -> 1836K
    u16*   PL   = (u16*)(misc + 1836 * 1024);         // packed lo 1104KB -> 2940K

    const dim3 gKV(TT * STOK / 64, 8);   // M=16384, N=512
    const dim3 gSEL(NQ / 64, 12);

    // ---- prep: zero, then single merged input-only kernel ----
    zero_kernel<<<8, blk, 0, stream>>>(CNT, Ubuf, Vbuf);
    prep_all<<<PB_TOT, blk, 0, stream>>>(
        f1w, f2w, aiw, aow, w1, w2, tiw, PH, PL,
        aib, btw, btb, WKVb, bkv,
        tow, bpw, MCATb,
        tob, bpb, Ubuf, Vbuf, Sbuf,
        xy, tq, c, st, Bm, tw, tbv, ce, FIN, IDX);

    // ---- sort queries by time index ----
    hist_kernel<<<NQ / 256, blk, 0, stream>>>(IDX, CNT);
    scan_kernel<<<1, dim3(512), 0, stream>>>(CNT, BASE, CUR);
    scat_kernel<<<NQ / 256, blk, 0, stream>>>(IDX, CUR, PERM);

    // ---- K/V (single merged GEMM, bf16 interleaved output) ----
    mgemm_b<1, 0><<<gKV, blk, 0, stream>>>(hs, WKVb, bkv, nullptr, KV, 512);

    // ---- fused trunk chain: 6 GEMMs in one dispatch, 16 waves/block ----
    chain1_kernel<<<NQ / 32, dim3(1024), 0, stream>>>(FIN, PH, PL, tib, lng, lnb,
                                                      f1b, f2b_, bng, bnb, aib, Qb, F);
    // ---- attention ----
    attn4_kernel<<<NQ, blk, 0, stream>>>(Qb, KV, IDX, PERM);
    // ---- fused post chain ----
    chain2_kernel<<<NQ / 32, dim3(1024), 0, stream>>>(Qb, PH, PL, aob, clg, clb,
                                                      b1, b2, C2);
    // ---- H[n] = M_{c[n]} @ C2[n] (SEL) ----
    mgemm_b<0, 1><<<gSEL, blk, 0, stream>>>(C2, MCATb, nullptr, c, H, 256);
    // ---- final dot ----
    dot_kernel<<<NQ / 4, blk, 0, stream>>>(F, H, C2, c, Ubuf, Vbuf, Sbuf, lt, cs, cbv, out);
}

// Round 13
// 282.479 us; speedup vs baseline: 1.4932x; 1.0130x over previous
//
#include <hip/hip_runtime.h>
#include <cstdint>
#include <cstddef>

typedef unsigned short u16;
typedef __attribute__((ext_vector_type(8))) short s16x8;
typedef __attribute__((ext_vector_type(4))) float f32x4;

#define NQ   8192
#define TT   512
#define STOK 32
#define LDF  260   // Fv row stride (floats): 256 + 4 pad -> bank rotation by 4/row

// prep_all block ranges
#define PB_PACK 2208
#define PB_COMB (PB_PACK + 512)    // 2720
#define PB_MCAT (PB_COMB + 768)    // 3488
#define PB_UVS  (PB_MCAT + 24)     // 3512
#define PB_TOT  (PB_UVS + NQ)      // 11704

__device__ __forceinline__ float b2f(u16 u) {
    return __uint_as_float(((uint32_t)u) << 16);
}
__device__ __forceinline__ u16 f2b(float f) {
    uint32_t x = __float_as_uint(f);
    uint32_t r = (x + 0x7FFFu + ((x >> 16) & 1u)) >> 16;
    return (u16)r;
}
__device__ __forceinline__ float silu_f(float x) { return x / (1.f + expf(-x)); }

__global__ __launch_bounds__(256) void const_kernel(float v, float* __restrict__ out) {
    int i = blockIdx.x * 256 + threadIdx.x;
    if (i < NQ) out[i] = v;
}

// ---------------------------------------------------------------------------
// zero CNT[512] + U[768] + V[768] (uvs accumulates via atomicAdd)
// ---------------------------------------------------------------------------
__global__ __launch_bounds__(256) void zero_kernel(int* __restrict__ cnt,
                                                   float* __restrict__ U,
                                                   float* __restrict__ V) {
    int i = blockIdx.x * 256 + threadIdx.x;
    if (i < 512) cnt[i] = 0;
    else if (i < 1280) U[i - 512] = 0.f;
    else if (i < 2048) V[i - 1280] = 0.f;
}

// ---------------------------------------------------------------------------
// prep_all: merged input-only prep. Block-uniform branch per range; uvs
// parallelized 8x with fp32 atomicAdd into pre-zeroed U/V. feat32 branch
// also does the IDX histogram (thread 0 holds idx in-register -> atomicAdd
// into CNT; 512 buckets, ~16 hits each, uncontended), replacing hist_kernel.
//   [0,2208)        pack_split
//   [2208,2720)     combine_kv32
//   [2720,3488)     mcat
//   [3488,3512)     uvs (3 comps x 8 row-chunks)
//   [3512,11704)    feat32 + hist
// ---------------------------------------------------------------------------
__global__ __launch_bounds__(256) void prep_all(
    const float* __restrict__ f1w, const float* __restrict__ f2w,
    const float* __restrict__ aiw, const float* __restrict__ aow,
    const float* __restrict__ w1, const float* __restrict__ w2,
    const float* __restrict__ tiw,
    u16* __restrict__ PH, u16* __restrict__ PL,
    const float* __restrict__ aib, const float* __restrict__ btw,
    const float* __restrict__ btb, u16* __restrict__ WKVb,
    float* __restrict__ bkv,
    const float* __restrict__ tow, const float* __restrict__ bpw,
    u16* __restrict__ MCATb,
    const float* __restrict__ tob, const float* __restrict__ bpb,
    float* __restrict__ U, float* __restrict__ V, float* __restrict__ S,
    const float* __restrict__ xy, const float* __restrict__ t_q,
    const int* __restrict__ c, const float* __restrict__ st,
    const float* __restrict__ B, const float* __restrict__ tw,
    const float* __restrict__ tb, const float* __restrict__ ce,
    float* __restrict__ FIN, int* __restrict__ IDX, int* __restrict__ cnt) {
    __shared__ float As2[16][17], Bs2[16][17];
    __shared__ float wrow[256];
    __shared__ float red[4];
    const int b = blockIdx.x;
    const int t = threadIdx.x;

    if (b < PB_PACK) {
        // ---- pack_split: chain weights -> MFMA-fragment-linear bf16 hi/lo
        int i = b * 256 + t;
        if (i >= 565248) return;
        float v;
        size_t pos;
        if (i < 524288) {
            int m = i >> 16, j = i & 65535;
            int col = j >> 8, k = j & 255;
            const float* src;
            switch (m) {
                case 0: src = f1w; break;
                case 1: src = f1w + 65536; break;
                case 2: src = f2w; break;
                case 3: src = f2w + 65536; break;
                case 4: src = aiw; break;      // wq = rows 0..255 of attn_in_w
                case 5: src = aow; break;
                case 6: src = w1; break;
                default: src = w2; break;
            }
            v = src[j];
            int ct = col >> 4, m16 = col & 15, k0 = k >> 5, quad = (k >> 3) & 3, jj = k & 7;
            pos = (size_t)m * 65536 + (size_t)(((ct * 8 + k0) * 64 + quad * 16 + m16) * 8 + jj);
        } else {
            int j = i - 524288;                // 0..40959
            int col = j / 160, k = j % 160;
            v = (k < 152) ? tiw[col * 152 + k] : 0.f;
            int ct = col >> 4, m16 = col & 15, k0 = k >> 5, quad = (k >> 3) & 3, jj = k & 7;
            pos = 524288 + (size_t)(((ct * 5 + k0) * 64 + quad * 16 + m16) * 8 + jj);
        }
        u16 h = f2b(v);
        PH[pos] = h;
        PL[pos] = f2b(v - b2f(h));
    } else if (b < PB_COMB) {
        // ---- combine_kv32: fold token projection into K/V weights
        int bb = b - PB_PACK;
        int kv = bb >> 8, m = bb & 255;
        int d = t;
        wrow[d] = aiw[(size_t)(kv + 1) * 65536 + (size_t)m * 256 + d];
        __syncthreads();
        float acc = 0.f;
#pragma unroll 8
        for (int o = 0; o < 256; o++) acc += wrow[o] * btw[(size_t)o * 256 + d];
        WKVb[(size_t)kv * 65536 + (size_t)m * 256 + d] = f2b(acc);
        float pb = wrow[d] * btb[d];
#pragma unroll
        for (int mm = 32; mm >= 1; mm >>= 1) pb += __shfl_xor(pb, mm);
        if ((d & 63) == 0) red[d >> 6] = pb;
        __syncthreads();
        if (d == 0)
            bkv[kv * 256 + m] = red[0] + red[1] + red[2] + red[3] + aib[(kv + 1) * 256 + m];
    } else if (b < PB_MCAT) {
        // ---- mcat: M_c = tow_c^T @ bpw_c, bf16 out
        int m = b - PB_COMB;
        const int cc = m >> 8;
        const int rem = m & 255;
        const int t0 = (rem >> 4) * 16, k0 = (rem & 15) * 16;
        const int lt = t & 15, lj = t >> 4;
        const int ot = t & 15, ok = t >> 4;
        float acc = 0.f;
        for (int j0 = 0; j0 < 256; j0 += 16) {
            As2[lj][lt] = tow[((size_t)cc * 256 + j0 + lj) * 256 + t0 + lt];
            Bs2[lj][lt] = bpw[((size_t)cc * 256 + j0 + lj) * 256 + k0 + lt];
            __syncthreads();
#pragma unroll
            for (int jj = 0; jj < 16; jj++) acc += As2[jj][ot] * Bs2[jj][ok];
            __syncthreads();
        }
        MCATb[((size_t)cc * 256 + t0 + ot) * 256 + k0 + ok] = f2b(acc);
    } else if (b < PB_UVS) {
        // ---- uvs (8x parallel per comp, atomicAdd into zeroed U/V)
        int m = b - PB_MCAT;
        const int cc = m / 8, j = m % 8;
        float v = 0.f, u = 0.f;
        for (int r = j * 32; r < j * 32 + 32; r++) {
            v += tow[((size_t)cc * 256 + r) * 256 + t] * bpb[cc * 256 + r];
            u += bpw[((size_t)cc * 256 + r) * 256 + t] * tob[cc * 256 + r];
        }
        atomicAdd(&V[cc * 256 + t], v);
        atomicAdd(&U[cc * 256 + t], u);
        if (j == 0) {
            float sp = tob[cc * 256 + t] * bpb[cc * 256 + t];
#pragma unroll
            for (int mm = 32; mm >= 1; mm >>= 1) sp += __shfl_xor(sp, mm);
            if ((t & 63) == 0) red[t >> 6] = sp;
            __syncthreads();
            if (t == 0) S[cc] = red[0] + red[1] + red[2] + red[3];
        }
    } else {
        // ---- feat32 + hist: FIN fp32 [NQ,160] (cols 152..159 = 0), IDX, CNT
        int n = b - PB_UVS;
        float tq = t_q[n];
        int lo = 0, hi = TT;
        while (lo < hi) {
            int mid = (lo + hi) >> 1;
            if (st[mid] <= tq) lo = mid + 1; else hi = mid;
        }
        int idx = lo - 1;
        if (idx < 0) idx = 0;
        float dt = tq - st[idx];
        if (dt < 0.f) dt = 0.f;
        if (t == 0) {
            IDX[n] = idx;
            atomicAdd(&cnt[idx], 1);
        }
        float x = xy[2 * n], y = xy[2 * n + 1];
        size_t base = (size_t)n * 160;
        if (t < 64) { float p = x * B[t] + y * B[64 + t]; FIN[base + t] = cosf(p); }
        else if (t < 128) { int j = t - 64; float p = x * B[j] + y * B[64 + j]; FIN[base + t] = sinf(p); }
        else if (t < 144) { int j = t - 128; FIN[base + t] = dt * tw[j] + tb[j]; }
        else if (t < 152) { int j = t - 144; FIN[base + t] = ce[c[n] * 8 + j]; }
        else if (t < 160) { FIN[base + t] = 0.f; }
    }
}

// ---------------------------------------------------------------------------
// counting-sort of queries by IDX (512 buckets) -> perm (hist now in prep_all)
// ---------------------------------------------------------------------------
__global__ __launch_bounds__(512) void scan_kernel(const int* __restrict__ cnt,
                                                   int* __restrict__ base,
                                                   int* __restrict__ cur) {
    __shared__ int s[TT];
    int t = threadIdx.x;
    int v = cnt[t];
    s[t] = v;
    __syncthreads();
    for (int off = 1; off < TT; off <<= 1) {
        int add = (t >= off) ? s[t - off] : 0;
        __syncthreads();
        s[t] += add;
        __syncthreads();
    }
    base[t] = s[t] - v;
    cur[t] = s[t] - v;
}
__global__ __launch_bounds__(256) void scat_kernel(const int* __restrict__ IDX,
                                                   int* __restrict__ cur,
                                                   int* __restrict__ perm) {
    int n = blockIdx.x * 256 + threadIdx.x;
    if (n < NQ) {
        int pos = atomicAdd(&cur[IDX[n]], 1);
        perm[pos] = n;
    }
}

// ---------------------------------------------------------------------------
// mgemm_b: MFMA bf16 GEMM, A fp32 (converted on the fly), W pre-converted
// bf16. K=256, output stride ldc. ST16: store bf16. SEL: component select.
// ---------------------------------------------------------------------------
template <int ST16, int SEL>
__global__ __launch_bounds__(256) void mgemm_b(
    const float* __restrict__ A, const u16* __restrict__ Wb,
    const float* __restrict__ bias, const int* __restrict__ csel,
    void* __restrict__ Cv, int ldc) {
    __shared__ u16 As[64 * 40];
    __shared__ u16 Ws[64 * 40];
    const int t = threadIdx.x;
    const size_t rb = (size_t)blockIdx.x * 64;
    const size_t cb = (size_t)blockIdx.y * 64;
    const int wave = t >> 6, lane = t & 63;
    const int m16 = lane & 15, quad = lane >> 4;
    const int sr = t >> 2, sk = (t & 3) * 8;
    const float* Ap = A + (rb + sr) * 256 + sk;
    const u16* Wp = Wb + (cb + sr) * 256 + sk;

    f32x4 acc[4] = {};
    for (int k0 = 0; k0 < 256; k0 += 32) {
        float4 a0 = *(const float4*)(Ap + k0);
        float4 a1 = *(const float4*)(Ap + k0 + 4);
        u16 ta[8] = {f2b(a0.x), f2b(a0.y), f2b(a0.z), f2b(a0.w),
                     f2b(a1.x), f2b(a1.y), f2b(a1.z), f2b(a1.w)};
        *(uint4*)&As[sr * 40 + sk] = *(const uint4*)ta;
        *(uint4*)&Ws[sr * 40 + sk] = *(const uint4*)(Wp + k0);
        __syncthreads();
        s16x8 af = *(const s16x8*)&As[(wave * 16 + m16) * 40 + quad * 8];
#pragma unroll
        for (int ct = 0; ct < 4; ct++) {
            s16x8 bf = *(const s16x8*)&Ws[(ct * 16 + m16) * 40 + quad * 8];
            acc[ct] = __builtin_amdgcn_mfma_f32_16x16x32_bf16(af, bf, acc[ct], 0, 0, 0);
        }
        __syncthreads();
    }
#pragma unroll
    for (int ct = 0; ct < 4; ct++) {
        size_t col = cb + ct * 16 + m16;
        float bb = bias ? bias[col] : 0.f;
#pragma unroll
        for (int r = 0; r < 4; r++) {
            size_t row = rb + wave * 16 + quad * 4 + r;
            float x = acc[ct][r] + bb;
            if (SEL) {
                int comp = (int)(col >> 8);
                if (csel[row] == comp)
                    ((float*)Cv)[row * 256 + (col & 255)] = x;
            } else if (ST16) {
                ((u16*)Cv)[row * (size_t)ldc + col] = f2b(x);
            } else {
                ((float*)Cv)[row * (size_t)ldc + col] = x;
            }
        }
    }
}

// ---------------------------------------------------------------------------
// Fused chain machinery, v3: 1024 threads (16 waves), 32 rows, wave owns one
// 16-col tile. wload() preloads ALL B-fragments of a GEMM phase into a
// register array so the 16 weight loads issue back-to-back -> ONE latency
// exposure per phase. (Best-known config. MCAT-fold R4-R6: spill signature;
// 16-row 2-blocks/CU R10: correctness failure -> both permanently reverted.)
// MFMA order is numerics-defining: split x3 (ah*bh + al*bh + ah*bl).
// ---------------------------------------------------------------------------
template <int NK0>
struct WF { s16x8 h[NK0], l[NK0]; };

template <int NK0>
__device__ __forceinline__ void wload(const u16* __restrict__ PH,
                                      const u16* __restrict__ PL, size_t mb,
                                      int wave, int lane, WF<NK0>& w) {
#pragma unroll
    for (int k0 = 0; k0 < NK0; k0++) {
        const size_t wo = mb + ((size_t)(wave * NK0 + k0) * 64 + lane) * 8;
        w.h[k0] = *(const s16x8*)&PH[wo];
        w.l[k0] = *(const s16x8*)&PL[wo];
    }
}

template <int NK0>
__device__ __forceinline__ void cgemm_c(const WF<NK0>& w,
                                        const u16* Ch, const u16* Cl,
                                        int lane, f32x4 (&acc)[2]) {
    acc[0] = (f32x4){0.f, 0.f, 0.f, 0.f};
    acc[1] = (f32x4){0.f, 0.f, 0.f, 0.f};
#pragma unroll
    for (int k0 = 0; k0 < NK0; k0++) {
        s16x8 a0h = *(const s16x8*)&Ch[(k0 * 64 + lane) * 8];
        s16x8 a0l = *(const s16x8*)&Cl[(k0 * 64 + lane) * 8];
        s16x8 a1h = *(const s16x8*)&Ch[((8 + k0) * 64 + lane) * 8];
        s16x8 a1l = *(const s16x8*)&Cl[((8 + k0) * 64 + lane) * 8];
        acc[0] = __builtin_amdgcn_mfma_f32_16x16x32_bf16(a0h, w.h[k0], acc[0], 0, 0, 0);
        acc[0] = __builtin_amdgcn_mfma_f32_16x16x32_bf16(a0l, w.h[k0], acc[0], 0, 0, 0);
        acc[0] = __builtin_amdgcn_mfma_f32_16x16x32_bf16(a0h, w.l[k0], acc[0], 0, 0, 0);
        acc[1] = __builtin_amdgcn_mfma_f32_16x16x32_bf16(a1h, w.h[k0], acc[1], 0, 0, 0);
        acc[1] = __builtin_amdgcn_mfma_f32_16x16x32_bf16(a1l, w.h[k0], acc[1], 0, 0, 0);
        acc[1] = __builtin_amdgcn_mfma_f32_16x16x32_bf16(a1h, w.l[k0], acc[1], 0, 0, 0);
    }
}

// LN over Fv -> packed split Ch/Cl. Phase A: 32 threads/row compute stats.
// Phase B (transposed): each thread normalizes one 8-col chunk, writes uint4.
__device__ __forceinline__ void ln_split(const float* __restrict__ Fv,
                                         u16* __restrict__ Ch, u16* __restrict__ Cl,
                                         const float* __restrict__ g,
                                         const float* __restrict__ b,
                                         float* __restrict__ mean_s,
                                         float* __restrict__ rstd_s, int t) {
    {
        const int row = t >> 5, q = t & 31;
        const float* fr = Fv + row * LDF;
        float4 v0 = *(const float4*)&fr[q * 4];
        float4 v1 = *(const float4*)&fr[q * 4 + 128];
        float s1 = v0.x + v0.y + v0.z + v0.w + v1.x + v1.y + v1.z + v1.w;
        float s2 = v0.x * v0.x + v0.y * v0.y + v0.z * v0.z + v0.w * v0.w +
                   v1.x * v1.x + v1.y * v1.y + v1.z * v1.z + v1.w * v1.w;
#pragma unroll
        for (int m = 16; m >= 1; m >>= 1) {
            s1 += __shfl_xor(s1, m);
            s2 += __shfl_xor(s2, m);
        }
        if (q == 0) {
            float mean = s1 * (1.f / 256.f);
            mean_s[row] = mean;
            rstd_s[row] = rsqrtf(s2 * (1.f / 256.f) - mean * mean + 1e-5f);
        }
    }
    __syncthreads();
    {
        const int rw = t & 31, qc = t >> 5;
        const float* fr = Fv + rw * LDF + qc * 8;
        float4 v0 = *(const float4*)fr;
        float4 v1 = *(const float4*)(fr + 4);
        const float mean = mean_s[rw], rstd = rstd_s[rw];
        float4 g0 = *(const float4*)&g[qc * 8], g1 = *(const float4*)&g[qc * 8 + 4];
        float4 b0 = *(const float4*)&b[qc * 8], b1 = *(const float4*)&b[qc * 8 + 4];
        float va[8] = {v0.x, v0.y, v0.z, v0.w, v1.x, v1.y, v1.z, v1.w};
        float ga[8] = {g0.x, g0.y, g0.z, g0.w, g1.x, g1.y, g1.z, g1.w};
        float ba[8] = {b0.x, b0.y, b0.z, b0.w, b1.x, b1.y, b1.z, b1.w};
        u16 hv[8], lv[8];
#pragma unroll
        for (int j = 0; j < 8; j++) {
            float x = (va[j] - mean) * rstd * ga[j] + ba[j];
            hv[j] = f2b(x);
            lv[j] = f2b(x - b2f(hv[j]));
        }
        const int c = qc * 8;
        const int off = (((rw >> 4) * 8 + (c >> 5)) * 64 +
                         (((c >> 3) & 3) * 16 + (rw & 15))) * 8;
        *(uint4*)&Ch[off] = *(const uint4*)hv;
        *(uint4*)&Cl[off] = *(const uint4*)lv;
    }
}

// ---------------------------------------------------------------------------
// chain1: trunk_in -> [LN,fc1,fc2] x2 -> (F to global) -> LN -> q-proj
// ---------------------------------------------------------------------------
__global__ __launch_bounds__(1024) void chain1_kernel(
    const float* __restrict__ FIN, const u16* __restrict__ PH,
    const u16* __restrict__ PL, const float* __restrict__ tib,
    const float* __restrict__ lng, const float* __restrict__ lnb,
    const float* __restrict__ f1b, const float* __restrict__ f2bv,
    const float* __restrict__ bng, const float* __restrict__ bnb,
    const float* __restrict__ aib,
    float* __restrict__ Qb, float* __restrict__ Fg) {
    __shared__ u16 Ch[8192], Cl[8192];
    __shared__ float Fv[32 * LDF];
    __shared__ float mean_s[32], rstd_s[32];
    const int t = threadIdx.x;
    const int wave = t >> 6, lane = t & 63;
    const int m16 = lane & 15, quad = lane >> 4;
    const size_t rb = (size_t)blockIdx.x * 32;
    const int col = wave * 16 + m16;
    f32x4 acc[2];

    // phase 0: FIN [32,160] -> split packed
    {
        const int row = t >> 5, q = t & 31;
        if (q < 20) {
            const float* p = FIN + (rb + row) * 160 + q * 8;
            float4 v0 = *(const float4*)p, v1 = *(const float4*)(p + 4);
            float va[8] = {v0.x, v0.y, v0.z, v0.w, v1.x, v1.y, v1.z, v1.w};
            u16 hv[8], lv[8];
#pragma unroll
            for (int j = 0; j < 8; j++) { hv[j] = f2b(va[j]); lv[j] = f2b(va[j] - b2f(hv[j])); }
            const int c = q * 8;
            const int off = (((row >> 4) * 8 + (c >> 5)) * 64 +
                             (((c >> 3) & 3) * 16 + (row & 15))) * 8;
            *(uint4*)&Ch[off] = *(const uint4*)hv;
            *(uint4*)&Cl[off] = *(const uint4*)lv;
        }
    }

    // trunk_in (K=160): silu -> Fv
    {
        WF<5> w;
        wload<5>(PH, PL, 524288, wave, lane, w);
        __syncthreads();
        cgemm_c<5>(w, Ch, Cl, lane, acc);
    }
    {
        const float bb = tib[col];
#pragma unroll
        for (int rt = 0; rt < 2; rt++)
#pragma unroll
            for (int r = 0; r < 4; r++)
                Fv[(rt * 16 + quad * 4 + r) * LDF + col] = silu_f(acc[rt][r] + bb);
    }
    __syncthreads();

    // two residual blocks
#pragma unroll
    for (int L = 0; L < 2; L++) {
        ln_split(Fv, Ch, Cl, lng + L * 256, lnb + L * 256, mean_s, rstd_s, t);
        {
            WF<8> w;
            wload<8>(PH, PL, (size_t)L * 65536, wave, lane, w);  // fc1
            __syncthreads();
            cgemm_c<8>(w, Ch, Cl, lane, acc);
        }
        __syncthreads();
        {
            const float bb = f1b[L * 256 + col];
            const int k0c = col >> 5, qc4 = (col >> 3) & 3, jc = col & 7;
#pragma unroll
            for (int rt = 0; rt < 2; rt++)
#pragma unroll
                for (int r = 0; r < 4; r++) {
                    const int row = rt * 16 + quad * 4 + r;
                    float x = silu_f(acc[rt][r] + bb);
                    const int off = ((rt * 8 + k0c) * 64 + (qc4 * 16 + (row & 15))) * 8 + jc;
                    u16 h = f2b(x);
                    Ch[off] = h;
                    Cl[off] = f2b(x - b2f(h));
                }
        }
        {
            WF<8> w;
            wload<8>(PH, PL, 131072 + (size_t)L * 65536, wave, lane, w);  // fc2
            __syncthreads();
            cgemm_c<8>(w, Ch, Cl, lane, acc);
        }
        {
            const float bb = f2bv[L * 256 + col];
#pragma unroll
            for (int rt = 0; rt < 2; rt++)
#pragma unroll
                for (int r = 0; r < 4; r++) {
                    const int row = rt * 16 + quad * 4 + r;
                    Fv[row * LDF + col] += acc[rt][r] + bb;
                }
        }
        __syncthreads();
    }

    // F -> global ; LN(bn) -> packed C
    {
        const int row = t >> 5, q = t & 31;
        const float* fr = Fv + row * LDF + q * 8;
        float4 v0 = *(const float4*)fr, v1 = *(const float4*)(fr + 4);
        float* dst = Fg + (rb + row) * 256 + q * 8;
        *(float4*)dst = v0;
        *(float4*)(dst + 4) = v1;
    }
    ln_split(Fv, Ch, Cl, bng, bnb, mean_s, rstd_s, t);

    // q projection -> Qb global
    {
        WF<8> w;
        wload<8>(PH, PL, 262144, wave, lane, w);
        __syncthreads();
        cgemm_c<8>(w, Ch, Cl, lane, acc);
    }
    {
        const float bb = aib[col];
#pragma unroll
        for (int rt = 0; rt < 2; rt++)
#pragma unroll
            for (int r = 0; r < 4; r++) {
                const int row = rt * 16 + quad * 4 + r;
                Qb[(rb + row) * 256 + col] = acc[rt][r] + bb;
            }
    }
}

// ---------------------------------------------------------------------------
// chain2: attn_out -> LN -> bc1(silu) -> bc2(+res) -> C2 global
// ---------------------------------------------------------------------------
__global__ __launch_bounds__(1024) void chain2_kernel(
    const float* __restrict__ CTX, const u16* __restrict__ PH,
    const u16* __restrict__ PL, const float* __restrict__ aob,
    const float* __restrict__ clg, const float* __restrict__ clb,
    const float* __restrict__ b1, const float* __restrict__ b2v,
    float* __restrict__ C2g) {
    __shared__ u16 Ch[8192], Cl[8192];
    __shared__ float Fv[32 * LDF];
    __shared__ float mean_s[32], rstd_s[32];
    const int t = threadIdx.x;
    const int wave = t >> 6, lane = t & 63;
    const int m16 = lane & 15, quad = lane >> 4;
    const size_t rb = (size_t)blockIdx.x * 32;
    const int col = wave * 16 + m16;
    f32x4 acc[2];

    // phase 0: CTX -> split packed
    {
        const int row = t >> 5, q = t & 31;
        const float* p = CTX + (rb + row) * 256 + q * 8;
        float4 v0 = *(const float4*)p, v1 = *(const float4*)(p + 4);
        float va[8] = {v0.x, v0.y, v0.z, v0.w, v1.x, v1.y, v1.z, v1.w};
        u16 hv[8], lv[8];
#pragma unroll
        for (int j = 0; j < 8; j++) { hv[j] = f2b(va[j]); lv[j] = f2b(va[j] - b2f(hv[j])); }
        const int c = q * 8;
        const int off = (((row >> 4) * 8 + (c >> 5)) * 64 +
                         (((c >> 3) & 3) * 16 + (row & 15))) * 8;
        *(uint4*)&Ch[off] = *(const uint4*)hv;
        *(uint4*)&Cl[off] = *(const uint4*)lv;
    }

    // attn_out -> Fv
    {
        WF<8> w;
        wload<8>(PH, PL, 327680, wave, lane, w);
        __syncthreads();
        cgemm_c<8>(w, Ch, Cl, lane, acc);
    }
    {
        const float bb = aob[col];
#pragma unroll
        for (int rt = 0; rt < 2; rt++)
#pragma unroll
            for (int r = 0; r < 4; r++)
                Fv[(rt * 16 + quad * 4 + r) * LDF + col] = acc[rt][r] + bb;
    }
    __syncthreads();

    ln_split(Fv, Ch, Cl, clg, clb, mean_s, rstd_s, t);
    {
        WF<8> w;
        wload<8>(PH, PL, 393216, wave, lane, w);  // bc1
        __syncthreads();
        cgemm_c<8>(w, Ch, Cl, lane, acc);
    }
    __syncthreads();
    {
        const float bb = b1[col];
        const int k0c = col >> 5, qc4 = (col >> 3) & 3, jc = col & 7;
#pragma unroll
        for (int rt = 0; rt < 2; rt++)
#pragma unroll
            for (int r = 0; r < 4; r++) {
                const int row = rt * 16 + quad * 4 + r;
                float x = silu_f(acc[rt][r] + bb);
                const int off = ((rt * 8 + k0c) * 64 + (qc4 * 16 + (row & 15))) * 8 + jc;
                u16 h = f2b(x);
                Ch[off] = h;
                Cl[off] = f2b(x - b2f(h));
            }
    }
    {
        WF<8> w;
        wload<8>(PH, PL, 458752, wave, lane, w);  // bc2
        __syncthreads();
        cgemm_c<8>(w, Ch, Cl, lane, acc);
    }
    {
        const float bb = b2v[col];
#pragma unroll
        for (int rt = 0; rt < 2; rt++)
#pragma unroll
            for (int r = 0; r < 4; r++) {
                const int row = rt * 16 + quad * 4 + r;
                C2g[(rb + row) * 256 + col] = acc[rt][r] + bb + Fv[row * LDF + col];
            }
    }
}

// ---------------------------------------------------------------------------
// attn4: one block per query (perm-ordered). KV interleaved [16384,512] bf16.
// In-place Qb -> CTX.
// ---------------------------------------------------------------------------
__global__ __launch_bounds__(256) void attn4_kernel(
    float* __restrict__ QC, const u16* __restrict__ KV,
    const int* __restrict__ idx, const int* __restrict__ perm) {
    __shared__ u16 vsh[STOK * 264];
    __shared__ float qsh[256], attw[4][STOK];
    const int n = perm[blockIdx.x];
    const int t = threadIdx.x;
    qsh[t] = QC[(size_t)n * 256 + t];
    int ii = idx[n];
    ii = ii < 0 ? 0 : (ii > TT - 1 ? TT - 1 : ii);
    const u16* kvb = KV + (size_t)ii * STOK * 512;
#pragma unroll
    for (int i = t; i < 1024; i += 256) {
        int s = i >> 5, dq = (i & 31) * 8;
        *(uint4*)&vsh[s * 264 + dq] = *(const uint4*)&kvb[(size_t)s * 512 + 256 + dq];
    }
    __syncthreads();
    if (t < 128) {
        int h = t >> 5, s = t & 31;
        const u16* kp = kvb + (size_t)s * 512 + h * 64;
        uint4 kv[8];
#pragma unroll
        for (int dq = 0; dq < 8; dq++) kv[dq] = *(const uint4*)(kp + dq * 8);
        float p0 = 0.f, p1 = 0.f;
#pragma unroll
        for (int dq = 0; dq < 8; dq++) {
            const u16* ks = (const u16*)&kv[dq];
            float a0 = 0.f;
#pragma unroll
            for (int j = 0; j < 8; j++) a0 += qsh[h * 64 + dq * 8 + j] * b2f(ks[j]);
            if (dq & 1) p1 += a0; else p0 += a0;
        }
        float sc = (p0 + p1) * 0.125f;
        float mx = sc;
#pragma unroll
        for (int m = 16; m >= 1; m >>= 1) mx = fmaxf(mx, __shfl_xor(mx, m));
        float e = expf(sc - mx);
        float sum = e;
#pragma unroll
        for (int m = 16; m >= 1; m >>= 1) sum += __shfl_xor(sum, m);
        attw[h][s] = e / sum;
    }
    __syncthreads();
    {
        int h = t >> 6;
        float a = 0.f;
#pragma unroll 8
        for (int s = 0; s < STOK; s++) a += attw[h][s] * b2f(vsh[s * 264 + t]);
        QC[(size_t)n * 256 + t] = a;
    }
}

// ---------------------------------------------------------------------------
// final dot: out[n] = (F·H + F·v_cc + u_cc·C2 + s_cc) * exp(lt)*cs + cb
// ---------------------------------------------------------------------------
__global__ __launch_bounds__(256) void dot_kernel(
    const float* __restrict__ F, const float* __restrict__ H,
    const float* __restrict__ C2, const int* __restrict__ c,
    const float* __restrict__ U, const float* __restrict__ V,
    const float* __restrict__ S, const float* __restrict__ lt,
    const float* __restrict__ cs, const float* __restrict__ cbv,
    float* __restrict__ out) {
    const int n = blockIdx.x * 4 + (threadIdx.x >> 6);
    const int lane = threadIdx.x & 63;
    const int cc = c[n];
    float4 f4 = *(const float4*)&F[(size_t)n * 256 + lane * 4];
    float4 h4 = *(const float4*)&H[(size_t)n * 256 + lane * 4];
    float4 g4 = *(const float4*)&C2[(size_t)n * 256 + lane * 4];
    float4 v4 = *(const float4*)&V[cc * 256 + lane * 4];
    float4 u4 = *(const float4*)&U[cc * 256 + lane * 4];
    float a = f4.x * (h4.x + v4.x) + f4.y * (h4.y + v4.y) +
              f4.z * (h4.z + v4.z) + f4.w * (h4.w + v4.w) +
              u4.x * g4.x + u4.y * g4.y + u4.z * g4.z + u4.w * g4.w;
#pragma unroll
    for (int m = 32; m >= 1; m >>= 1) a += __shfl_xor(a, m);
    if (lane == 0)
        out[n] = (a + S[cc]) * expf(lt[0]) * cs[cc] + cbv[cc];
}

// ---------------------------------------------------------------------------
extern "C" void kernel_launch(void* const* d_in, const int* in_sizes, int n_in,
                              void* d_out, int out_size, void* d_ws, size_t ws_size,
                              hipStream_t stream) {
    float* out = (float*)d_out;
    const dim3 blk(256);

    static const int EXPECT[38] = {
        16384, 8192, 8192, 4194304, 512, 128, 16, 16, 24,
        38912, 256, 512, 512, 131072, 512, 131072, 512,
        65536, 256, 256, 256, 196608, 768, 65536, 256,
        256, 256, 65536, 256, 65536, 256, 196608, 768,
        196608, 768, 1, 3, 3};
    if (n_in != 38) { const_kernel<<<NQ / 256, blk, 0, stream>>>(99.0e6f, out); return; }
    for (int i = 0; i < 38; i++)
        if (in_sizes[i] != EXPECT[i]) {
            const_kernel<<<NQ / 256, blk, 0, stream>>>((100.0f + i) * 1.0e6f, out);
            return;
        }

    const float* xy  = (const float*)d_in[0];
    const float* tq  = (const float*)d_in[1];
    const int*   c   = (const int*)d_in[2];
    const float* hs  = (const float*)d_in[3];
    const float* st  = (const float*)d_in[4];
    const float* Bm  = (const float*)d_in[5];
    const float* tw  = (const float*)d_in[6];
    const float* tbv = (const float*)d_in[7];
    const float* ce  = (const float*)d_in[8];
    const float* tiw = (const float*)d_in[9];
    const float* tib = (const float*)d_in[10];
    const float* lng = (const float*)d_in[11];
    const float* lnb = (const float*)d_in[12];
    const float* f1w = (const float*)d_in[13];
    const float* f1b = (const float*)d_in[14];
    const float* f2w = (const float*)d_in[15];
    const float* f2b_ = (const float*)d_in[16];
    const float* btw = (const float*)d_in[17];
    const float* btb = (const float*)d_in[18];
    const float* bng = (const float*)d_in[19];
    const float* bnb = (const float*)d_in[20];
    const float* aiw = (const float*)d_in[21];
    const float* aib = (const float*)d_in[22];
    const float* aow = (const float*)d_in[23];
    const float* aob = (const float*)d_in[24];
    const float* clg = (const float*)d_in[25];
    const float* clb = (const float*)d_in[26];
    const float* w1  = (const float*)d_in[27];
    const float* b1  = (const float*)d_in[28];
    const float* w2  = (const float*)d_in[29];
    const float* b2  = (const float*)d_in[30];
    const float* tow = (const float*)d_in[31];
    const float* tob = (const float*)d_in[32];
    const float* bpw = (const float*)d_in[33];
    const float* bpb = (const float*)d_in[34];
    const float* lt  = (const float*)d_in[35];
    const float* cs  = (const float*)d_in[36];
    const float* cbv = (const float*)d_in[37];

    char* ws = (char*)d_ws;
    const size_t MB = 1 << 20;
    if (ws_size < 44 * MB) {
        const_kernel<<<NQ / 256, blk, 0, stream>>>(8.0e6f, out);
        return;
    }

    // KV interleaved [16384,512] bf16 = 16 MB at [0,16). Slots 8 MB each.
    u16*   KV   = (u16*)(ws + 0 * MB);
    char*  S_A  = ws + 16 * MB;   // FIN -> H (SEL output)
    char*  S_B  = ws + 24 * MB;   // F (trunk state, written once by chain1)
    char*  S_C  = ws + 32 * MB;   // Qb -> CTX (attn in-place) -> C2 (in-place)
    char*  misc = ws + 40 * MB;
    float* FIN  = (float*)S_A;
    float* H    = (float*)S_A;
    float* F    = (float*)S_B;
    float* Qb   = (float*)S_C;
    float* C2   = (float*)S_C;
    int*   IDX  = (int*)(misc + 0);                   // 32KB
    float* bkv  = (float*)(misc + 32 * 1024);         // 4KB
    float* Ubuf = (float*)(misc + 36 * 1024);
    float* Vbuf = (float*)(misc + 40 * 1024);
    float* Sbuf = (float*)(misc + 44 * 1024);
    int*   CNT  = (int*)(misc + 48 * 1024);
    int*   BASE = (int*)(misc + 52 * 1024);
    int*   CUR  = (int*)(misc + 56 * 1024);
    int*   PERM = (int*)(misc + 60 * 1024);           // 32KB -> 92K
    u16*   WKVb = (u16*)(misc + 92 * 1024);           // [512,256] 256KB -> 348K
    u16*   MCATb= (u16*)(misc + 348 * 1024);          // [768,256] 384KB -> 732K
    u16*   PH   = (u16*)(misc + 732 * 1024);          // packed hi 1104KB -> 1836K
    u16*   PL   = (u16*)(misc + 1836 * 1024);         // packed lo 1104KB -> 2940K

    const dim3 gKV(TT * STOK / 64, 8);   // M=16384, N=512
    const dim3 gSEL(NQ / 64, 12);

    // ---- prep: zero, then single merged input-only kernel (incl. hist) ----
    zero_kernel<<<8, blk, 0, stream>>>(CNT, Ubuf, Vbuf);
    prep_all<<<PB_TOT, blk, 0, stream>>>(
        f1w, f2w, aiw, aow, w1, w2, tiw, PH, PL,
        aib, btw, btb, WKVb, bkv,
        tow, bpw, MCATb,
        tob, bpb, Ubuf, Vbuf, Sbuf,
        xy, tq, c, st, Bm, tw, tbv, ce, FIN, IDX, CNT);

    // ---- sort queries by time index (hist fused into prep_all) ----
    scan_kernel<<<1, dim3(512), 0, stream>>>(CNT, BASE, CUR);
    scat_kernel<<<NQ / 256, blk, 0, stream>>>(IDX, CUR, PERM);

    // ---- K/V (single merged GEMM, bf16 interleaved output) ----
    mgemm_b<1, 0><<<gKV, blk, 0, stream>>>(hs, WKVb, bkv, nullptr, KV, 512);

    // ---- fused trunk chain: 6 GEMMs in one dispatch, 16 waves/block ----
    chain1_kernel<<<NQ / 32, dim3(1024), 0, stream>>>(FIN, PH, PL, tib, lng, lnb,
                                                      f1b, f2b_, bng, bnb, aib, Qb, F);
    // ---- attention ----
    attn4_kernel<<<NQ, blk, 0, stream>>>(Qb, KV, IDX, PERM);
    // ---- fused post chain ----
    chain2_kernel<<<NQ / 32, dim3(1024), 0, stream>>>(Qb, PH, PL, aob, clg, clb,
                                                      b1, b2, C2);
    // ---- H[n] = M_{c[n]} @ C2[n] (SEL) ----
    mgemm_b<0, 1><<<gSEL, blk, 0, stream>>>(C2, MCATb, nullptr, c, H, 256);
    // ---- final dot ----
    dot_kernel<<<NQ / 4, blk, 0, stream>>>(F, H, C2, c, Ubuf, Vbuf, Sbuf, lt, cs, cbv, out);
}